// Round 3
// baseline (2172.170 us; speedup 1.0000x reference)
//
#include <hip/hip_runtime.h>
#include <cstdint>
#include <cstddef>

#define F4(p)  (*(reinterpret_cast<float4*>(p)))
#define CF4(p) (*(reinterpret_cast<const float4*>(p)))

typedef __attribute__((ext_vector_type(8))) short short8;
typedef __attribute__((ext_vector_type(4))) float f32x4;

__device__ __forceinline__ float bf2f(unsigned short h) {
  return __uint_as_float(((unsigned int)h) << 16);
}
__device__ __forceinline__ unsigned short f2bf(float x) {
  unsigned int u = __float_as_uint(x);
  return (unsigned short)((u + 0x7FFFu + ((u >> 16) & 1u)) >> 16);
}

#if __has_builtin(__builtin_amdgcn_global_load_lds)
#define USE_GLL 1
#else
#define USE_GLL 0
#endif

__device__ __forceinline__ void stage16(unsigned short* lds_lane,
                                        unsigned short* lds_wavebase,
                                        const unsigned short* g) {
#if USE_GLL
  __builtin_amdgcn_global_load_lds(
      (const __attribute__((address_space(1))) unsigned int*)g,
      (__attribute__((address_space(3))) unsigned int*)lds_wavebase, 16, 0, 0);
#else
  *(short8*)lds_lane = *(const short8*)g;
#endif
}

// =====================================================================
// bf16 MFMA GEMM: C = post( scale*(A@B^T) + bias + src )
// dual-A (k-split) and dual-B (n-split) supported. 128x128 tile, BK=64,
// 4 waves 2x2, XOR-swizzled LDS via pre-swizzled global source.
// qperm: write f32 C in the recurrence's Qr fragment order.
// src_c0: src added only for gc>=src_c0, at column (gc-src_c0).
// =====================================================================
__global__ __launch_bounds__(256) void gemm_bf(
    const unsigned short* __restrict__ A, int lda,
    const unsigned short* __restrict__ A2, int lda2, int kSplit,
    const unsigned short* __restrict__ B, int ldb,
    const unsigned short* __restrict__ B2, int ldb2, int nSplit,
    void* __restrict__ Cv, int ldc, int K,
    const float* __restrict__ bias,
    const float* __restrict__ src, int ldsrc, int src_c0,
    const float* __restrict__ scale_ptr, int relu, int obf16, int qperm)
{
  __shared__ unsigned short As[128 * 64];
  __shared__ unsigned short Bs[128 * 64];
  const int tid = threadIdx.x;
  const int wv = tid >> 6, ln = tid & 63;
  const int wm = wv >> 1, wn = wv & 1;
  const size_t gm0 = (size_t)blockIdx.y * 128;
  const size_t gn0 = (size_t)blockIdx.x * 128;

  f32x4 acc[4][4];
  #pragma unroll
  for (int i = 0; i < 4; ++i)
    #pragma unroll
    for (int j = 0; j < 4; ++j) acc[i][j] = (f32x4){0.f, 0.f, 0.f, 0.f};

  for (int kk = 0; kk < K; kk += 64) {
    const unsigned short* Ause = A; int lduse = lda; int kkA = kk;
    if (A2 != nullptr && kk >= kSplit) { Ause = A2; lduse = lda2; kkA = kk - kSplit; }
    #pragma unroll
    for (int j = 0; j < 4; ++j) {
      int idx = j * 256 + tid;
      int r = idx >> 3, u = idx & 7;
      int ksw = (u ^ (r & 7)) << 3;
      const unsigned short* ga = Ause + (gm0 + r) * lduse + kkA + ksw;
      stage16(&As[idx * 8], &As[(idx & ~63) * 8], ga);
      size_t nr = gn0 + r;
      const unsigned short* gb = (nr < (size_t)nSplit)
          ? B + nr * ldb + kk + ksw
          : B2 + (nr - nSplit) * ldb2 + kk + ksw;
      stage16(&Bs[idx * 8], &Bs[(idx & ~63) * 8], gb);
    }
    __syncthreads();
    #pragma unroll
    for (int ks = 0; ks < 2; ++ks) {
      short8 af[4], bfv[4];
      #pragma unroll
      for (int mi = 0; mi < 4; ++mi) {
        int r = wm * 64 + mi * 16 + (ln & 15);
        int u = (ks * 4 + (ln >> 4)) ^ (r & 7);
        af[mi] = *(const short8*)&As[(r * 8 + u) * 8];
      }
      #pragma unroll
      for (int nj = 0; nj < 4; ++nj) {
        int r = wn * 64 + nj * 16 + (ln & 15);
        int u = (ks * 4 + (ln >> 4)) ^ (r & 7);
        bfv[nj] = *(const short8*)&Bs[(r * 8 + u) * 8];
      }
      #pragma unroll
      for (int mi = 0; mi < 4; ++mi)
        #pragma unroll
        for (int nj = 0; nj < 4; ++nj)
          acc[mi][nj] = __builtin_amdgcn_mfma_f32_16x16x32_bf16(
              af[mi], bfv[nj], acc[mi][nj], 0, 0, 0);
    }
    __syncthreads();
  }

  float sc = scale_ptr ? *scale_ptr : 1.0f;
  #pragma unroll
  for (int nj = 0; nj < 4; ++nj) {
    int gc = (int)gn0 + wn * 64 + nj * 16 + (ln & 15);
    float bv = bias ? bias[gc] : 0.f;
    #pragma unroll
    for (int mi = 0; mi < 4; ++mi) {
      #pragma unroll
      for (int qq = 0; qq < 4; ++qq) {
        int gr = (int)gm0 + wm * 64 + mi * 16 + ((ln >> 4) << 2) + qq;
        float v = acc[mi][nj][qq] * sc + bv;
        if (src && gc >= src_c0) v += src[(size_t)gr * ldsrc + (gc - src_c0)];
        if (relu) v = fmaxf(v, 0.f);
        if (qperm) {
          int t = gr & 127, bq = gr >> 7;
          int g = gc >> 8, d = gc & 255;
          int ddq = d >> 5, doff = d & 31;
          int wq = bq >> 4;
          int lq = (bq & 15) + ((doff >> 3) << 4);
          size_t qi = (((((size_t)t * 8 + ddq) * 3 + g) * 4 + wq) * 64 + lq) * 8
                      + (doff & 7);
          ((float*)Cv)[qi] = v;
        } else if (obf16) {
          ((unsigned short*)Cv)[(size_t)gr * ldc + gc] = f2bf(v);
        } else {
          ((float*)Cv)[(size_t)gr * ldc + gc] = v;
        }
      }
    }
  }
}

// =====================================================================
__global__ __launch_bounds__(256) void cvt_bf(
    const float* __restrict__ in, unsigned short* __restrict__ outp, int n4)
{
  int i = blockIdx.x * 256 + threadIdx.x;
  if (i < n4) {
    float4 v = CF4(in + (size_t)i * 4);
    ushort4 o;
    o.x = f2bf(v.x); o.y = f2bf(v.y); o.z = f2bf(v.z); o.w = f2bf(v.w);
    *(ushort4*)(outp + (size_t)i * 4) = o;
  }
}

__global__ __launch_bounds__(256) void transpose_bf(
    const float* __restrict__ in, int ldin, unsigned short* __restrict__ outp, int R)
{
  __shared__ float tile[32][33];
  int c0 = blockIdx.x * 32, r0 = blockIdx.y * 32;
  int tx = threadIdx.x & 31, ty = threadIdx.x >> 5;
  #pragma unroll
  for (int i = ty; i < 32; i += 8)
    tile[i][tx] = in[(size_t)(r0 + i) * ldin + c0 + tx];
  __syncthreads();
  #pragma unroll
  for (int i = ty; i < 32; i += 8)
    outp[(size_t)(c0 + i) * R + r0 + tx] = f2bf(tile[tx][i]);
}

// out3[m*3072+i] = dot(A[i], x_m) + aib[i],  m=0..2 (A row read once)
__global__ __launch_bounds__(64) void matvec3(
    const float* __restrict__ A,
    const float* __restrict__ x0, const float* __restrict__ x1,
    const float* __restrict__ x2, const float* __restrict__ aib,
    float* __restrict__ outp)
{
  int i = blockIdx.x, t = threadIdx.x;
  const float* Ar = A + (size_t)i * 1024;
  float s0 = 0.f, s1 = 0.f, s2 = 0.f;
  for (int k = t * 4; k < 1024; k += 256) {
    float4 a = CF4(Ar + k);
    float4 v0 = CF4(x0 + k), v1 = CF4(x1 + k), v2 = CF4(x2 + k);
    s0 += a.x*v0.x + a.y*v0.y + a.z*v0.z + a.w*v0.w;
    s1 += a.x*v1.x + a.y*v1.y + a.z*v1.z + a.w*v1.w;
    s2 += a.x*v2.x + a.y*v2.y + a.z*v2.z + a.w*v2.w;
  }
  #pragma unroll
  for (int m = 32; m > 0; m >>= 1) {
    s0 += __shfl_xor(s0, m); s1 += __shfl_xor(s1, m); s2 += __shfl_xor(s2, m);
  }
  if (t == 0) {
    float b = aib[i];
    outp[i] = s0 + b; outp[3072 + i] = s1 + b; outp[6144 + i] = s2 + b;
  }
}

__global__ __launch_bounds__(64) void matvec_nt(
    const float* __restrict__ A, int lda,
    const float* __restrict__ x, const float* __restrict__ badd,
    float* __restrict__ outp, int K)
{
  int i = blockIdx.x, t = threadIdx.x;
  const float* Ar = A + (size_t)i * lda;
  float s = 0.f;
  for (int k = t * 4; k < K; k += 256) {
    float4 a = CF4(Ar + k);
    float4 xx = CF4(x + k);
    s += a.x*xx.x + a.y*xx.y + a.z*xx.z + a.w*xx.w;
  }
  #pragma unroll
  for (int m = 32; m > 0; m >>= 1) s += __shfl_xor(s, m);
  if (t == 0) outp[i] = s + (badd ? badd[i] : 0.f);
}

__global__ __launch_bounds__(256) void imp_rep_k(
    const float* __restrict__ importance, const float* __restrict__ aob,
    float* __restrict__ imp, float* __restrict__ rep)
{
  __shared__ float si[3];
  if (threadIdx.x == 0) {
    float a = importance[0], b = importance[1], c = importance[2];
    float mx = fmaxf(a, fmaxf(b, c));
    float ea = expf(a - mx), eb = expf(b - mx), ec = expf(c - mx);
    float inv = 1.f / (ea + eb + ec);
    si[0] = ea * inv; si[1] = eb * inv; si[2] = ec * inv;
    imp[0] = si[0]; imp[1] = si[1]; imp[2] = si[2];
  }
  __syncthreads();
  for (int idx = threadIdx.x; idx < 3072; idx += 256)
    rep[idx] = si[idx >> 10] * aob[idx & 1023];
}

// cb768 = gbih + [gbhh_r | gbhh_z | 0] ; cb2048 = [prb | 0]
__global__ __launch_bounds__(256) void bias_prep(
    const float* __restrict__ gbih, const float* __restrict__ gbhh,
    const float* __restrict__ prb, float* __restrict__ cb768,
    float* __restrict__ cb2048)
{
  int i = blockIdx.x * 256 + threadIdx.x;
  if (i < 768) cb768[i] = gbih[i] + (i < 512 ? gbhh[i] : 0.f);
  if (i < 2048) cb2048[i] = (i < 1024) ? prb[i] : 0.f;
}

// =====================================================================
// 3-token MHA, bf16 in -> bf16 out
// =====================================================================
__global__ __launch_bounds__(256) void attn3(
    const unsigned short* __restrict__ qkv, unsigned short* __restrict__ att)
{
  const int n = blockIdx.x;
  const unsigned short* row = qkv + (size_t)n * 9216;
  __shared__ float qk[6144];
  __shared__ float sc[72];
  __shared__ float pw[72];
  const int t = threadIdx.x;
  for (int idx = t; idx < 768; idx += 256) {
    int m = idx >> 7;                  // 0..5
    int off = (idx & 127) << 3;
    const unsigned short* srcp = (m < 3) ? (row + m * 3072 + off)
                                         : (row + (m - 3) * 3072 + 1024 + off);
    short8 v = *(const short8*)srcp;
    float* dst = &qk[m * 1024 + off];
    #pragma unroll
    for (int j = 0; j < 8; ++j) dst[j] = bf2f(((const unsigned short*)&v)[j]);
  }
  __syncthreads();
  if (t < 72) {
    int h = t / 9, i = (t % 9) / 3, j = t % 3;
    const float* qp = &qk[i * 1024 + h * 128];
    const float* kp = &qk[3072 + j * 1024 + h * 128];
    float s = 0.f;
    int rot = (t & 31) * 4;
    for (int d2 = 0; d2 < 128; ++d2) {
      int dx = (d2 + rot) & 127;
      s += qp[dx] * kp[dx];
    }
    sc[t] = s * 0.08838834764831845f;
  }
  __syncthreads();
  if (t < 24) {
    int base = t * 3;
    float a = sc[base], b = sc[base + 1], c = sc[base + 2];
    float mx = fmaxf(a, fmaxf(b, c));
    float ea = expf(a - mx), eb = expf(b - mx), ec = expf(c - mx);
    float inv = 1.f / (ea + eb + ec);
    pw[base] = ea * inv; pw[base + 1] = eb * inv; pw[base + 2] = ec * inv;
  }
  __syncthreads();
  unsigned short* outp = att + (size_t)n * 3072;
  #pragma unroll
  for (int rep = 0; rep < 3; ++rep) {
    int idx = (rep * 256 + t) << 2;
    int i = idx >> 10;
    int hd = idx & 1023;
    int h = hd >> 7;
    int pb = (h * 3 + i) * 3;
    float w0 = pw[pb], w1 = pw[pb + 1], w2 = pw[pb + 2];
    ushort4 v0 = *(const ushort4*)(row + 2048 + hd);
    ushort4 v1 = *(const ushort4*)(row + 3072 + 2048 + hd);
    ushort4 v2 = *(const ushort4*)(row + 6144 + 2048 + hd);
    ushort4 o;
    o.x = f2bf(w0 * bf2f(v0.x) + w1 * bf2f(v1.x) + w2 * bf2f(v2.x));
    o.y = f2bf(w0 * bf2f(v0.y) + w1 * bf2f(v1.y) + w2 * bf2f(v2.y));
    o.z = f2bf(w0 * bf2f(v0.z) + w1 * bf2f(v1.z) + w2 * bf2f(v2.z));
    o.w = f2bf(w0 * bf2f(v0.w) + w1 * bf2f(v1.w) + w2 * bf2f(v2.w));
    *(ushort4*)(outp + idx) = o;
  }
}

// =====================================================================
__global__ __launch_bounds__(256) void layernorm_bf(
    unsigned short* __restrict__ X, const float* __restrict__ g,
    const float* __restrict__ bta)
{
  int n = blockIdx.x, t = threadIdx.x;
  unsigned short* row = X + (size_t)n * 1024;
  ushort4 hv = *(ushort4*)(row + t * 4);
  float x0 = bf2f(hv.x), x1 = bf2f(hv.y), x2 = bf2f(hv.z), x3 = bf2f(hv.w);
  float s = x0 + x1 + x2 + x3;
  float ss = x0*x0 + x1*x1 + x2*x2 + x3*x3;
  #pragma unroll
  for (int m = 32; m > 0; m >>= 1) { s += __shfl_xor(s, m); ss += __shfl_xor(ss, m); }
  __shared__ float rs[4], rss[4];
  int w = t >> 6;
  if ((t & 63) == 0) { rs[w] = s; rss[w] = ss; }
  __syncthreads();
  s = rs[0] + rs[1] + rs[2] + rs[3];
  ss = rss[0] + rss[1] + rss[2] + rss[3];
  float mean = s * (1.0f / 1024.0f);
  float var = ss * (1.0f / 1024.0f) - mean * mean;
  float inv = 1.0f / sqrtf(var + 1e-5f);
  float4 gg = CF4(g + t * 4);
  float4 bb = CF4(bta + t * 4);
  ushort4 o;
  o.x = f2bf((x0 - mean) * inv * gg.x + bb.x);
  o.y = f2bf((x1 - mean) * inv * gg.y + bb.y);
  o.z = f2bf((x2 - mean) * inv * gg.z + bb.z);
  o.w = f2bf((x3 - mean) * inv * gg.w + bb.w);
  *(ushort4*)(row + t * 4) = o;
}

__global__ __launch_bounds__(256) void build_R_bf(
    const float* __restrict__ Fpb, const float* __restrict__ noise,
    const float* __restrict__ s0, unsigned short* __restrict__ R)
{
  size_t idx = (size_t)blockIdx.x * 256 + threadIdx.x;
  int n = (int)(idx >> 8);
  int k4 = (int)(idx & 255) << 2;
  float4 v;
  if ((n & 127) == 0) {
    v = CF4(s0 + (size_t)(n >> 7) * 1024 + k4);
  } else {
    float4 f = CF4(Fpb + (size_t)(n - 1) * 1024 + k4);
    float4 z = CF4(noise + (size_t)(n - 1) * 1024 + k4);
    v.x = f.x + z.x; v.y = f.y + z.y; v.z = f.z + z.z; v.w = f.w + z.w;
  }
  ushort4 o;
  o.x = f2bf(v.x); o.y = f2bf(v.y); o.z = f2bf(v.z); o.w = f2bf(v.w);
  *(ushort4*)(R + (size_t)n * 1024 + k4) = o;
}

__global__ __launch_bounds__(256) void s_out_k(
    float* __restrict__ outp, const float* __restrict__ noise)
{
  size_t idx = (size_t)blockIdx.x * 256 + threadIdx.x;
  int n = (int)(idx >> 8);
  int j4 = (int)(idx & 255) << 2;
  float4 p = CF4(outp + (size_t)n * 3328 + 2304 + j4);
  float4 z = CF4(noise + (size_t)n * 1024 + j4);
  float4 o; o.x = p.x + z.x; o.y = p.y + z.y; o.z = p.z + z.z; o.w = p.w + z.w;
  F4(outp + (size_t)n * 3328 + 256 + j4) = o;
}

// =====================================================================
// Recurrence weight prep: 8 blocks x 12 row-tiles of 16 rows, B-frag order.
// Wr[((dd*12+r)*8+kt)*512 + l*8 + j] = W[(g%3)*256 + dd*32 + (r&1)*16 + (l&15)]
//                                       [kt*32 + (l>>4)*8 + j],  g=r>>1
// =====================================================================
__global__ __launch_bounds__(256) void wr_prep(
    const unsigned short* __restrict__ M1bf, const unsigned short* __restrict__ Whhbf,
    unsigned short* __restrict__ Wr)
{
  int idx = blockIdx.x * 256 + threadIdx.x;   // < 393216
  int j = idx & 7, l = (idx >> 3) & 63, kt = (idx >> 9) & 7;
  int rest = idx >> 12;                        // dd*12 + r
  int r = rest % 12, dd = rest / 12;
  int g = r >> 1, dhalf = r & 1;
  int d = dd * 32 + dhalf * 16 + (l & 15);
  int srow = (g % 3) * 256 + d;
  int k = kt * 32 + ((l >> 4) << 3) + j;
  const unsigned short* srcp = (g < 3) ? M1bf : Whhbf;
  Wr[idx] = srcp[(size_t)srow * 256 + k];
}

// hist frag layout: [buf][w'][kt][l][j], b=16w'+(l&15), k=kt*32+(l>>4)*8+j
__global__ __launch_bounds__(256) void h0_prep(
    const float* __restrict__ h0, unsigned short* __restrict__ hist)
{
  int idx = blockIdx.x * 256 + threadIdx.x;   // < 16384
  int j = idx & 7, l = (idx >> 3) & 63, kt = (idx >> 9) & 7, w = idx >> 12;
  int b = 16 * w + (l & 15);
  int k = kt * 32 + ((l >> 4) << 3) + j;
  hist[idx] = f2bf(h0[(size_t)b * 256 + k]);
}

// =====================================================================
// Sequential RSSM v3. 8 blocks (32 d-cols each), 256 thr = 4 waves.
// Weights register-resident (24 B-frags/wave). Per step: 32 coalesced
// A-frag loads -> 96 MFMA/wave -> gate LDS exchange -> GRU (8 cells/thr)
// -> one 16B frag store + Hrow/out stores -> 8-block barrier w/ Q prefetch.
// =====================================================================
#define LOADQ(tt) do { \
  _Pragma("unroll") \
  for (int g = 0; g < 3; ++g) { \
    const float* qp = Qr + (((((size_t)(tt) * 8 + dd) * 3 + g) * 4 + w) * 64 + l) * 8; \
    float4 qa = CF4(qp); float4 qb = CF4(qp + 4); \
    qv[g][0] = qa.x; qv[g][1] = qa.y; qv[g][2] = qa.z; qv[g][3] = qa.w; \
    qv[g][4] = qb.x; qv[g][5] = qb.y; qv[g][6] = qb.z; qv[g][7] = qb.w; \
  } } while (0)

__global__ __launch_bounds__(256, 1) void rssm_recur3(
    const unsigned short* __restrict__ Wr, const float* __restrict__ Qr,
    const float* __restrict__ bhh_n, unsigned short* __restrict__ hist,
    unsigned short* __restrict__ Hrow, float* __restrict__ outp,
    unsigned int* __restrict__ counter)
{
  const int dd = blockIdx.x;          // 0..7
  const int tid = threadIdx.x;
  const int w = tid >> 6, l = tid & 63;
  __shared__ float G[12][16][66];     // ~50KB gate exchange

  // persistent B-frags: 3 row-tiles x 8 kt
  short8 Bf[3][8];
  {
    const unsigned short* wb = Wr + ((size_t)(dd * 12 + w * 3) * 8) * 512 + l * 8;
    #pragma unroll
    for (int ri = 0; ri < 3; ++ri)
      #pragma unroll
      for (int kt = 0; kt < 8; ++kt)
        Bf[ri][kt] = *(const short8*)(wb + (size_t)(ri * 8 + kt) * 512);
  }
  float bhn[8];
  #pragma unroll
  for (int j = 0; j < 8; ++j) bhn[j] = bhh_n[dd * 32 + ((l >> 4) << 3) + j];

  const int bg = w * 16 + (l & 15);       // GRU batch row
  const int dhalf = l >> 5;               // 0..1
  const int d16b = ((l >> 4) & 1) << 3;   // 0 or 8
  float qv[3][8];
  LOADQ(0);

  unsigned int target = 0;
  #pragma unroll 1
  for (int t = 0; t < 128; ++t) {
    const unsigned short* hb = hist + (size_t)(t & 1) * 16384;
    // A-frags (all 4 b-tiles) + own h_old frag
    short8 a[4][8];
    #pragma unroll
    for (int bt = 0; bt < 4; ++bt)
      #pragma unroll
      for (int kt = 0; kt < 8; ++kt)
        a[bt][kt] = *(const short8*)(hb + (size_t)((bt * 8 + kt) * 64 + l) * 8);
    short8 ha = *(const short8*)(hb + (size_t)((w * 8 + dd) * 64 + l) * 8);

    f32x4 acc[4][3];
    #pragma unroll
    for (int bt = 0; bt < 4; ++bt)
      #pragma unroll
      for (int ri = 0; ri < 3; ++ri) acc[bt][ri] = (f32x4){0.f, 0.f, 0.f, 0.f};
    #pragma unroll
    for (int kt = 0; kt < 8; ++kt)
      #pragma unroll
      for (int bt = 0; bt < 4; ++bt)
        #pragma unroll
        for (int ri = 0; ri < 3; ++ri)
          acc[bt][ri] = __builtin_amdgcn_mfma_f32_16x16x32_bf16(
              a[bt][kt], Bf[ri][kt], acc[bt][ri], 0, 0, 0);

    // gate exchange
    #pragma unroll
    for (int bt = 0; bt < 4; ++bt)
      #pragma unroll
      for (int ri = 0; ri < 3; ++ri)
        #pragma unroll
        for (int qq = 0; qq < 4; ++qq)
          G[w * 3 + ri][l & 15][bt * 16 + ((l >> 4) << 2) + qq] = acc[bt][ri][qq];
    __syncthreads();

    // GRU: 8 cells (b = bg, d = dd*32 + (l>>4)*8 + j)
    const float m1s = (t == 0) ? 0.f : 1.f;
    unsigned short hn8[8];
    float hf8[8];
    #pragma unroll
    for (int j = 0; j < 8; ++j) {
      int d16 = d16b + j;
      float m1r = G[0 + dhalf][d16][bg];
      float m1z = G[2 + dhalf][d16][bg];
      float m1n = G[4 + dhalf][d16][bg];
      float ghr = G[6 + dhalf][d16][bg];
      float ghz = G[8 + dhalf][d16][bg];
      float ghn = G[10 + dhalf][d16][bg] + bhn[j];
      float gir = fmaf(m1r, m1s, qv[0][j]);
      float giz = fmaf(m1z, m1s, qv[1][j]);
      float gin = fmaf(m1n, m1s, qv[2][j]);
      float r = 1.f / (1.f + expf(-(gir + ghr)));
      float z = 1.f / (1.f + expf(-(giz + ghz)));
      float nn = tanhf(gin + r * ghn);
      float hold = bf2f(((const unsigned short*)&ha)[j]);
      float hn = (1.f - z) * nn + z * hold;
      unsigned short hbv = f2bf(hn);
      hn8[j] = hbv;
      hf8[j] = bf2f(hbv);
    }

    // stores: hist frag (16B), Hrow (16B), out f32 (32B)
    short8 hv = *(const short8*)hn8;
    *(short8*)(hist + (size_t)((t + 1) & 1) * 16384
               + (size_t)((w * 8 + dd) * 64 + l) * 8) = hv;
    *(short8*)(Hrow + (size_t)(bg * 128 + t) * 256 + dd * 32 + ((l >> 4) << 3)) = hv;
    float* op = outp + (size_t)(bg * 128 + t) * 3328 + dd * 32 + ((l >> 4) << 3);
    float4 o0; o0.x = hf8[0]; o0.y = hf8[1]; o0.z = hf8[2]; o0.w = hf8[3];
    float4 o1; o1.x = hf8[4]; o1.y = hf8[5]; o1.z = hf8[6]; o1.w = hf8[7];
    F4(op) = o0; F4(op + 4) = o1;

    if (t < 127) {
      __threadfence();
      __syncthreads();
      target += 8;
      if (tid == 0)
        __hip_atomic_fetch_add(counter, 1u, __ATOMIC_ACQ_REL, __HIP_MEMORY_SCOPE_AGENT);
      LOADQ(t + 1);
      while (__hip_atomic_load(counter, __ATOMIC_ACQUIRE, __HIP_MEMORY_SCOPE_AGENT)
             < target) {
        __builtin_amdgcn_s_sleep(1);
      }
    }
  }
}

// =====================================================================
// Host side
// =====================================================================
static inline void g_bf(const unsigned short* A, int lda,
                        const unsigned short* B, int ldb,
                        void* C, int ldc, int M, int N, int K,
                        const float* bias, const float* src, int ldsrc,
                        const float* scale, int relu, int obf16, hipStream_t s,
                        const unsigned short* A2 = nullptr, int lda2 = 0,
                        int kSplit = 1 << 30,
                        const unsigned short* B2 = nullptr, int ldb2 = 0,
                        int nSplit = 1 << 30,
                        int src_c0 = 0, int qperm = 0)
{
  dim3 grid(N / 128, M / 128);
  gemm_bf<<<grid, 256, 0, s>>>(A, lda, A2, lda2, kSplit, B, ldb, B2, ldb2, nSplit,
                               C, ldc, K, bias, src, ldsrc, src_c0, scale, relu,
                               obf16, qperm);
}

extern "C" void kernel_launch(void* const* d_in, const int* in_sizes, int n_in,
                              void* d_out, int out_size, void* d_ws, size_t ws_size,
                              hipStream_t stream)
{
  (void)in_sizes; (void)n_in; (void)out_size;

  const float* emb_v = (const float*)d_in[0];
  const float* emb_t = (const float*)d_in[1];
  const float* emb_p = (const float*)d_in[2];
  const float* noise = (const float*)d_in[3];
  const float* h0    = (const float*)d_in[4];
  const float* s0    = (const float*)d_in[5];
  const float* pvw   = (const float*)d_in[6];
  const float* pvb   = (const float*)d_in[7];
  const float* ptw   = (const float*)d_in[8];
  const float* ptb   = (const float*)d_in[9];
  const float* ppw   = (const float*)d_in[10];
  const float* ppb   = (const float*)d_in[11];
  const float* aiw   = (const float*)d_in[12];
  const float* aib   = (const float*)d_in[13];
  const float* aow   = (const float*)d_in[14];
  const float* aob   = (const float*)d_in[15];
  const float* importance = (const float*)d_in[16];
  const float* fw1   = (const float*)d_in[17];
  const float* fb1   = (const float*)d_in[18];
  const float* fw2   = (const float*)d_in[19];
  const float* fb2   = (const float*)d_in[20];
  const float* ln_g  = (const float*)d_in[21];
  const float* ln_b  = (const float*)d_in[22];
  const float* gwih  = (const float*)d_in[23];
  const float* gwhh  = (const float*)d_in[24];
  const float* gbih  = (const float*)d_in[25];
  const float* gbhh  = (const float*)d_in[26];
  const float* prw   = (const float*)d_in[27];
  const float* prb   = (const float*)d_in[28];
  const float* pow_  = (const float*)d_in[29];
  const float* pob   = (const float*)d_in[30];

  float* out = (float*)d_out;
  char* W = (char*)d_ws;

  size_t off = 0;
  auto alloc = [&](size_t bytes) { off = (off + 63) & ~63ull; size_t o = off; off += bytes; return o; };
  const size_t o_cnt    = alloc(256);
  const size_t o_imp    = alloc(16);
  const size_t o_rep    = alloc(3072 * 4);
  const size_t o_bqkv   = alloc(9216 * 4);
  const size_t o_bf1    = alloc(1024 * 4);
  const size_t o_cb768  = alloc(768 * 4);
  const size_t o_cb2048 = alloc(2048 * 4);
  const size_t o_gwihb  = alloc(768ull * 2048 * 2);
  const size_t o_whhb   = alloc(768ull * 256 * 2);
  const size_t o_m1b    = alloc(768ull * 256 * 2);
  const size_t o_prwb   = alloc(1024ull * 256 * 2);
  const size_t o_powb   = alloc(1024ull * 1280 * 2);
  const size_t o_wr     = alloc(393216ull * 2);
  const size_t o_hist   = alloc(2ull * 16384 * 2);
  const size_t o_hrow   = alloc(8192ull * 256 * 2);
  const size_t o_fusedb = alloc(8192ull * 1024 * 2);
  const size_t o_fpb    = alloc(8192ull * 1024 * 4);
  const size_t o_rbf    = alloc(8192ull * 1024 * 2);
  const size_t o_embvb  = alloc(8192ull * 512 * 2);
  const size_t o_embtb  = alloc(8192ull * 512 * 2);
  const size_t o_embpb  = alloc(8192ull * 256 * 2);
  const size_t o_wqv    = alloc(3072ull * 512 * 2);
  const size_t o_wqt    = alloc(3072ull * 512 * 2);
  const size_t o_wqp    = alloc(3072ull * 256 * 2);
  const size_t o_wf1    = alloc(1024ull * 3072 * 2);
  const size_t o_fw2b   = alloc(1024ull * 1024 * 2);
  const size_t o_fused1 = alloc(8192ull * 1024 * 2);
  const size_t o_sub    = (off + 63) & ~63ull;

  // sub-pool (time-shared): prep temps -> per-chunk qkv/att -> Qr
  const size_t so_aiwb = 0;
  const size_t so_fw1b = so_aiwb + 3072ull * 1024 * 2;
  const size_t so_pTv  = so_fw1b + 1024ull * 3072 * 2;
  const size_t so_pTt  = so_pTv + 512ull * 1024 * 2;
  const size_t so_pTp  = so_pTt + 512ull * 1024 * 2;
  const size_t so_aoT  = so_pTp + 256ull * 1024 * 2;
  const size_t so_WphT = so_aoT + 1024ull * 1024 * 2;
  const size_t prep_bytes = so_WphT + 256ull * 1024 * 2;
  const size_t q_bytes = 8192ull * 768 * 4;

  int NC = 512;
  for (int cand : {8192, 4096, 2048, 1024}) {
    size_t sub = prep_bytes > q_bytes ? prep_bytes : q_bytes;
    size_t cb = (size_t)cand * 9216 * 2 + (size_t)cand * 3072 * 2;
    if (cb > sub) sub = cb;
    if (o_sub + sub <= ws_size) { NC = cand; break; }
  }
  const size_t o_qkvc = o_sub;
  const size_t o_attc = o_sub + (size_t)NC * 9216 * 2;
  const size_t o_qr   = o_sub;

  auto FP = [&](size_t o) { return (float*)(W + o); };
  auto UP = [&](size_t o) { return (unsigned short*)(W + o); };

  hipMemsetAsync(W + o_cnt, 0, 256, stream);
  imp_rep_k<<<1, 256, 0, stream>>>(importance, aob, FP(o_imp), FP(o_rep));
  bias_prep<<<8, 256, 0, stream>>>(gbih, gbhh, prb, FP(o_cb768), FP(o_cb2048));

  auto cvt = [&](const float* in, unsigned short* op, size_t n) {
    int n4 = (int)(n / 4);
    cvt_bf<<<(n4 + 255) / 256, 256, 0, stream>>>(in, op, n4);
  };
  cvt(aiw,  UP(o_sub + so_aiwb), 3072ull * 1024);
  cvt(fw1,  UP(o_sub + so_fw1b), 1024ull * 3072);
  cvt(fw2,  UP(o_fw2b), 1024ull * 1024);
  cvt(gwih, UP(o_gwihb), 768ull * 2048);
  cvt(gwhh, UP(o_whhb), 768ull * 256);
  cvt(prw,  UP(o_prwb), 1024ull * 256);
  cvt(pow_, UP(o_powb), 1024ull * 1280);
  cvt(emb_v, UP(o_embvb), 8192ull * 512);
  cvt(emb_t, UP(o_embtb), 8192ull * 512);
  cvt(emb_p, UP(o_embpb), 8192ull * 256);

  transpose_bf<<<dim3(16, 32), 256, 0, stream>>>(pvw, 512, UP(o_sub + so_pTv), 1024);
  transpose_bf<<<dim3(16, 32), 256, 0, stream>>>(ptw, 512, UP(o_sub + so_pTt), 1024);
  transpose_bf<<<dim3(8, 32), 256, 0, stream>>>(ppw, 256, UP(o_sub + so_pTp), 1024);
  transpose_bf<<<dim3(32, 32), 256, 0, stream>>>(aow, 1024, UP(o_sub + so_aoT), 1024);
  transpose_bf<<<dim3(8, 32), 256, 0, stream>>>(pow_, 1280, UP(o_sub + so_WphT), 1024);

  matvec3<<<3072, 64, 0, stream>>>(aiw, pvb, ptb, ppb, aib, FP(o_bqkv));
  matvec_nt<<<1024, 64, 0, stream>>>(fw1, 3072, FP(o_rep), fb1, FP(o_bf1), 3072);

  // folded weights
  g_bf(UP(o_sub + so_aiwb), 1024, UP(o_sub + so_pTv), 1024, UP(o_wqv), 512,
       3072, 512, 1024, nullptr, nullptr, 0, nullptr, 0, 1, stream);
  g_bf(UP(o_sub + so_aiwb), 1024, UP(o_sub + so_pTt), 1024, UP(o_wqt), 512,
       3072, 512, 1024, nullptr, nullptr, 0, nullptr, 0, 1, stream);
  g_bf(UP(o_sub + so_aiwb), 1024, UP(o_sub + so_pTp), 1024, UP(o_wqp), 256,
       3072, 256, 1024, nullptr, nullptr, 0, nullptr, 0, 1, stream);
  for (int m = 0; m < 3; ++m)
    g_bf(UP(o_sub + so_fw1b) + m * 1024, 3072, UP(o_sub + so_aoT), 1024,
         UP(o_wf1) + m * 1024, 3072, 1024, 1024, 1024,
         nullptr, nullptr, 0, FP(o_imp) + m, 0, 1, stream);
  g_bf(UP(o_gwihb), 2048, UP(o_sub + so_WphT), 1024, UP(o_m1b), 256,
       768, 256, 1024, nullptr, nullptr, 0, nullptr, 0, 1, stream);

  wr_prep<<<1536, 256, 0, stream>>>(UP(o_m1b), UP(o_whhb), UP(o_wr));
  h0_prep<<<64, 256, 0, stream>>>(h0, UP(o_hist));

  // phase A: qkv (bf16) -> attention -> fused1
  const int nchunk = 8192 / NC;
  for (int c = 0; c < nchunk; ++c) {
    g_bf(UP(o_embvb) + (size_t)c * NC * 512, 512, UP(o_wqv), 512,
         UP(o_qkvc) + 0, 9216, NC, 3072, 512, FP(o_bqkv) + 0,
         nullptr, 0, nullptr, 0, 1, stream);
    g_bf(UP(o_embtb) + (size_t)c * NC * 512, 512, UP(o_wqt), 512,
         UP(o_qkvc) + 3072, 9216, NC, 3072, 512, FP(o_bqkv) + 3072,
         nullptr, 0, nullptr, 0, 1, stream);
    g_bf(UP(o_embpb) + (size_t)c * NC * 256, 256, UP(o_wqp), 256,
         UP(o_qkvc) + 6144, 9216, NC, 3072, 256, FP(o_bqkv) + 6144,
         nullptr, 0, nullptr, 0, 1, stream);
    attn3<<<NC, 256, 0, stream>>>(UP(o_qkvc), UP(o_attc));
    g_bf(UP(o_attc), 3072, UP(o_wf1), 3072,
         UP(o_fused1) + (size_t)c * NC * 1024, 1024, NC, 1024, 3072,
         FP(o_bf1), nullptr, 0, nullptr, 1 /*relu*/, 1, stream);
  }

  g_bf(UP(o_fused1), 1024, UP(o_fw2b), 1024, UP(o_fusedb), 1024,
       8192, 1024, 1024, fb2, nullptr, 0, nullptr, 0, 1, stream);
  layernorm_bf<<<8192, 256, 0, stream>>>(UP(o_fusedb), ln_g, ln_b);

  g_bf(UP(o_fusedb), 1024, UP(o_powb) + 256, 1280, FP(o_fpb), 1024,
       8192, 1024, 1024, pob, nullptr, 0, nullptr, 0, 0, stream);
  build_R_bf<<<8192, 256, 0, stream>>>(FP(o_fpb), noise, s0, UP(o_rbf));
  // Qr = [R | fused] @ gwih^T + (gbih + bhh_rz), written in frag-perm order
  g_bf(UP(o_rbf), 1024, UP(o_gwihb), 2048, FP(o_qr), 768,
       8192, 768, 2048, FP(o_cb768), nullptr, 0, nullptr, 0, 0, stream,
       UP(o_fusedb), 1024, 1024, nullptr, 0, 1 << 30, 0, 1 /*qperm*/);

  rssm_recur3<<<8, 256, 0, stream>>>(UP(o_wr), FP(o_qr), gbhh + 512, UP(o_hist),
                                     UP(o_hrow), out, (unsigned int*)(W + o_cnt));

  // prior | post in one dual-B GEMM (out cols 1280..3327)
  g_bf(UP(o_hrow), 256, UP(o_prwb), 256, out + 1280, 3328,
       8192, 2048, 256, FP(o_cb2048), FP(o_fpb), 1024, nullptr, 0, 0, stream,
       nullptr, 0, 1 << 30, UP(o_powb), 1280, 1024, 1024 /*src_c0*/, 0);
  s_out_k<<<8192, 256, 0, stream>>>(out, noise);
}

// Round 4
// 1782.094 us; speedup vs baseline: 1.2189x; 1.2189x over previous
//
#include <hip/hip_runtime.h>
#include <cstdint>
#include <cstddef>

#define F4(p)  (*(reinterpret_cast<float4*>(p)))
#define CF4(p) (*(reinterpret_cast<const float4*>(p)))

typedef __attribute__((ext_vector_type(8))) short short8;
typedef __attribute__((ext_vector_type(4))) float f32x4;

__device__ __forceinline__ float bf2f(unsigned short h) {
  return __uint_as_float(((unsigned int)h) << 16);
}
__device__ __forceinline__ unsigned short f2bf(float x) {
  unsigned int u = __float_as_uint(x);
  return (unsigned short)((u + 0x7FFFu + ((u >> 16) & 1u)) >> 16);
}

#if __has_builtin(__builtin_amdgcn_global_load_lds)
#define USE_GLL 1
#else
#define USE_GLL 0
#endif

__device__ __forceinline__ void stage16(unsigned short* lds_lane,
                                        unsigned short* lds_wavebase,
                                        const unsigned short* g) {
#if USE_GLL
  __builtin_amdgcn_global_load_lds(
      (const __attribute__((address_space(1))) unsigned int*)g,
      (__attribute__((address_space(3))) unsigned int*)lds_wavebase, 16, 0, 0);
#else
  *(short8*)lds_lane = *(const short8*)g;
#endif
}

// =====================================================================
// bf16 MFMA GEMM: C = post( scale*(A@B^T) + bias + src )
// dual-A (k-split) and dual-B (n-split) supported. 128x128 tile, BK=64,
// 4 waves 2x2, XOR-swizzled LDS via pre-swizzled global source.
// qperm: write f32 C in the recurrence's Qr fragment order.
// src_c0: src added only for gc>=src_c0, at column (gc-src_c0).
// =====================================================================
__global__ __launch_bounds__(256) void gemm_bf(
    const unsigned short* __restrict__ A, int lda,
    const unsigned short* __restrict__ A2, int lda2, int kSplit,
    const unsigned short* __restrict__ B, int ldb,
    const unsigned short* __restrict__ B2, int ldb2, int nSplit,
    void* __restrict__ Cv, int ldc, int K,
    const float* __restrict__ bias,
    const float* __restrict__ src, int ldsrc, int src_c0,
    const float* __restrict__ scale_ptr, int relu, int obf16, int qperm)
{
  __shared__ unsigned short As[128 * 64];
  __shared__ unsigned short Bs[128 * 64];
  const int tid = threadIdx.x;
  const int wv = tid >> 6, ln = tid & 63;
  const int wm = wv >> 1, wn = wv & 1;
  const size_t gm0 = (size_t)blockIdx.y * 128;
  const size_t gn0 = (size_t)blockIdx.x * 128;

  f32x4 acc[4][4];
  #pragma unroll
  for (int i = 0; i < 4; ++i)
    #pragma unroll
    for (int j = 0; j < 4; ++j) acc[i][j] = (f32x4){0.f, 0.f, 0.f, 0.f};

  for (int kk = 0; kk < K; kk += 64) {
    const unsigned short* Ause = A; int lduse = lda; int kkA = kk;
    if (A2 != nullptr && kk >= kSplit) { Ause = A2; lduse = lda2; kkA = kk - kSplit; }
    #pragma unroll
    for (int j = 0; j < 4; ++j) {
      int idx = j * 256 + tid;
      int r = idx >> 3, u = idx & 7;
      int ksw = (u ^ (r & 7)) << 3;
      const unsigned short* ga = Ause + (gm0 + r) * lduse + kkA + ksw;
      stage16(&As[idx * 8], &As[(idx & ~63) * 8], ga);
      size_t nr = gn0 + r;
      const unsigned short* gb = (nr < (size_t)nSplit)
          ? B + nr * ldb + kk + ksw
          : B2 + (nr - nSplit) * ldb2 + kk + ksw;
      stage16(&Bs[idx * 8], &Bs[(idx & ~63) * 8], gb);
    }
    __syncthreads();
    #pragma unroll
    for (int ks = 0; ks < 2; ++ks) {
      short8 af[4], bfv[4];
      #pragma unroll
      for (int mi = 0; mi < 4; ++mi) {
        int r = wm * 64 + mi * 16 + (ln & 15);
        int u = (ks * 4 + (ln >> 4)) ^ (r & 7);
        af[mi] = *(const short8*)&As[(r * 8 + u) * 8];
      }
      #pragma unroll
      for (int nj = 0; nj < 4; ++nj) {
        int r = wn * 64 + nj * 16 + (ln & 15);
        int u = (ks * 4 + (ln >> 4)) ^ (r & 7);
        bfv[nj] = *(const short8*)&Bs[(r * 8 + u) * 8];
      }
      #pragma unroll
      for (int mi = 0; mi < 4; ++mi)
        #pragma unroll
        for (int nj = 0; nj < 4; ++nj)
          acc[mi][nj] = __builtin_amdgcn_mfma_f32_16x16x32_bf16(
              af[mi], bfv[nj], acc[mi][nj], 0, 0, 0);
    }
    __syncthreads();
  }

  float sc = scale_ptr ? *scale_ptr : 1.0f;
  #pragma unroll
  for (int nj = 0; nj < 4; ++nj) {
    int gc = (int)gn0 + wn * 64 + nj * 16 + (ln & 15);
    float bv = bias ? bias[gc] : 0.f;
    #pragma unroll
    for (int mi = 0; mi < 4; ++mi) {
      #pragma unroll
      for (int qq = 0; qq < 4; ++qq) {
        int gr = (int)gm0 + wm * 64 + mi * 16 + ((ln >> 4) << 2) + qq;
        float v = acc[mi][nj][qq] * sc + bv;
        if (src && gc >= src_c0) v += src[(size_t)gr * ldsrc + (gc - src_c0)];
        if (relu) v = fmaxf(v, 0.f);
        if (qperm) {
          int t = gr & 127, bq = gr >> 7;
          int g = gc >> 8, d = gc & 255;
          int ddq = d >> 5, doff = d & 31;
          int wq = bq >> 4;
          int lq = (bq & 15) + ((doff >> 3) << 4);
          size_t qi = (((((size_t)t * 8 + ddq) * 3 + g) * 4 + wq) * 64 + lq) * 8
                      + (doff & 7);
          ((float*)Cv)[qi] = v;
        } else if (obf16) {
          ((unsigned short*)Cv)[(size_t)gr * ldc + gc] = f2bf(v);
        } else {
          ((float*)Cv)[(size_t)gr * ldc + gc] = v;
        }
      }
    }
  }
}

// =====================================================================
__global__ __launch_bounds__(256) void cvt_bf(
    const float* __restrict__ in, unsigned short* __restrict__ outp, int n4)
{
  int i = blockIdx.x * 256 + threadIdx.x;
  if (i < n4) {
    float4 v = CF4(in + (size_t)i * 4);
    ushort4 o;
    o.x = f2bf(v.x); o.y = f2bf(v.y); o.z = f2bf(v.z); o.w = f2bf(v.w);
    *(ushort4*)(outp + (size_t)i * 4) = o;
  }
}

__global__ __launch_bounds__(256) void transpose_bf(
    const float* __restrict__ in, int ldin, unsigned short* __restrict__ outp, int R)
{
  __shared__ float tile[32][33];
  int c0 = blockIdx.x * 32, r0 = blockIdx.y * 32;
  int tx = threadIdx.x & 31, ty = threadIdx.x >> 5;
  #pragma unroll
  for (int i = ty; i < 32; i += 8)
    tile[i][tx] = in[(size_t)(r0 + i) * ldin + c0 + tx];
  __syncthreads();
  #pragma unroll
  for (int i = ty; i < 32; i += 8)
    outp[(size_t)(c0 + i) * R + r0 + tx] = f2bf(tile[tx][i]);
}

// out3[m*3072+i] = dot(A[i], x_m) + aib[i],  m=0..2 (A row read once)
__global__ __launch_bounds__(64) void matvec3(
    const float* __restrict__ A,
    const float* __restrict__ x0, const float* __restrict__ x1,
    const float* __restrict__ x2, const float* __restrict__ aib,
    float* __restrict__ outp)
{
  int i = blockIdx.x, t = threadIdx.x;
  const float* Ar = A + (size_t)i * 1024;
  float s0 = 0.f, s1 = 0.f, s2 = 0.f;
  for (int k = t * 4; k < 1024; k += 256) {
    float4 a = CF4(Ar + k);
    float4 v0 = CF4(x0 + k), v1 = CF4(x1 + k), v2 = CF4(x2 + k);
    s0 += a.x*v0.x + a.y*v0.y + a.z*v0.z + a.w*v0.w;
    s1 += a.x*v1.x + a.y*v1.y + a.z*v1.z + a.w*v1.w;
    s2 += a.x*v2.x + a.y*v2.y + a.z*v2.z + a.w*v2.w;
  }
  #pragma unroll
  for (int m = 32; m > 0; m >>= 1) {
    s0 += __shfl_xor(s0, m); s1 += __shfl_xor(s1, m); s2 += __shfl_xor(s2, m);
  }
  if (t == 0) {
    float b = aib[i];
    outp[i] = s0 + b; outp[3072 + i] = s1 + b; outp[6144 + i] = s2 + b;
  }
}

__global__ __launch_bounds__(64) void matvec_nt(
    const float* __restrict__ A, int lda,
    const float* __restrict__ x, const float* __restrict__ badd,
    float* __restrict__ outp, int K)
{
  int i = blockIdx.x, t = threadIdx.x;
  const float* Ar = A + (size_t)i * lda;
  float s = 0.f;
  for (int k = t * 4; k < K; k += 256) {
    float4 a = CF4(Ar + k);
    float4 xx = CF4(x + k);
    s += a.x*xx.x + a.y*xx.y + a.z*xx.z + a.w*xx.w;
  }
  #pragma unroll
  for (int m = 32; m > 0; m >>= 1) s += __shfl_xor(s, m);
  if (t == 0) outp[i] = s + (badd ? badd[i] : 0.f);
}

__global__ __launch_bounds__(256) void imp_rep_k(
    const float* __restrict__ importance, const float* __restrict__ aob,
    float* __restrict__ imp, float* __restrict__ rep)
{
  __shared__ float si[3];
  if (threadIdx.x == 0) {
    float a = importance[0], b = importance[1], c = importance[2];
    float mx = fmaxf(a, fmaxf(b, c));
    float ea = expf(a - mx), eb = expf(b - mx), ec = expf(c - mx);
    float inv = 1.f / (ea + eb + ec);
    si[0] = ea * inv; si[1] = eb * inv; si[2] = ec * inv;
    imp[0] = si[0]; imp[1] = si[1]; imp[2] = si[2];
  }
  __syncthreads();
  for (int idx = threadIdx.x; idx < 3072; idx += 256)
    rep[idx] = si[idx >> 10] * aob[idx & 1023];
}

// cb768 = gbih + [gbhh_r | gbhh_z | 0] ; cb2048 = [prb | 0]
__global__ __launch_bounds__(256) void bias_prep(
    const float* __restrict__ gbih, const float* __restrict__ gbhh,
    const float* __restrict__ prb, float* __restrict__ cb768,
    float* __restrict__ cb2048)
{
  int i = blockIdx.x * 256 + threadIdx.x;
  if (i < 768) cb768[i] = gbih[i] + (i < 512 ? gbhh[i] : 0.f);
  if (i < 2048) cb2048[i] = (i < 1024) ? prb[i] : 0.f;
}

// =====================================================================
// 3-token MHA, bf16 in -> bf16 out
// =====================================================================
__global__ __launch_bounds__(256) void attn3(
    const unsigned short* __restrict__ qkv, unsigned short* __restrict__ att)
{
  const int n = blockIdx.x;
  const unsigned short* row = qkv + (size_t)n * 9216;
  __shared__ float qk[6144];
  __shared__ float sc[72];
  __shared__ float pw[72];
  const int t = threadIdx.x;
  for (int idx = t; idx < 768; idx += 256) {
    int m = idx >> 7;                  // 0..5
    int off = (idx & 127) << 3;
    const unsigned short* srcp = (m < 3) ? (row + m * 3072 + off)
                                         : (row + (m - 3) * 3072 + 1024 + off);
    short8 v = *(const short8*)srcp;
    float* dst = &qk[m * 1024 + off];
    #pragma unroll
    for (int j = 0; j < 8; ++j) dst[j] = bf2f(((const unsigned short*)&v)[j]);
  }
  __syncthreads();
  if (t < 72) {
    int h = t / 9, i = (t % 9) / 3, j = t % 3;
    const float* qp = &qk[i * 1024 + h * 128];
    const float* kp = &qk[3072 + j * 1024 + h * 128];
    float s = 0.f;
    int rot = (t & 31) * 4;
    for (int d2 = 0; d2 < 128; ++d2) {
      int dx = (d2 + rot) & 127;
      s += qp[dx] * kp[dx];
    }
    sc[t] = s * 0.08838834764831845f;
  }
  __syncthreads();
  if (t < 24) {
    int base = t * 3;
    float a = sc[base], b = sc[base + 1], c = sc[base + 2];
    float mx = fmaxf(a, fmaxf(b, c));
    float ea = expf(a - mx), eb = expf(b - mx), ec = expf(c - mx);
    float inv = 1.f / (ea + eb + ec);
    pw[base] = ea * inv; pw[base + 1] = eb * inv; pw[base + 2] = ec * inv;
  }
  __syncthreads();
  unsigned short* outp = att + (size_t)n * 3072;
  #pragma unroll
  for (int rep = 0; rep < 3; ++rep) {
    int idx = (rep * 256 + t) << 2;
    int i = idx >> 10;
    int hd = idx & 1023;
    int h = hd >> 7;
    int pb = (h * 3 + i) * 3;
    float w0 = pw[pb], w1 = pw[pb + 1], w2 = pw[pb + 2];
    ushort4 v0 = *(const ushort4*)(row + 2048 + hd);
    ushort4 v1 = *(const ushort4*)(row + 3072 + 2048 + hd);
    ushort4 v2 = *(const ushort4*)(row + 6144 + 2048 + hd);
    ushort4 o;
    o.x = f2bf(w0 * bf2f(v0.x) + w1 * bf2f(v1.x) + w2 * bf2f(v2.x));
    o.y = f2bf(w0 * bf2f(v0.y) + w1 * bf2f(v1.y) + w2 * bf2f(v2.y));
    o.z = f2bf(w0 * bf2f(v0.z) + w1 * bf2f(v1.z) + w2 * bf2f(v2.z));
    o.w = f2bf(w0 * bf2f(v0.w) + w1 * bf2f(v1.w) + w2 * bf2f(v2.w));
    *(ushort4*)(outp + idx) = o;
  }
}

// =====================================================================
__global__ __launch_bounds__(256) void layernorm_bf(
    unsigned short* __restrict__ X, const float* __restrict__ g,
    const float* __restrict__ bta)
{
  int n = blockIdx.x, t = threadIdx.x;
  unsigned short* row = X + (size_t)n * 1024;
  ushort4 hv = *(ushort4*)(row + t * 4);
  float x0 = bf2f(hv.x), x1 = bf2f(hv.y), x2 = bf2f(hv.z), x3 = bf2f(hv.w);
  float s = x0 + x1 + x2 + x3;
  float ss = x0*x0 + x1*x1 + x2*x2 + x3*x3;
  #pragma unroll
  for (int m = 32; m > 0; m >>= 1) { s += __shfl_xor(s, m); ss += __shfl_xor(ss, m); }
  __shared__ float rs[4], rss[4];
  int w = t >> 6;
  if ((t & 63) == 0) { rs[w] = s; rss[w] = ss; }
  __syncthreads();
  s = rs[0] + rs[1] + rs[2] + rs[3];
  ss = rss[0] + rss[1] + rss[2] + rss[3];
  float mean = s * (1.0f / 1024.0f);
  float var = ss * (1.0f / 1024.0f) - mean * mean;
  float inv = 1.0f / sqrtf(var + 1e-5f);
  float4 gg = CF4(g + t * 4);
  float4 bb = CF4(bta + t * 4);
  ushort4 o;
  o.x = f2bf((x0 - mean) * inv * gg.x + bb.x);
  o.y = f2bf((x1 - mean) * inv * gg.y + bb.y);
  o.z = f2bf((x2 - mean) * inv * gg.z + bb.z);
  o.w = f2bf((x3 - mean) * inv * gg.w + bb.w);
  *(ushort4*)(row + t * 4) = o;
}

__global__ __launch_bounds__(256) void build_R_bf(
    const float* __restrict__ Fpb, const float* __restrict__ noise,
    const float* __restrict__ s0, unsigned short* __restrict__ R)
{
  size_t idx = (size_t)blockIdx.x * 256 + threadIdx.x;
  int n = (int)(idx >> 8);
  int k4 = (int)(idx & 255) << 2;
  float4 v;
  if ((n & 127) == 0) {
    v = CF4(s0 + (size_t)(n >> 7) * 1024 + k4);
  } else {
    float4 f = CF4(Fpb + (size_t)(n - 1) * 1024 + k4);
    float4 z = CF4(noise + (size_t)(n - 1) * 1024 + k4);
    v.x = f.x + z.x; v.y = f.y + z.y; v.z = f.z + z.z; v.w = f.w + z.w;
  }
  ushort4 o;
  o.x = f2bf(v.x); o.y = f2bf(v.y); o.z = f2bf(v.z); o.w = f2bf(v.w);
  *(ushort4*)(R + (size_t)n * 1024 + k4) = o;
}

__global__ __launch_bounds__(256) void s_out_k(
    float* __restrict__ outp, const float* __restrict__ noise)
{
  size_t idx = (size_t)blockIdx.x * 256 + threadIdx.x;
  int n = (int)(idx >> 8);
  int j4 = (int)(idx & 255) << 2;
  float4 p = CF4(outp + (size_t)n * 3328 + 2304 + j4);
  float4 z = CF4(noise + (size_t)n * 1024 + j4);
  float4 o; o.x = p.x + z.x; o.y = p.y + z.y; o.z = p.z + z.z; o.w = p.w + z.w;
  F4(outp + (size_t)n * 3328 + 256 + j4) = o;
}

// =====================================================================
// Recurrence weight prep: 8 blocks x 12 row-tiles of 16 rows, B-frag order.
// =====================================================================
__global__ __launch_bounds__(256) void wr_prep(
    const unsigned short* __restrict__ M1bf, const unsigned short* __restrict__ Whhbf,
    unsigned short* __restrict__ Wr)
{
  int idx = blockIdx.x * 256 + threadIdx.x;   // < 393216
  int j = idx & 7, l = (idx >> 3) & 63, kt = (idx >> 9) & 7;
  int rest = idx >> 12;                        // dd*12 + r
  int r = rest % 12, dd = rest / 12;
  int g = r >> 1, dhalf = r & 1;
  int d = dd * 32 + dhalf * 16 + (l & 15);
  int srow = (g % 3) * 256 + d;
  int k = kt * 32 + ((l >> 4) << 3) + j;
  const unsigned short* srcp = (g < 3) ? M1bf : Whhbf;
  Wr[idx] = srcp[(size_t)srow * 256 + k];
}

// hist frag layout: [buf][w'][kt][l][j], b=16w'+(l&15), k=kt*32+(l>>4)*8+j
__global__ __launch_bounds__(256) void h0_prep(
    const float* __restrict__ h0, unsigned short* __restrict__ hist)
{
  int idx = blockIdx.x * 256 + threadIdx.x;   // < 16384
  int j = idx & 7, l = (idx >> 3) & 63, kt = (idx >> 9) & 7, w = idx >> 12;
  int b = 16 * w + (l & 15);
  int k = kt * 32 + ((l >> 4) << 3) + j;
  hist[idx] = f2bf(h0[(size_t)b * 256 + k]);
}

// =====================================================================
// Sequential RSSM v4. 8 blocks (32 d-cols each), 256 thr = 4 waves.
// Weights register-resident (24 B-frags/wave, loaded once). Per step:
//   stage hist (32KB) -> LDS via global_load_lds (coalesced, 1x per block)
//   -> ds_read A-frags + 96 MFMA/wave -> gate LDS exchange -> GRU
//   -> 16B frag store + Hrow/out stores -> single-thread-poll barrier
//   (Q for t+1 prefetched before the fence).
// =====================================================================
#define LOADQ(tt) do { \
  _Pragma("unroll") \
  for (int g = 0; g < 3; ++g) { \
    const float* qp = Qr + (((((size_t)(tt) * 8 + dd) * 3 + g) * 4 + w) * 64 + l) * 8; \
    float4 qa = CF4(qp); float4 qb = CF4(qp + 4); \
    qv[g][0] = qa.x; qv[g][1] = qa.y; qv[g][2] = qa.z; qv[g][3] = qa.w; \
    qv[g][4] = qb.x; qv[g][5] = qb.y; qv[g][6] = qb.z; qv[g][7] = qb.w; \
  } } while (0)

__global__ __launch_bounds__(256, 1) void rssm_recur4(
    const unsigned short* __restrict__ Wr, const float* __restrict__ Qr,
    const float* __restrict__ bhh_n, unsigned short* __restrict__ hist,
    unsigned short* __restrict__ Hrow, float* __restrict__ outp,
    unsigned int* __restrict__ counter)
{
  const int dd = blockIdx.x;          // 0..7
  const int tid = threadIdx.x;
  const int w = tid >> 6, l = tid & 63;
  __shared__ float G[12][16][66];            // ~50KB gate exchange
  __shared__ unsigned short hL[16384];       // 32KB staged h frags

  // persistent B-frags: 3 row-tiles x 8 kt (96 VGPR)
  short8 Bf[3][8];
  {
    const unsigned short* wb = Wr + ((size_t)(dd * 12 + w * 3) * 8) * 512 + l * 8;
    #pragma unroll
    for (int ri = 0; ri < 3; ++ri)
      #pragma unroll
      for (int kt = 0; kt < 8; ++kt)
        Bf[ri][kt] = *(const short8*)(wb + (size_t)(ri * 8 + kt) * 512);
  }
  float bhn[8];
  #pragma unroll
  for (int j = 0; j < 8; ++j) bhn[j] = bhh_n[dd * 32 + ((l >> 4) << 3) + j];

  const int bg = w * 16 + (l & 15);       // GRU batch row
  const int dhalf = l >> 5;               // 0..1
  const int d16b = ((l >> 4) & 1) << 3;   // 0 or 8
  float qv[3][8];
  LOADQ(0);

  unsigned int target = 0;
  #pragma unroll 1
  for (int t = 0; t < 128; ++t) {
    // stage hist[t&1] -> hL (one coalesced 32KB global_load_lds pass)
    const unsigned short* hsrc = hist + (size_t)(t & 1) * 16384;
    #pragma unroll
    for (int j = 0; j < 8; ++j) {
      int idx = j * 256 + tid;
      stage16(&hL[idx * 8], &hL[(idx & ~63) * 8], hsrc + (size_t)idx * 8);
    }
    __syncthreads();   // drains vmcnt: hL ready

    f32x4 acc[4][3];
    #pragma unroll
    for (int bt = 0; bt < 4; ++bt)
      #pragma unroll
      for (int ri = 0; ri < 3; ++ri) acc[bt][ri] = (f32x4){0.f, 0.f, 0.f, 0.f};
    #pragma unroll
    for (int kt = 0; kt < 8; ++kt)
      #pragma unroll
      for (int bt = 0; bt < 4; ++bt) {
        short8 a = *(const short8*)&hL[((bt * 8 + kt) * 64 + l) * 8];
        acc[bt][0] = __builtin_amdgcn_mfma_f32_16x16x32_bf16(a, Bf[0][kt], acc[bt][0], 0, 0, 0);
        acc[bt][1] = __builtin_amdgcn_mfma_f32_16x16x32_bf16(a, Bf[1][kt], acc[bt][1], 0, 0, 0);
        acc[bt][2] = __builtin_amdgcn_mfma_f32_16x16x32_bf16(a, Bf[2][kt], acc[bt][2], 0, 0, 0);
      }
    short8 ha = *(const short8*)&hL[((w * 8 + dd) * 64 + l) * 8];

    // gate exchange
    #pragma unroll
    for (int bt = 0; bt < 4; ++bt)
      #pragma unroll
      for (int ri = 0; ri < 3; ++ri)
        #pragma unroll
        for (int qq = 0; qq < 4; ++qq)
          G[w * 3 + ri][l & 15][bt * 16 + ((l >> 4) << 2) + qq] = acc[bt][ri][qq];
    __syncthreads();

    // GRU: 8 cells (b = bg, d = dd*32 + (l>>4)*8 + j)
    const float m1s = (t == 0) ? 0.f : 1.f;
    unsigned short hn8[8];
    float hf8[8];
    #pragma unroll
    for (int j = 0; j < 8; ++j) {
      int d16 = d16b + j;
      float m1r = G[0 + dhalf][d16][bg];
      float m1z = G[2 + dhalf][d16][bg];
      float m1n = G[4 + dhalf][d16][bg];
      float ghr = G[6 + dhalf][d16][bg];
      float ghz = G[8 + dhalf][d16][bg];
      float ghn = G[10 + dhalf][d16][bg] + bhn[j];
      float gir = fmaf(m1r, m1s, qv[0][j]);
      float giz = fmaf(m1z, m1s, qv[1][j]);
      float gin = fmaf(m1n, m1s, qv[2][j]);
      float r = 1.f / (1.f + expf(-(gir + ghr)));
      float z = 1.f / (1.f + expf(-(giz + ghz)));
      float nn = tanhf(gin + r * ghn);
      float hold = bf2f(((const unsigned short*)&ha)[j]);
      float hn = (1.f - z) * nn + z * hold;
      unsigned short hbv = f2bf(hn);
      hn8[j] = hbv;
      hf8[j] = bf2f(hbv);
    }

    // stores: hist frag (16B), Hrow (16B), out f32 (32B)
    short8 hv = *(const short8*)hn8;
    *(short8*)(hist + (size_t)((t + 1) & 1) * 16384
               + (size_t)((w * 8 + dd) * 64 + l) * 8) = hv;
    *(short8*)(Hrow + (size_t)(bg * 128 + t) * 256 + dd * 32 + ((l >> 4) << 3)) = hv;
    float* op = outp + (size_t)(bg * 128 + t) * 3328 + dd * 32 + ((l >> 4) << 3);
    float4 o0; o0.x = hf8[0]; o0.y = hf8[1]; o0.z = hf8[2]; o0.w = hf8[3];
    float4 o1; o1.x = hf8[4]; o1.y = hf8[5]; o1.z = hf8[6]; o1.w = hf8[7];
    F4(op) = o0; F4(op + 4) = o1;

    if (t < 127) {
      LOADQ(t + 1);        // overlap Q prefetch with fence/barrier
      __threadfence();
      __syncthreads();     // all stores in flight drained; hL reads done
      target += 8;
      if (tid == 0) {
        __hip_atomic_fetch_add(counter, 1u, __ATOMIC_ACQ_REL, __HIP_MEMORY_SCOPE_AGENT);
        while (__hip_atomic_load(counter, __ATOMIC_ACQUIRE, __HIP_MEMORY_SCOPE_AGENT)
               < target) {
          __builtin_amdgcn_s_sleep(2);
        }
      }
      __syncthreads();
      __threadfence();
    }
  }
}

// =====================================================================
// Host side
// =====================================================================
static inline void g_bf(const unsigned short* A, int lda,
                        const unsigned short* B, int ldb,
                        void* C, int ldc, int M, int N, int K,
                        const float* bias, const float* src, int ldsrc,
                        const float* scale, int relu, int obf16, hipStream_t s,
                        const unsigned short* A2 = nullptr, int lda2 = 0,
                        int kSplit = 1 << 30,
                        const unsigned short* B2 = nullptr, int ldb2 = 0,
                        int nSplit = 1 << 30,
                        int src_c0 = 0, int qperm = 0)
{
  dim3 grid(N / 128, M / 128);
  gemm_bf<<<grid, 256, 0, s>>>(A, lda, A2, lda2, kSplit, B, ldb, B2, ldb2, nSplit,
                               C, ldc, K, bias, src, ldsrc, src_c0, scale, relu,
                               obf16, qperm);
}

extern "C" void kernel_launch(void* const* d_in, const int* in_sizes, int n_in,
                              void* d_out, int out_size, void* d_ws, size_t ws_size,
                              hipStream_t stream)
{
  (void)in_sizes; (void)n_in; (void)out_size;

  const float* emb_v = (const float*)d_in[0];
  const float* emb_t = (const float*)d_in[1];
  const float* emb_p = (const float*)d_in[2];
  const float* noise = (const float*)d_in[3];
  const float* h0    = (const float*)d_in[4];
  const float* s0    = (const float*)d_in[5];
  const float* pvw   = (const float*)d_in[6];
  const float* pvb   = (const float*)d_in[7];
  const float* ptw   = (const float*)d_in[8];
  const float* ptb   = (const float*)d_in[9];
  const float* ppw   = (const float*)d_in[10];
  const float* ppb   = (const float*)d_in[11];
  const float* aiw   = (const float*)d_in[12];
  const float* aib   = (const float*)d_in[13];
  const float* aow   = (const float*)d_in[14];
  const float* aob   = (const float*)d_in[15];
  const float* importance = (const float*)d_in[16];
  const float* fw1   = (const float*)d_in[17];
  const float* fb1   = (const float*)d_in[18];
  const float* fw2   = (const float*)d_in[19];
  const float* fb2   = (const float*)d_in[20];
  const float* ln_g  = (const float*)d_in[21];
  const float* ln_b  = (const float*)d_in[22];
  const float* gwih  = (const float*)d_in[23];
  const float* gwhh  = (const float*)d_in[24];
  const float* gbih  = (const float*)d_in[25];
  const float* gbhh  = (const float*)d_in[26];
  const float* prw   = (const float*)d_in[27];
  const float* prb   = (const float*)d_in[28];
  const float* pow_  = (const float*)d_in[29];
  const float* pob   = (const float*)d_in[30];

  float* out = (float*)d_out;
  char* W = (char*)d_ws;

  size_t off = 0;
  auto alloc = [&](size_t bytes) { off = (off + 63) & ~63ull; size_t o = off; off += bytes; return o; };
  const size_t o_cnt    = alloc(256);
  const size_t o_imp    = alloc(16);
  const size_t o_rep    = alloc(3072 * 4);
  const size_t o_bqkv   = alloc(9216 * 4);
  const size_t o_bf1    = alloc(1024 * 4);
  const size_t o_cb768  = alloc(768 * 4);
  const size_t o_cb2048 = alloc(2048 * 4);
  const size_t o_gwihb  = alloc(768ull * 2048 * 2);
  const size_t o_whhb   = alloc(768ull * 256 * 2);
  const size_t o_m1b    = alloc(768ull * 256 * 2);
  const size_t o_prwb   = alloc(1024ull * 256 * 2);
  const size_t o_powb   = alloc(1024ull * 1280 * 2);
  const size_t o_wr     = alloc(393216ull * 2);
  const size_t o_hist   = alloc(2ull * 16384 * 2);
  const size_t o_hrow   = alloc(8192ull * 256 * 2);
  const size_t o_fusedb = alloc(8192ull * 1024 * 2);
  const size_t o_fpb    = alloc(8192ull * 1024 * 4);
  const size_t o_rbf    = alloc(8192ull * 1024 * 2);
  const size_t o_embvb  = alloc(8192ull * 512 * 2);
  const size_t o_embtb  = alloc(8192ull * 512 * 2);
  const size_t o_embpb  = alloc(8192ull * 256 * 2);
  const size_t o_wqv    = alloc(3072ull * 512 * 2);
  const size_t o_wqt    = alloc(3072ull * 512 * 2);
  const size_t o_wqp    = alloc(3072ull * 256 * 2);
  const size_t o_wf1    = alloc(1024ull * 3072 * 2);
  const size_t o_fw2b   = alloc(1024ull * 1024 * 2);
  const size_t o_fused1 = alloc(8192ull * 1024 * 2);
  const size_t o_sub    = (off + 63) & ~63ull;

  // sub-pool (time-shared): prep temps -> per-chunk qkv/att -> Qr
  const size_t so_aiwb = 0;
  const size_t so_fw1b = so_aiwb + 3072ull * 1024 * 2;
  const size_t so_pTv  = so_fw1b + 1024ull * 3072 * 2;
  const size_t so_pTt  = so_pTv + 512ull * 1024 * 2;
  const size_t so_pTp  = so_pTt + 512ull * 1024 * 2;
  const size_t so_aoT  = so_pTp + 256ull * 1024 * 2;
  const size_t so_WphT = so_aoT + 1024ull * 1024 * 2;
  const size_t prep_bytes = so_WphT + 256ull * 1024 * 2;
  const size_t q_bytes = 8192ull * 768 * 4;

  int NC = 512;
  for (int cand : {8192, 4096, 2048, 1024}) {
    size_t sub = prep_bytes > q_bytes ? prep_bytes : q_bytes;
    size_t cb = (size_t)cand * 9216 * 2 + (size_t)cand * 3072 * 2;
    if (cb > sub) sub = cb;
    if (o_sub + sub <= ws_size) { NC = cand; break; }
  }
  const size_t o_qkvc = o_sub;
  const size_t o_attc = o_sub + (size_t)NC * 9216 * 2;
  const size_t o_qr   = o_sub;

  auto FP = [&](size_t o) { return (float*)(W + o); };
  auto UP = [&](size_t o) { return (unsigned short*)(W + o); };

  hipMemsetAsync(W + o_cnt, 0, 256, stream);
  imp_rep_k<<<1, 256, 0, stream>>>(importance, aob, FP(o_imp), FP(o_rep));
  bias_prep<<<8, 256, 0, stream>>>(gbih, gbhh, prb, FP(o_cb768), FP(o_cb2048));

  auto cvt = [&](const float* in, unsigned short* op, size_t n) {
    int n4 = (int)(n / 4);
    cvt_bf<<<(n4 + 255) / 256, 256, 0, stream>>>(in, op, n4);
  };
  cvt(aiw,  UP(o_sub + so_aiwb), 3072ull * 1024);
  cvt(fw1,  UP(o_sub + so_fw1b), 1024ull * 3072);
  cvt(fw2,  UP(o_fw2b), 1024ull * 1024);
  cvt(gwih, UP(o_gwihb), 768ull * 2048);
  cvt(gwhh, UP(o_whhb), 768ull * 256);
  cvt(prw,  UP(o_prwb), 1024ull * 256);
  cvt(pow_, UP(o_powb), 1024ull * 1280);
  cvt(emb_v, UP(o_embvb), 8192ull * 512);
  cvt(emb_t, UP(o_embtb), 8192ull * 512);
  cvt(emb_p, UP(o_embpb), 8192ull * 256);

  transpose_bf<<<dim3(16, 32), 256, 0, stream>>>(pvw, 512, UP(o_sub + so_pTv), 1024);
  transpose_bf<<<dim3(16, 32), 256, 0, stream>>>(ptw, 512, UP(o_sub + so_pTt), 1024);
  transpose_bf<<<dim3(8, 32), 256, 0, stream>>>(ppw, 256, UP(o_sub + so_pTp), 1024);
  transpose_bf<<<dim3(32, 32), 256, 0, stream>>>(aow, 1024, UP(o_sub + so_aoT), 1024);
  transpose_bf<<<dim3(8, 32), 256, 0, stream>>>(pow_, 1280, UP(o_sub + so_WphT), 1024);

  matvec3<<<3072, 64, 0, stream>>>(aiw, pvb, ptb, ppb, aib, FP(o_bqkv));
  matvec_nt<<<1024, 64, 0, stream>>>(fw1, 3072, FP(o_rep), fb1, FP(o_bf1), 3072);

  // folded weights
  g_bf(UP(o_sub + so_aiwb), 1024, UP(o_sub + so_pTv), 1024, UP(o_wqv), 512,
       3072, 512, 1024, nullptr, nullptr, 0, nullptr, 0, 1, stream);
  g_bf(UP(o_sub + so_aiwb), 1024, UP(o_sub + so_pTt), 1024, UP(o_wqt), 512,
       3072, 512, 1024, nullptr, nullptr, 0, nullptr, 0, 1, stream);
  g_bf(UP(o_sub + so_aiwb), 1024, UP(o_sub + so_pTp), 1024, UP(o_wqp), 256,
       3072, 256, 1024, nullptr, nullptr, 0, nullptr, 0, 1, stream);
  for (int m = 0; m < 3; ++m)
    g_bf(UP(o_sub + so_fw1b) + m * 1024, 3072, UP(o_sub + so_aoT), 1024,
         UP(o_wf1) + m * 1024, 3072, 1024, 1024, 1024,
         nullptr, nullptr, 0, FP(o_imp) + m, 0, 1, stream);
  g_bf(UP(o_gwihb), 2048, UP(o_sub + so_WphT), 1024, UP(o_m1b), 256,
       768, 256, 1024, nullptr, nullptr, 0, nullptr, 0, 1, stream);

  wr_prep<<<1536, 256, 0, stream>>>(UP(o_m1b), UP(o_whhb), UP(o_wr));
  h0_prep<<<64, 256, 0, stream>>>(h0, UP(o_hist));

  // phase A: qkv (bf16) -> attention -> fused1
  const int nchunk = 8192 / NC;
  for (int c = 0; c < nchunk; ++c) {
    g_bf(UP(o_embvb) + (size_t)c * NC * 512, 512, UP(o_wqv), 512,
         UP(o_qkvc) + 0, 9216, NC, 3072, 512, FP(o_bqkv) + 0,
         nullptr, 0, nullptr, 0, 1, stream);
    g_bf(UP(o_embtb) + (size_t)c * NC * 512, 512, UP(o_wqt), 512,
         UP(o_qkvc) + 3072, 9216, NC, 3072, 512, FP(o_bqkv) + 3072,
         nullptr, 0, nullptr, 0, 1, stream);
    g_bf(UP(o_embpb) + (size_t)c * NC * 256, 256, UP(o_wqp), 256,
         UP(o_qkvc) + 6144, 9216, NC, 3072, 256, FP(o_bqkv) + 6144,
         nullptr, 0, nullptr, 0, 1, stream);
    attn3<<<NC, 256, 0, stream>>>(UP(o_qkvc), UP(o_attc));
    g_bf(UP(o_attc), 3072, UP(o_wf1), 3072,
         UP(o_fused1) + (size_t)c * NC * 1024, 1024, NC, 1024, 3072,
         FP(o_bf1), nullptr, 0, nullptr, 1 /*relu*/, 1, stream);
  }

  g_bf(UP(o_fused1), 1024, UP(o_fw2b), 1024, UP(o_fusedb), 1024,
       8192, 1024, 1024, fb2, nullptr, 0, nullptr, 0, 1, stream);
  layernorm_bf<<<8192, 256, 0, stream>>>(UP(o_fusedb), ln_g, ln_b);

  g_bf(UP(o_fusedb), 1024, UP(o_powb) + 256, 1280, FP(o_fpb), 1024,
       8192, 1024, 1024, pob, nullptr, 0, nullptr, 0, 0, stream);
  build_R_bf<<<8192, 256, 0, stream>>>(FP(o_fpb), noise, s0, UP(o_rbf));
  // Qr = [R | fused] @ gwih^T + (gbih + bhh_rz), written in frag-perm order
  g_bf(UP(o_rbf), 1024, UP(o_gwihb), 2048, FP(o_qr), 768,
       8192, 768, 2048, FP(o_cb768), nullptr, 0, nullptr, 0, 0, stream,
       UP(o_fusedb), 1024, 1024, nullptr, 0, 1 << 30, 0, 1 /*qperm*/);

  rssm_recur4<<<8, 256, 0, stream>>>(UP(o_wr), FP(o_qr), gbhh + 512, UP(o_hist),
                                     UP(o_hrow), out, (unsigned int*)(W + o_cnt));

  // prior | post in one dual-B GEMM (out cols 1280..3327)
  g_bf(UP(o_hrow), 256, UP(o_prwb), 256, out + 1280, 3328,
       8192, 2048, 256, FP(o_cb2048), FP(o_fpb), 1024, nullptr, 0, 0, stream,
       nullptr, 0, 1 << 30, UP(o_powb), 1280, 1024, 1024 /*src_c0*/, 0);
  s_out_k<<<8192, 256, 0, stream>>>(out, noise);
}

// Round 5
// 1454.472 us; speedup vs baseline: 1.4934x; 1.2253x over previous
//
#include <hip/hip_runtime.h>
#include <cstdint>
#include <cstddef>

#define F4(p)  (*(reinterpret_cast<float4*>(p)))
#define CF4(p) (*(reinterpret_cast<const float4*>(p)))

typedef __attribute__((ext_vector_type(8))) short short8;
typedef __attribute__((ext_vector_type(4))) float f32x4;
typedef __attribute__((ext_vector_type(4))) int i32x4;

__device__ __forceinline__ float bf2f(unsigned short h) {
  return __uint_as_float(((unsigned int)h) << 16);
}
__device__ __forceinline__ unsigned short f2bf(float x) {
  unsigned int u = __float_as_uint(x);
  return (unsigned short)((u + 0x7FFFu + ((u >> 16) & 1u)) >> 16);
}

#if __has_builtin(__builtin_amdgcn_global_load_lds)
#define USE_GLL 1
#else
#define USE_GLL 0
#endif
#if __has_builtin(__builtin_amdgcn_sched_barrier)
#define SCHED_BARRIER() __builtin_amdgcn_sched_barrier(0)
#else
#define SCHED_BARRIER()
#endif

__device__ __forceinline__ void stage16(unsigned short* lds_lane,
                                        unsigned short* lds_wavebase,
                                        const unsigned short* g) {
#if USE_GLL
  __builtin_amdgcn_global_load_lds(
      (const __attribute__((address_space(1))) unsigned int*)g,
      (__attribute__((address_space(3))) unsigned int*)lds_wavebase, 16, 0, 0);
#else
  *(short8*)lds_lane = *(const short8*)g;
#endif
}

// device-coherent (cross-XCD) 16B load/store: sc0 sc1 -> MALL coherence point
__device__ __forceinline__ i32x4 coh_load16(const void* p) {
  i32x4 r;
  asm volatile("global_load_dwordx4 %0, %1, off sc0 sc1"
               : "=v"(r) : "v"(p) : "memory");
  return r;
}
__device__ __forceinline__ void coh_store16(void* p, i32x4 v) {
  asm volatile("global_store_dwordx4 %0, %1, off sc0 sc1"
               :: "v"(p), "v"(v) : "memory");
}

__device__ __forceinline__ float fsigmoid(float x) {
  return 1.0f / (1.0f + __expf(-x));
}
__device__ __forceinline__ float ftanh(float x) {
  float ax = fabsf(x);
  float e = __expf(2.0f * ax);
  float t = 1.0f - 2.0f / (e + 1.0f);
  return copysignf(t, x);
}

// =====================================================================
// bf16 MFMA GEMM: C = post( scale*(A@B^T) + bias + src )
// dual-A (k-split) and dual-B (n-split) supported. 128x128 tile, BK=64,
// 4 waves 2x2, XOR-swizzled LDS via pre-swizzled global source.
// qperm: write f32 C in the recurrence's Qr fragment order.
// src_c0: src added only for gc>=src_c0, at column (gc-src_c0).
// =====================================================================
__global__ __launch_bounds__(256) void gemm_bf(
    const unsigned short* __restrict__ A, int lda,
    const unsigned short* __restrict__ A2, int lda2, int kSplit,
    const unsigned short* __restrict__ B, int ldb,
    const unsigned short* __restrict__ B2, int ldb2, int nSplit,
    void* __restrict__ Cv, int ldc, int K,
    const float* __restrict__ bias,
    const float* __restrict__ src, int ldsrc, int src_c0,
    const float* __restrict__ scale_ptr, int relu, int obf16, int qperm)
{
  __shared__ unsigned short As[128 * 64];
  __shared__ unsigned short Bs[128 * 64];
  const int tid = threadIdx.x;
  const int wv = tid >> 6, ln = tid & 63;
  const int wm = wv >> 1, wn = wv & 1;
  const size_t gm0 = (size_t)blockIdx.y * 128;
  const size_t gn0 = (size_t)blockIdx.x * 128;

  f32x4 acc[4][4];
  #pragma unroll
  for (int i = 0; i < 4; ++i)
    #pragma unroll
    for (int j = 0; j < 4; ++j) acc[i][j] = (f32x4){0.f, 0.f, 0.f, 0.f};

  for (int kk = 0; kk < K; kk += 64) {
    const unsigned short* Ause = A; int lduse = lda; int kkA = kk;
    if (A2 != nullptr && kk >= kSplit) { Ause = A2; lduse = lda2; kkA = kk - kSplit; }
    #pragma unroll
    for (int j = 0; j < 4; ++j) {
      int idx = j * 256 + tid;
      int r = idx >> 3, u = idx & 7;
      int ksw = (u ^ (r & 7)) << 3;
      const unsigned short* ga = Ause + (gm0 + r) * lduse + kkA + ksw;
      stage16(&As[idx * 8], &As[(idx & ~63) * 8], ga);
      size_t nr = gn0 + r;
      const unsigned short* gb = (nr < (size_t)nSplit)
          ? B + nr * ldb + kk + ksw
          : B2 + (nr - nSplit) * ldb2 + kk + ksw;
      stage16(&Bs[idx * 8], &Bs[(idx & ~63) * 8], gb);
    }
    __syncthreads();
    #pragma unroll
    for (int ks = 0; ks < 2; ++ks) {
      short8 af[4], bfv[4];
      #pragma unroll
      for (int mi = 0; mi < 4; ++mi) {
        int r = wm * 64 + mi * 16 + (ln & 15);
        int u = (ks * 4 + (ln >> 4)) ^ (r & 7);
        af[mi] = *(const short8*)&As[(r * 8 + u) * 8];
      }
      #pragma unroll
      for (int nj = 0; nj < 4; ++nj) {
        int r = wn * 64 + nj * 16 + (ln & 15);
        int u = (ks * 4 + (ln >> 4)) ^ (r & 7);
        bfv[nj] = *(const short8*)&Bs[(r * 8 + u) * 8];
      }
      #pragma unroll
      for (int mi = 0; mi < 4; ++mi)
        #pragma unroll
        for (int nj = 0; nj < 4; ++nj)
          acc[mi][nj] = __builtin_amdgcn_mfma_f32_16x16x32_bf16(
              af[mi], bfv[nj], acc[mi][nj], 0, 0, 0);
    }
    __syncthreads();
  }

  float sc = scale_ptr ? *scale_ptr : 1.0f;
  #pragma unroll
  for (int nj = 0; nj < 4; ++nj) {
    int gc = (int)gn0 + wn * 64 + nj * 16 + (ln & 15);
    float bv = bias ? bias[gc] : 0.f;
    #pragma unroll
    for (int mi = 0; mi < 4; ++mi) {
      #pragma unroll
      for (int qq = 0; qq < 4; ++qq) {
        int gr = (int)gm0 + wm * 64 + mi * 16 + ((ln >> 4) << 2) + qq;
        float v = acc[mi][nj][qq] * sc + bv;
        if (src && gc >= src_c0) v += src[(size_t)gr * ldsrc + (gc - src_c0)];
        if (relu) v = fmaxf(v, 0.f);
        if (qperm) {
          int t = gr & 127, bq = gr >> 7;
          int g = gc >> 8, d = gc & 255;
          int ddq = d >> 5, doff = d & 31;
          int wq = bq >> 4;
          int lq = (bq & 15) + ((doff >> 3) << 4);
          size_t qi = (((((size_t)t * 8 + ddq) * 3 + g) * 4 + wq) * 64 + lq) * 8
                      + (doff & 7);
          ((float*)Cv)[qi] = v;
        } else if (obf16) {
          ((unsigned short*)Cv)[(size_t)gr * ldc + gc] = f2bf(v);
        } else {
          ((float*)Cv)[(size_t)gr * ldc + gc] = v;
        }
      }
    }
  }
}

// =====================================================================
__global__ __launch_bounds__(256) void cvt_bf(
    const float* __restrict__ in, unsigned short* __restrict__ outp, int n4)
{
  int i = blockIdx.x * 256 + threadIdx.x;
  if (i < n4) {
    float4 v = CF4(in + (size_t)i * 4);
    ushort4 o;
    o.x = f2bf(v.x); o.y = f2bf(v.y); o.z = f2bf(v.z); o.w = f2bf(v.w);
    *(ushort4*)(outp + (size_t)i * 4) = o;
  }
}

__global__ __launch_bounds__(256) void transpose_bf(
    const float* __restrict__ in, int ldin, unsigned short* __restrict__ outp, int R)
{
  __shared__ float tile[32][33];
  int c0 = blockIdx.x * 32, r0 = blockIdx.y * 32;
  int tx = threadIdx.x & 31, ty = threadIdx.x >> 5;
  #pragma unroll
  for (int i = ty; i < 32; i += 8)
    tile[i][tx] = in[(size_t)(r0 + i) * ldin + c0 + tx];
  __syncthreads();
  #pragma unroll
  for (int i = ty; i < 32; i += 8)
    outp[(size_t)(c0 + i) * R + r0 + tx] = f2bf(tile[tx][i]);
}

// out3[m*3072+i] = dot(A[i], x_m) + aib[i],  m=0..2 (A row read once)
__global__ __launch_bounds__(64) void matvec3(
    const float* __restrict__ A,
    const float* __restrict__ x0, const float* __restrict__ x1,
    const float* __restrict__ x2, const float* __restrict__ aib,
    float* __restrict__ outp)
{
  int i = blockIdx.x, t = threadIdx.x;
  const float* Ar = A + (size_t)i * 1024;
  float s0 = 0.f, s1 = 0.f, s2 = 0.f;
  for (int k = t * 4; k < 1024; k += 256) {
    float4 a = CF4(Ar + k);
    float4 v0 = CF4(x0 + k), v1 = CF4(x1 + k), v2 = CF4(x2 + k);
    s0 += a.x*v0.x + a.y*v0.y + a.z*v0.z + a.w*v0.w;
    s1 += a.x*v1.x + a.y*v1.y + a.z*v1.z + a.w*v1.w;
    s2 += a.x*v2.x + a.y*v2.y + a.z*v2.z + a.w*v2.w;
  }
  #pragma unroll
  for (int m = 32; m > 0; m >>= 1) {
    s0 += __shfl_xor(s0, m); s1 += __shfl_xor(s1, m); s2 += __shfl_xor(s2, m);
  }
  if (t == 0) {
    float b = aib[i];
    outp[i] = s0 + b; outp[3072 + i] = s1 + b; outp[6144 + i] = s2 + b;
  }
}

__global__ __launch_bounds__(64) void matvec_nt(
    const float* __restrict__ A, int lda,
    const float* __restrict__ x, const float* __restrict__ badd,
    float* __restrict__ outp, int K)
{
  int i = blockIdx.x, t = threadIdx.x;
  const float* Ar = A + (size_t)i * lda;
  float s = 0.f;
  for (int k = t * 4; k < K; k += 256) {
    float4 a = CF4(Ar + k);
    float4 xx = CF4(x + k);
    s += a.x*xx.x + a.y*xx.y + a.z*xx.z + a.w*xx.w;
  }
  #pragma unroll
  for (int m = 32; m > 0; m >>= 1) s += __shfl_xor(s, m);
  if (t == 0) outp[i] = s + (badd ? badd[i] : 0.f);
}

__global__ __launch_bounds__(256) void imp_rep_k(
    const float* __restrict__ importance, const float* __restrict__ aob,
    float* __restrict__ imp, float* __restrict__ rep)
{
  __shared__ float si[3];
  if (threadIdx.x == 0) {
    float a = importance[0], b = importance[1], c = importance[2];
    float mx = fmaxf(a, fmaxf(b, c));
    float ea = expf(a - mx), eb = expf(b - mx), ec = expf(c - mx);
    float inv = 1.f / (ea + eb + ec);
    si[0] = ea * inv; si[1] = eb * inv; si[2] = ec * inv;
    imp[0] = si[0]; imp[1] = si[1]; imp[2] = si[2];
  }
  __syncthreads();
  for (int idx = threadIdx.x; idx < 3072; idx += 256)
    rep[idx] = si[idx >> 10] * aob[idx & 1023];
}

// cb768 = gbih + [gbhh_r | gbhh_z | 0] ; cb2048 = [prb | 0]
__global__ __launch_bounds__(256) void bias_prep(
    const float* __restrict__ gbih, const float* __restrict__ gbhh,
    const float* __restrict__ prb, float* __restrict__ cb768,
    float* __restrict__ cb2048)
{
  int i = blockIdx.x * 256 + threadIdx.x;
  if (i < 768) cb768[i] = gbih[i] + (i < 512 ? gbhh[i] : 0.f);
  if (i < 2048) cb2048[i] = (i < 1024) ? prb[i] : 0.f;
}

// =====================================================================
// 3-token MHA, bf16 in -> bf16 out
// =====================================================================
__global__ __launch_bounds__(256) void attn3(
    const unsigned short* __restrict__ qkv, unsigned short* __restrict__ att)
{
  const int n = blockIdx.x;
  const unsigned short* row = qkv + (size_t)n * 9216;
  __shared__ float qk[6144];
  __shared__ float sc[72];
  __shared__ float pw[72];
  const int t = threadIdx.x;
  for (int idx = t; idx < 768; idx += 256) {
    int m = idx >> 7;                  // 0..5
    int off = (idx & 127) << 3;
    const unsigned short* srcp = (m < 3) ? (row + m * 3072 + off)
                                         : (row + (m - 3) * 3072 + 1024 + off);
    short8 v = *(const short8*)srcp;
    float* dst = &qk[m * 1024 + off];
    #pragma unroll
    for (int j = 0; j < 8; ++j) dst[j] = bf2f(((const unsigned short*)&v)[j]);
  }
  __syncthreads();
  if (t < 72) {
    int h = t / 9, i = (t % 9) / 3, j = t % 3;
    const float* qp = &qk[i * 1024 + h * 128];
    const float* kp = &qk[3072 + j * 1024 + h * 128];
    float s = 0.f;
    int rot = (t & 31) * 4;
    for (int d2 = 0; d2 < 128; ++d2) {
      int dx = (d2 + rot) & 127;
      s += qp[dx] * kp[dx];
    }
    sc[t] = s * 0.08838834764831845f;
  }
  __syncthreads();
  if (t < 24) {
    int base = t * 3;
    float a = sc[base], b = sc[base + 1], c = sc[base + 2];
    float mx = fmaxf(a, fmaxf(b, c));
    float ea = expf(a - mx), eb = expf(b - mx), ec = expf(c - mx);
    float inv = 1.f / (ea + eb + ec);
    pw[base] = ea * inv; pw[base + 1] = eb * inv; pw[base + 2] = ec * inv;
  }
  __syncthreads();
  unsigned short* outp = att + (size_t)n * 3072;
  #pragma unroll
  for (int rep = 0; rep < 3; ++rep) {
    int idx = (rep * 256 + t) << 2;
    int i = idx >> 10;
    int hd = idx & 1023;
    int h = hd >> 7;
    int pb = (h * 3 + i) * 3;
    float w0 = pw[pb], w1 = pw[pb + 1], w2 = pw[pb + 2];
    ushort4 v0 = *(const ushort4*)(row + 2048 + hd);
    ushort4 v1 = *(const ushort4*)(row + 3072 + 2048 + hd);
    ushort4 v2 = *(const ushort4*)(row + 6144 + 2048 + hd);
    ushort4 o;
    o.x = f2bf(w0 * bf2f(v0.x) + w1 * bf2f(v1.x) + w2 * bf2f(v2.x));
    o.y = f2bf(w0 * bf2f(v0.y) + w1 * bf2f(v1.y) + w2 * bf2f(v2.y));
    o.z = f2bf(w0 * bf2f(v0.z) + w1 * bf2f(v1.z) + w2 * bf2f(v2.z));
    o.w = f2bf(w0 * bf2f(v0.w) + w1 * bf2f(v1.w) + w2 * bf2f(v2.w));
    *(ushort4*)(outp + idx) = o;
  }
}

// =====================================================================
__global__ __launch_bounds__(256) void layernorm_bf(
    unsigned short* __restrict__ X, const float* __restrict__ g,
    const float* __restrict__ bta)
{
  int n = blockIdx.x, t = threadIdx.x;
  unsigned short* row = X + (size_t)n * 1024;
  ushort4 hv = *(ushort4*)(row + t * 4);
  float x0 = bf2f(hv.x), x1 = bf2f(hv.y), x2 = bf2f(hv.z), x3 = bf2f(hv.w);
  float s = x0 + x1 + x2 + x3;
  float ss = x0*x0 + x1*x1 + x2*x2 + x3*x3;
  #pragma unroll
  for (int m = 32; m > 0; m >>= 1) { s += __shfl_xor(s, m); ss += __shfl_xor(ss, m); }
  __shared__ float rs[4], rss[4];
  int w = t >> 6;
  if ((t & 63) == 0) { rs[w] = s; rss[w] = ss; }
  __syncthreads();
  s = rs[0] + rs[1] + rs[2] + rs[3];
  ss = rss[0] + rss[1] + rss[2] + rss[3];
  float mean = s * (1.0f / 1024.0f);
  float var = ss * (1.0f / 1024.0f) - mean * mean;
  float inv = 1.0f / sqrtf(var + 1e-5f);
  float4 gg = CF4(g + t * 4);
  float4 bb = CF4(bta + t * 4);
  ushort4 o;
  o.x = f2bf((x0 - mean) * inv * gg.x + bb.x);
  o.y = f2bf((x1 - mean) * inv * gg.y + bb.y);
  o.z = f2bf((x2 - mean) * inv * gg.z + bb.z);
  o.w = f2bf((x3 - mean) * inv * gg.w + bb.w);
  *(ushort4*)(row + t * 4) = o;
}

__global__ __launch_bounds__(256) void build_R_bf(
    const float* __restrict__ Fpb, const float* __restrict__ noise,
    const float* __restrict__ s0, unsigned short* __restrict__ R)
{
  size_t idx = (size_t)blockIdx.x * 256 + threadIdx.x;
  int n = (int)(idx >> 8);
  int k4 = (int)(idx & 255) << 2;
  float4 v;
  if ((n & 127) == 0) {
    v = CF4(s0 + (size_t)(n >> 7) * 1024 + k4);
  } else {
    float4 f = CF4(Fpb + (size_t)(n - 1) * 1024 + k4);
    float4 z = CF4(noise + (size_t)(n - 1) * 1024 + k4);
    v.x = f.x + z.x; v.y = f.y + z.y; v.z = f.z + z.z; v.w = f.w + z.w;
  }
  ushort4 o;
  o.x = f2bf(v.x); o.y = f2bf(v.y); o.z = f2bf(v.z); o.w = f2bf(v.w);
  *(ushort4*)(R + (size_t)n * 1024 + k4) = o;
}

__global__ __launch_bounds__(256) void s_out_k(
    float* __restrict__ outp, const float* __restrict__ noise)
{
  size_t idx = (size_t)blockIdx.x * 256 + threadIdx.x;
  int n = (int)(idx >> 8);
  int j4 = (int)(idx & 255) << 2;
  float4 p = CF4(outp + (size_t)n * 3328 + 2304 + j4);
  float4 z = CF4(noise + (size_t)n * 1024 + j4);
  float4 o; o.x = p.x + z.x; o.y = p.y + z.y; o.z = p.z + z.z; o.w = p.w + z.w;
  F4(outp + (size_t)n * 3328 + 256 + j4) = o;
}

// =====================================================================
// Recurrence weight prep: 8 blocks x 12 row-tiles of 16 rows, B-frag order.
// =====================================================================
__global__ __launch_bounds__(256) void wr_prep(
    const unsigned short* __restrict__ M1bf, const unsigned short* __restrict__ Whhbf,
    unsigned short* __restrict__ Wr)
{
  int idx = blockIdx.x * 256 + threadIdx.x;   // < 393216
  int j = idx & 7, l = (idx >> 3) & 63, kt = (idx >> 9) & 7;
  int rest = idx >> 12;                        // dd*12 + r
  int r = rest % 12, dd = rest / 12;
  int g = r >> 1, dhalf = r & 1;
  int d = dd * 32 + dhalf * 16 + (l & 15);
  int srow = (g % 3) * 256 + d;
  int k = kt * 32 + ((l >> 4) << 3) + j;
  const unsigned short* srcp = (g < 3) ? M1bf : Whhbf;
  Wr[idx] = srcp[(size_t)srow * 256 + k];
}

// hist frag layout: [buf][w'][kt][l][j], b=16w'+(l&15), k=kt*32+(l>>4)*8+j
__global__ __launch_bounds__(256) void h0_prep(
    const float* __restrict__ h0, unsigned short* __restrict__ hist)
{
  int idx = blockIdx.x * 256 + threadIdx.x;   // < 16384
  int j = idx & 7, l = (idx >> 3) & 63, kt = (idx >> 9) & 7, w = idx >> 12;
  int b = 16 * w + (l & 15);
  int k = kt * 32 + ((l >> 4) << 3) + j;
  hist[idx] = f2bf(h0[(size_t)b * 256 + k]);
}

// =====================================================================
// Sequential RSSM v5. 8 blocks (32 d-cols each), 256 thr = 4 waves.
// Weights register-resident. h exchange via sc0/sc1 device-coherent
// 16B loads/stores (no threadfence, no L2 wb/inv). Barrier: vmcnt(0) ->
// sync -> relaxed atomic add -> background Hrow/out/Q-prefetch ->
// relaxed poll (tid0, no sleep) -> sync.
// =====================================================================
#define LOADQ(tt) do { \
  _Pragma("unroll") \
  for (int g = 0; g < 3; ++g) { \
    const float* qp = Qr + (((((size_t)(tt) * 8 + dd) * 3 + g) * 4 + w) * 64 + l) * 8; \
    float4 qa = CF4(qp); float4 qb = CF4(qp + 4); \
    qv[g][0] = qa.x; qv[g][1] = qa.y; qv[g][2] = qa.z; qv[g][3] = qa.w; \
    qv[g][4] = qb.x; qv[g][5] = qb.y; qv[g][6] = qb.z; qv[g][7] = qb.w; \
  } } while (0)

__global__ __launch_bounds__(256, 1) void rssm_recur5(
    const unsigned short* __restrict__ Wr, const float* __restrict__ Qr,
    const float* __restrict__ bhh_n, unsigned short* __restrict__ hist,
    unsigned short* __restrict__ Hrow, float* __restrict__ outp,
    unsigned int* __restrict__ counter)
{
  const int dd = blockIdx.x;          // 0..7
  const int tid = threadIdx.x;
  const int w = tid >> 6, l = tid & 63;
  __shared__ float G[12][16][68];            // 52KB gate exchange (16B-aligned rows)
  __shared__ unsigned short hL[16384];       // 32KB staged h frags

  // persistent B-frags: 3 row-tiles x 8 kt (96 VGPR)
  short8 Bf[3][8];
  {
    const unsigned short* wb = Wr + ((size_t)(dd * 12 + w * 3) * 8) * 512 + l * 8;
    #pragma unroll
    for (int ri = 0; ri < 3; ++ri)
      #pragma unroll
      for (int kt = 0; kt < 8; ++kt)
        Bf[ri][kt] = *(const short8*)(wb + (size_t)(ri * 8 + kt) * 512);
  }
  float bhn[8];
  #pragma unroll
  for (int j = 0; j < 8; ++j) bhn[j] = bhh_n[dd * 32 + ((l >> 4) << 3) + j];

  const int bg = w * 16 + (l & 15);       // GRU batch row
  const int dhalf = l >> 5;               // 0..1
  const int d16b = ((l >> 4) & 1) << 3;   // 0 or 8
  float qv[3][8];
  LOADQ(0);

  unsigned int target = 0;
  #pragma unroll 1
  for (int t = 0; t < 128; ++t) {
    // ---- stage hist[t&1] -> hL via device-coherent loads ----
    const unsigned short* hsrc = hist + (size_t)(t & 1) * 16384;
    i32x4 sv[8];
    #pragma unroll
    for (int j = 0; j < 8; ++j)
      sv[j] = coh_load16(hsrc + (size_t)(j * 256 + tid) * 8);
    asm volatile("s_waitcnt vmcnt(0)" ::: "memory");
    SCHED_BARRIER();
    #pragma unroll
    for (int j = 0; j < 8; ++j)
      *(i32x4*)&hL[(size_t)(j * 256 + tid) * 8] = sv[j];
    __syncthreads();

    // ---- MFMA: 96 per wave ----
    f32x4 acc[4][3];
    #pragma unroll
    for (int bt = 0; bt < 4; ++bt)
      #pragma unroll
      for (int ri = 0; ri < 3; ++ri) acc[bt][ri] = (f32x4){0.f, 0.f, 0.f, 0.f};
    #pragma unroll
    for (int kt = 0; kt < 8; ++kt)
      #pragma unroll
      for (int bt = 0; bt < 4; ++bt) {
        short8 a = *(const short8*)&hL[((bt * 8 + kt) * 64 + l) * 8];
        acc[bt][0] = __builtin_amdgcn_mfma_f32_16x16x32_bf16(a, Bf[0][kt], acc[bt][0], 0, 0, 0);
        acc[bt][1] = __builtin_amdgcn_mfma_f32_16x16x32_bf16(a, Bf[1][kt], acc[bt][1], 0, 0, 0);
        acc[bt][2] = __builtin_amdgcn_mfma_f32_16x16x32_bf16(a, Bf[2][kt], acc[bt][2], 0, 0, 0);
      }
    short8 ha = *(const short8*)&hL[((w * 8 + dd) * 64 + l) * 8];

    // ---- gate exchange (vector ds_write_b128) ----
    #pragma unroll
    for (int bt = 0; bt < 4; ++bt)
      #pragma unroll
      for (int ri = 0; ri < 3; ++ri)
        *(f32x4*)&G[w * 3 + ri][l & 15][bt * 16 + ((l >> 4) << 2)] = acc[bt][ri];
    __syncthreads();

    // ---- GRU: 8 cells (b = bg, d = dd*32 + (l>>4)*8 + j) ----
    const float m1s = (t == 0) ? 0.f : 1.f;
    unsigned short hn8[8];
    float hf8[8];
    #pragma unroll
    for (int j = 0; j < 8; ++j) {
      int d16 = d16b + j;
      float m1r = G[0 + dhalf][d16][bg];
      float m1z = G[2 + dhalf][d16][bg];
      float m1n = G[4 + dhalf][d16][bg];
      float ghr = G[6 + dhalf][d16][bg];
      float ghz = G[8 + dhalf][d16][bg];
      float ghn = G[10 + dhalf][d16][bg] + bhn[j];
      float gir = fmaf(m1r, m1s, qv[0][j]);
      float giz = fmaf(m1z, m1s, qv[1][j]);
      float gin = fmaf(m1n, m1s, qv[2][j]);
      float r = fsigmoid(gir + ghr);
      float z = fsigmoid(giz + ghz);
      float nn = ftanh(gin + r * ghn);
      float hold = bf2f(((const unsigned short*)&ha)[j]);
      float hn = (1.f - z) * nn + z * hold;
      unsigned short hbv = f2bf(hn);
      hn8[j] = hbv;
      hf8[j] = bf2f(hbv);
    }

    // ---- coherent h store (the only store on the critical path) ----
    union { short8 s; i32x4 i; } hu;
    hu.s = *(const short8*)hn8;
    coh_store16(hist + (size_t)((t + 1) & 1) * 16384
                + (size_t)((w * 8 + dd) * 64 + l) * 8, hu.i);

    if (t < 127) {
      asm volatile("s_waitcnt vmcnt(0)" ::: "memory");   // h store acked at MALL
      __syncthreads();                                   // all 256 threads done
      target += 8;
      if (tid == 0)
        __hip_atomic_fetch_add(counter, 1u, __ATOMIC_RELAXED,
                               __HIP_MEMORY_SCOPE_AGENT);
      // background work — drains during the poll
      LOADQ(t + 1);
      *(short8*)(Hrow + (size_t)(bg * 128 + t) * 256 + dd * 32 + ((l >> 4) << 3)) =
          *(const short8*)hn8;
      float* op = outp + (size_t)(bg * 128 + t) * 3328 + dd * 32 + ((l >> 4) << 3);
      float4 o0; o0.x = hf8[0]; o0.y = hf8[1]; o0.z = hf8[2]; o0.w = hf8[3];
      float4 o1; o1.x = hf8[4]; o1.y = hf8[5]; o1.z = hf8[6]; o1.w = hf8[7];
      F4(op) = o0; F4(op + 4) = o1;
      if (tid == 0) {
        while (__hip_atomic_load(counter, __ATOMIC_RELAXED,
                                 __HIP_MEMORY_SCOPE_AGENT) < target) {}
      }
      __syncthreads();
    } else {
      *(short8*)(Hrow + (size_t)(bg * 128 + t) * 256 + dd * 32 + ((l >> 4) << 3)) =
          *(const short8*)hn8;
      float* op = outp + (size_t)(bg * 128 + t) * 3328 + dd * 32 + ((l >> 4) << 3);
      float4 o0; o0.x = hf8[0]; o0.y = hf8[1]; o0.z = hf8[2]; o0.w = hf8[3];
      float4 o1; o1.x = hf8[4]; o1.y = hf8[5]; o1.z = hf8[6]; o1.w = hf8[7];
      F4(op) = o0; F4(op + 4) = o1;
    }
  }
}

// =====================================================================
// Host side
// =====================================================================
static inline void g_bf(const unsigned short* A, int lda,
                        const unsigned short* B, int ldb,
                        void* C, int ldc, int M, int N, int K,
                        const float* bias, const float* src, int ldsrc,
                        const float* scale, int relu, int obf16, hipStream_t s,
                        const unsigned short* A2 = nullptr, int lda2 = 0,
                        int kSplit = 1 << 30,
                        const unsigned short* B2 = nullptr, int ldb2 = 0,
                        int nSplit = 1 << 30,
                        int src_c0 = 0, int qperm = 0)
{
  dim3 grid(N / 128, M / 128);
  gemm_bf<<<grid, 256, 0, s>>>(A, lda, A2, lda2, kSplit, B, ldb, B2, ldb2, nSplit,
                               C, ldc, K, bias, src, ldsrc, src_c0, scale, relu,
                               obf16, qperm);
}

extern "C" void kernel_launch(void* const* d_in, const int* in_sizes, int n_in,
                              void* d_out, int out_size, void* d_ws, size_t ws_size,
                              hipStream_t stream)
{
  (void)in_sizes; (void)n_in; (void)out_size;

  const float* emb_v = (const float*)d_in[0];
  const float* emb_t = (const float*)d_in[1];
  const float* emb_p = (const float*)d_in[2];
  const float* noise = (const float*)d_in[3];
  const float* h0    = (const float*)d_in[4];
  const float* s0    = (const float*)d_in[5];
  const float* pvw   = (const float*)d_in[6];
  const float* pvb   = (const float*)d_in[7];
  const float* ptw   = (const float*)d_in[8];
  const float* ptb   = (const float*)d_in[9];
  const float* ppw   = (const float*)d_in[10];
  const float* ppb   = (const float*)d_in[11];
  const float* aiw   = (const float*)d_in[12];
  const float* aib   = (const float*)d_in[13];
  const float* aow   = (const float*)d_in[14];
  const float* aob   = (const float*)d_in[15];
  const float* importance = (const float*)d_in[16];
  const float* fw1   = (const float*)d_in[17];
  const float* fb1   = (const float*)d_in[18];
  const float* fw2   = (const float*)d_in[19];
  const float* fb2   = (const float*)d_in[20];
  const float* ln_g  = (const float*)d_in[21];
  const float* ln_b  = (const float*)d_in[22];
  const float* gwih  = (const float*)d_in[23];
  const float* gwhh  = (const float*)d_in[24];
  const float* gbih  = (const float*)d_in[25];
  const float* gbhh  = (const float*)d_in[26];
  const float* prw   = (const float*)d_in[27];
  const float* prb   = (const float*)d_in[28];
  const float* pow_  = (const float*)d_in[29];
  const float* pob   = (const float*)d_in[30];

  float* out = (float*)d_out;
  char* W = (char*)d_ws;

  size_t off = 0;
  auto alloc = [&](size_t bytes) { off = (off + 63) & ~63ull; size_t o = off; off += bytes; return o; };
  const size_t o_cnt    = alloc(256);
  const size_t o_imp    = alloc(16);
  const size_t o_rep    = alloc(3072 * 4);
  const size_t o_bqkv   = alloc(9216 * 4);
  const size_t o_bf1    = alloc(1024 * 4);
  const size_t o_cb768  = alloc(768 * 4);
  const size_t o_cb2048 = alloc(2048 * 4);
  const size_t o_gwihb  = alloc(768ull * 2048 * 2);
  const size_t o_whhb   = alloc(768ull * 256 * 2);
  const size_t o_m1b    = alloc(768ull * 256 * 2);
  const size_t o_prwb   = alloc(1024ull * 256 * 2);
  const size_t o_powb   = alloc(1024ull * 1280 * 2);
  const size_t o_wr     = alloc(393216ull * 2);
  const size_t o_hist   = alloc(2ull * 16384 * 2);
  const size_t o_hrow   = alloc(8192ull * 256 * 2);
  const size_t o_fusedb = alloc(8192ull * 1024 * 2);
  const size_t o_fpb    = alloc(8192ull * 1024 * 4);
  const size_t o_rbf    = alloc(8192ull * 1024 * 2);
  const size_t o_embvb  = alloc(8192ull * 512 * 2);
  const size_t o_embtb  = alloc(8192ull * 512 * 2);
  const size_t o_embpb  = alloc(8192ull * 256 * 2);
  const size_t o_wqv    = alloc(3072ull * 512 * 2);
  const size_t o_wqt    = alloc(3072ull * 512 * 2);
  const size_t o_wqp    = alloc(3072ull * 256 * 2);
  const size_t o_wf1    = alloc(1024ull * 3072 * 2);
  const size_t o_fw2b   = alloc(1024ull * 1024 * 2);
  const size_t o_fused1 = alloc(8192ull * 1024 * 2);
  const size_t o_sub    = (off + 63) & ~63ull;

  // sub-pool (time-shared): prep temps -> per-chunk qkv/att -> Qr
  const size_t so_aiwb = 0;
  const size_t so_fw1b = so_aiwb + 3072ull * 1024 * 2;
  const size_t so_pTv  = so_fw1b + 1024ull * 3072 * 2;
  const size_t so_pTt  = so_pTv + 512ull * 1024 * 2;
  const size_t so_pTp  = so_pTt + 512ull * 1024 * 2;
  const size_t so_aoT  = so_pTp + 256ull * 1024 * 2;
  const size_t so_WphT = so_aoT + 1024ull * 1024 * 2;
  const size_t prep_bytes = so_WphT + 256ull * 1024 * 2;
  const size_t q_bytes = 8192ull * 768 * 4;

  int NC = 512;
  for (int cand : {8192, 4096, 2048, 1024}) {
    size_t sub = prep_bytes > q_bytes ? prep_bytes : q_bytes;
    size_t cb = (size_t)cand * 9216 * 2 + (size_t)cand * 3072 * 2;
    if (cb > sub) sub = cb;
    if (o_sub + sub <= ws_size) { NC = cand; break; }
  }
  const size_t o_qkvc = o_sub;
  const size_t o_attc = o_sub + (size_t)NC * 9216 * 2;
  const size_t o_qr   = o_sub;

  auto FP = [&](size_t o) { return (float*)(W + o); };
  auto UP = [&](size_t o) { return (unsigned short*)(W + o); };

  hipMemsetAsync(W + o_cnt, 0, 256, stream);
  imp_rep_k<<<1, 256, 0, stream>>>(importance, aob, FP(o_imp), FP(o_rep));
  bias_prep<<<8, 256, 0, stream>>>(gbih, gbhh, prb, FP(o_cb768), FP(o_cb2048));

  auto cvt = [&](const float* in, unsigned short* op, size_t n) {
    int n4 = (int)(n / 4);
    cvt_bf<<<(n4 + 255) / 256, 256, 0, stream>>>(in, op, n4);
  };
  cvt(aiw,  UP(o_sub + so_aiwb), 3072ull * 1024);
  cvt(fw1,  UP(o_sub + so_fw1b), 1024ull * 3072);
  cvt(fw2,  UP(o_fw2b), 1024ull * 1024);
  cvt(gwih, UP(o_gwihb), 768ull * 2048);
  cvt(gwhh, UP(o_whhb), 768ull * 256);
  cvt(prw,  UP(o_prwb), 1024ull * 256);
  cvt(pow_, UP(o_powb), 1024ull * 1280);
  cvt(emb_v, UP(o_embvb), 8192ull * 512);
  cvt(emb_t, UP(o_embtb), 8192ull * 512);
  cvt(emb_p, UP(o_embpb), 8192ull * 256);

  transpose_bf<<<dim3(16, 32), 256, 0, stream>>>(pvw, 512, UP(o_sub + so_pTv), 1024);
  transpose_bf<<<dim3(16, 32), 256, 0, stream>>>(ptw, 512, UP(o_sub + so_pTt), 1024);
  transpose_bf<<<dim3(8, 32), 256, 0, stream>>>(ppw, 256, UP(o_sub + so_pTp), 1024);
  transpose_bf<<<dim3(32, 32), 256, 0, stream>>>(aow, 1024, UP(o_sub + so_aoT), 1024);
  transpose_bf<<<dim3(8, 32), 256, 0, stream>>>(pow_, 1280, UP(o_sub + so_WphT), 1024);

  matvec3<<<3072, 64, 0, stream>>>(aiw, pvb, ptb, ppb, aib, FP(o_bqkv));
  matvec_nt<<<1024, 64, 0, stream>>>(fw1, 3072, FP(o_rep), fb1, FP(o_bf1), 3072);

  // folded weights
  g_bf(UP(o_sub + so_aiwb), 1024, UP(o_sub + so_pTv), 1024, UP(o_wqv), 512,
       3072, 512, 1024, nullptr, nullptr, 0, nullptr, 0, 1, stream);
  g_bf(UP(o_sub + so_aiwb), 1024, UP(o_sub + so_pTt), 1024, UP(o_wqt), 512,
       3072, 512, 1024, nullptr, nullptr, 0, nullptr, 0, 1, stream);
  g_bf(UP(o_sub + so_aiwb), 1024, UP(o_sub + so_pTp), 1024, UP(o_wqp), 256,
       3072, 256, 1024, nullptr, nullptr, 0, nullptr, 0, 1, stream);
  for (int m = 0; m < 3; ++m)
    g_bf(UP(o_sub + so_fw1b) + m * 1024, 3072, UP(o_sub + so_aoT), 1024,
         UP(o_wf1) + m * 1024, 3072, 1024, 1024, 1024,
         nullptr, nullptr, 0, FP(o_imp) + m, 0, 1, stream);
  g_bf(UP(o_gwihb), 2048, UP(o_sub + so_WphT), 1024, UP(o_m1b), 256,
       768, 256, 1024, nullptr, nullptr, 0, nullptr, 0, 1, stream);

  wr_prep<<<1536, 256, 0, stream>>>(UP(o_m1b), UP(o_whhb), UP(o_wr));
  h0_prep<<<64, 256, 0, stream>>>(h0, UP(o_hist));

  // phase A: qkv (bf16) -> attention -> fused1
  const int nchunk = 8192 / NC;
  for (int c = 0; c < nchunk; ++c) {
    g_bf(UP(o_embvb) + (size_t)c * NC * 512, 512, UP(o_wqv), 512,
         UP(o_qkvc) + 0, 9216, NC, 3072, 512, FP(o_bqkv) + 0,
         nullptr, 0, nullptr, 0, 1, stream);
    g_bf(UP(o_embtb) + (size_t)c * NC * 512, 512, UP(o_wqt), 512,
         UP(o_qkvc) + 3072, 9216, NC, 3072, 512, FP(o_bqkv) + 3072,
         nullptr, 0, nullptr, 0, 1, stream);
    g_bf(UP(o_embpb) + (size_t)c * NC * 256, 256, UP(o_wqp), 256,
         UP(o_qkvc) + 6144, 9216, NC, 3072, 256, FP(o_bqkv) + 6144,
         nullptr, 0, nullptr, 0, 1, stream);
    attn3<<<NC, 256, 0, stream>>>(UP(o_qkvc), UP(o_attc));
    g_bf(UP(o_attc), 3072, UP(o_wf1), 3072,
         UP(o_fused1) + (size_t)c * NC * 1024, 1024, NC, 1024, 3072,
         FP(o_bf1), nullptr, 0, nullptr, 1 /*relu*/, 1, stream);
  }

  g_bf(UP(o_fused1), 1024, UP(o_fw2b), 1024, UP(o_fusedb), 1024,
       8192, 1024, 1024, fb2, nullptr, 0, nullptr, 0, 1, stream);
  layernorm_bf<<<8192, 256, 0, stream>>>(UP(o_fusedb), ln_g, ln_b);

  g_bf(UP(o_fusedb), 1024, UP(o_powb) + 256, 1280, FP(o_fpb), 1024,
       8192, 1024, 1024, pob, nullptr, 0, nullptr, 0, 0, stream);
  build_R_bf<<<8192, 256, 0, stream>>>(FP(o_fpb), noise, s0, UP(o_rbf));
  // Qr = [R | fused] @ gwih^T + (gbih + bhh_rz), written in frag-perm order
  g_bf(UP(o_rbf), 1024, UP(o_gwihb), 2048, FP(o_qr), 768,
       8192, 768, 2048, FP(o_cb768), nullptr, 0, nullptr, 0, 0, stream,
       UP(o_fusedb), 1024, 1024, nullptr, 0, 1 << 30, 0, 1 /*qperm*/);

  rssm_recur5<<<8, 256, 0, stream>>>(UP(o_wr), FP(o_qr), gbhh + 512, UP(o_hist),
                                     UP(o_hrow), out, (unsigned int*)(W + o_cnt));

  // prior | post in one dual-B GEMM (out cols 1280..3327)
  g_bf(UP(o_hrow), 256, UP(o_prwb), 256, out + 1280, 3328,
       8192, 2048, 256, FP(o_cb2048), FP(o_fpb), 1024, nullptr, 0, 0, stream,
       nullptr, 0, 1 << 30, UP(o_powb), 1280, 1024, 1024 /*src_c0*/, 0);
  s_out_k<<<8192, 256, 0, stream>>>(out, noise);
}

// Round 6
// 1359.115 us; speedup vs baseline: 1.5982x; 1.0702x over previous
//
#include <hip/hip_runtime.h>
#include <cstdint>
#include <cstddef>

#define F4(p)  (*(reinterpret_cast<float4*>(p)))
#define CF4(p) (*(reinterpret_cast<const float4*>(p)))

typedef __attribute__((ext_vector_type(8))) short short8;
typedef __attribute__((ext_vector_type(4))) float f32x4;
typedef __attribute__((ext_vector_type(4))) int i32x4;

__device__ __forceinline__ float bf2f(unsigned short h) {
  return __uint_as_float(((unsigned int)h) << 16);
}
__device__ __forceinline__ unsigned short f2bf(float x) {
  unsigned int u = __float_as_uint(x);
  return (unsigned short)((u + 0x7FFFu + ((u >> 16) & 1u)) >> 16);
}

#if __has_builtin(__builtin_amdgcn_global_load_lds)
#define USE_GLL 1
#else
#define USE_GLL 0
#endif
#if __has_builtin(__builtin_amdgcn_sched_barrier)
#define SCHED_BARRIER() __builtin_amdgcn_sched_barrier(0)
#else
#define SCHED_BARRIER()
#endif

__device__ __forceinline__ void stage16(unsigned short* lds_lane,
                                        unsigned short* lds_wavebase,
                                        const unsigned short* g) {
#if USE_GLL
  __builtin_amdgcn_global_load_lds(
      (const __attribute__((address_space(1))) unsigned int*)g,
      (__attribute__((address_space(3))) unsigned int*)lds_wavebase, 16, 0, 0);
#else
  *(short8*)lds_lane = *(const short8*)g;
#endif
}

// L2-coherent (same-XCD) 16B load/store: sc0 bypasses L0/L1; all workers are
// pinned to one XCD, so the shared L2 is the coherence point (no MALL trip).
__device__ __forceinline__ i32x4 coh_load16(const void* p) {
  i32x4 r;
  asm volatile("global_load_dwordx4 %0, %1, off sc0"
               : "=v"(r) : "v"(p) : "memory");
  return r;
}
__device__ __forceinline__ void coh_store16(void* p, i32x4 v) {
  asm volatile("global_store_dwordx4 %0, %1, off sc0"
               :: "v"(p), "v"(v) : "memory");
}

__device__ __forceinline__ float fsigmoid(float x) {
  return 1.0f / (1.0f + __expf(-x));
}
__device__ __forceinline__ float ftanh(float x) {
  float ax = fabsf(x);
  float e = __expf(2.0f * ax);
  float t = 1.0f - 2.0f / (e + 1.0f);
  return copysignf(t, x);
}

// =====================================================================
// bf16 MFMA GEMM: C = post( scale*(A@B^T) + bias + src )
// dual-A (k-split) and dual-B (n-split) supported. 128x128 tile, BK=64,
// 4 waves 2x2, XOR-swizzled LDS via pre-swizzled global source.
// qperm: write f32 C in the recurrence's Qr fragment order.
// src_c0: src added only for gc>=src_c0, at column (gc-src_c0).
// =====================================================================
__global__ __launch_bounds__(256) void gemm_bf(
    const unsigned short* __restrict__ A, int lda,
    const unsigned short* __restrict__ A2, int lda2, int kSplit,
    const unsigned short* __restrict__ B, int ldb,
    const unsigned short* __restrict__ B2, int ldb2, int nSplit,
    void* __restrict__ Cv, int ldc, int K,
    const float* __restrict__ bias,
    const float* __restrict__ src, int ldsrc, int src_c0,
    const float* __restrict__ scale_ptr, int relu, int obf16, int qperm)
{
  __shared__ unsigned short As[128 * 64];
  __shared__ unsigned short Bs[128 * 64];
  const int tid = threadIdx.x;
  const int wv = tid >> 6, ln = tid & 63;
  const int wm = wv >> 1, wn = wv & 1;
  const size_t gm0 = (size_t)blockIdx.y * 128;
  const size_t gn0 = (size_t)blockIdx.x * 128;

  f32x4 acc[4][4];
  #pragma unroll
  for (int i = 0; i < 4; ++i)
    #pragma unroll
    for (int j = 0; j < 4; ++j) acc[i][j] = (f32x4){0.f, 0.f, 0.f, 0.f};

  for (int kk = 0; kk < K; kk += 64) {
    const unsigned short* Ause = A; int lduse = lda; int kkA = kk;
    if (A2 != nullptr && kk >= kSplit) { Ause = A2; lduse = lda2; kkA = kk - kSplit; }
    #pragma unroll
    for (int j = 0; j < 4; ++j) {
      int idx = j * 256 + tid;
      int r = idx >> 3, u = idx & 7;
      int ksw = (u ^ (r & 7)) << 3;
      const unsigned short* ga = Ause + (gm0 + r) * lduse + kkA + ksw;
      stage16(&As[idx * 8], &As[(idx & ~63) * 8], ga);
      size_t nr = gn0 + r;
      const unsigned short* gb = (nr < (size_t)nSplit)
          ? B + nr * ldb + kk + ksw
          : B2 + (nr - nSplit) * ldb2 + kk + ksw;
      stage16(&Bs[idx * 8], &Bs[(idx & ~63) * 8], gb);
    }
    __syncthreads();
    #pragma unroll
    for (int ks = 0; ks < 2; ++ks) {
      short8 af[4], bfv[4];
      #pragma unroll
      for (int mi = 0; mi < 4; ++mi) {
        int r = wm * 64 + mi * 16 + (ln & 15);
        int u = (ks * 4 + (ln >> 4)) ^ (r & 7);
        af[mi] = *(const short8*)&As[(r * 8 + u) * 8];
      }
      #pragma unroll
      for (int nj = 0; nj < 4; ++nj) {
        int r = wn * 64 + nj * 16 + (ln & 15);
        int u = (ks * 4 + (ln >> 4)) ^ (r & 7);
        bfv[nj] = *(const short8*)&Bs[(r * 8 + u) * 8];
      }
      #pragma unroll
      for (int mi = 0; mi < 4; ++mi)
        #pragma unroll
        for (int nj = 0; nj < 4; ++nj)
          acc[mi][nj] = __builtin_amdgcn_mfma_f32_16x16x32_bf16(
              af[mi], bfv[nj], acc[mi][nj], 0, 0, 0);
    }
    __syncthreads();
  }

  float sc = scale_ptr ? *scale_ptr : 1.0f;
  #pragma unroll
  for (int nj = 0; nj < 4; ++nj) {
    int gc = (int)gn0 + wn * 64 + nj * 16 + (ln & 15);
    float bv = bias ? bias[gc] : 0.f;
    #pragma unroll
    for (int mi = 0; mi < 4; ++mi) {
      #pragma unroll
      for (int qq = 0; qq < 4; ++qq) {
        int gr = (int)gm0 + wm * 64 + mi * 16 + ((ln >> 4) << 2) + qq;
        float v = acc[mi][nj][qq] * sc + bv;
        if (src && gc >= src_c0) v += src[(size_t)gr * ldsrc + (gc - src_c0)];
        if (relu) v = fmaxf(v, 0.f);
        if (qperm) {
          int t = gr & 127, bq = gr >> 7;
          int g = gc >> 8, d = gc & 255;
          int ddq = d >> 5, doff = d & 31;
          int wq = bq >> 4;
          int lq = (bq & 15) + ((doff >> 3) << 4);
          size_t qi = (((((size_t)t * 8 + ddq) * 3 + g) * 4 + wq) * 64 + lq) * 8
                      + (doff & 7);
          ((float*)Cv)[qi] = v;
        } else if (obf16) {
          ((unsigned short*)Cv)[(size_t)gr * ldc + gc] = f2bf(v);
        } else {
          ((float*)Cv)[(size_t)gr * ldc + gc] = v;
        }
      }
    }
  }
}

// =====================================================================
__global__ __launch_bounds__(256) void cvt_bf(
    const float* __restrict__ in, unsigned short* __restrict__ outp, int n4)
{
  int i = blockIdx.x * 256 + threadIdx.x;
  if (i < n4) {
    float4 v = CF4(in + (size_t)i * 4);
    ushort4 o;
    o.x = f2bf(v.x); o.y = f2bf(v.y); o.z = f2bf(v.z); o.w = f2bf(v.w);
    *(ushort4*)(outp + (size_t)i * 4) = o;
  }
}

__global__ __launch_bounds__(256) void transpose_bf(
    const float* __restrict__ in, int ldin, unsigned short* __restrict__ outp, int R)
{
  __shared__ float tile[32][33];
  int c0 = blockIdx.x * 32, r0 = blockIdx.y * 32;
  int tx = threadIdx.x & 31, ty = threadIdx.x >> 5;
  #pragma unroll
  for (int i = ty; i < 32; i += 8)
    tile[i][tx] = in[(size_t)(r0 + i) * ldin + c0 + tx];
  __syncthreads();
  #pragma unroll
  for (int i = ty; i < 32; i += 8)
    outp[(size_t)(c0 + i) * R + r0 + tx] = f2bf(tile[tx][i]);
}

// out3[m*3072+i] = dot(A[i], x_m) + aib[i],  m=0..2 (A row read once)
__global__ __launch_bounds__(64) void matvec3(
    const float* __restrict__ A,
    const float* __restrict__ x0, const float* __restrict__ x1,
    const float* __restrict__ x2, const float* __restrict__ aib,
    float* __restrict__ outp)
{
  int i = blockIdx.x, t = threadIdx.x;
  const float* Ar = A + (size_t)i * 1024;
  float s0 = 0.f, s1 = 0.f, s2 = 0.f;
  for (int k = t * 4; k < 1024; k += 256) {
    float4 a = CF4(Ar + k);
    float4 v0 = CF4(x0 + k), v1 = CF4(x1 + k), v2 = CF4(x2 + k);
    s0 += a.x*v0.x + a.y*v0.y + a.z*v0.z + a.w*v0.w;
    s1 += a.x*v1.x + a.y*v1.y + a.z*v1.z + a.w*v1.w;
    s2 += a.x*v2.x + a.y*v2.y + a.z*v2.z + a.w*v2.w;
  }
  #pragma unroll
  for (int m = 32; m > 0; m >>= 1) {
    s0 += __shfl_xor(s0, m); s1 += __shfl_xor(s1, m); s2 += __shfl_xor(s2, m);
  }
  if (t == 0) {
    float b = aib[i];
    outp[i] = s0 + b; outp[3072 + i] = s1 + b; outp[6144 + i] = s2 + b;
  }
}

__global__ __launch_bounds__(64) void matvec_nt(
    const float* __restrict__ A, int lda,
    const float* __restrict__ x, const float* __restrict__ badd,
    float* __restrict__ outp, int K)
{
  int i = blockIdx.x, t = threadIdx.x;
  const float* Ar = A + (size_t)i * lda;
  float s = 0.f;
  for (int k = t * 4; k < K; k += 256) {
    float4 a = CF4(Ar + k);
    float4 xx = CF4(x + k);
    s += a.x*xx.x + a.y*xx.y + a.z*xx.z + a.w*xx.w;
  }
  #pragma unroll
  for (int m = 32; m > 0; m >>= 1) s += __shfl_xor(s, m);
  if (t == 0) outp[i] = s + (badd ? badd[i] : 0.f);
}

__global__ __launch_bounds__(256) void imp_rep_k(
    const float* __restrict__ importance, const float* __restrict__ aob,
    float* __restrict__ imp, float* __restrict__ rep)
{
  __shared__ float si[3];
  if (threadIdx.x == 0) {
    float a = importance[0], b = importance[1], c = importance[2];
    float mx = fmaxf(a, fmaxf(b, c));
    float ea = expf(a - mx), eb = expf(b - mx), ec = expf(c - mx);
    float inv = 1.f / (ea + eb + ec);
    si[0] = ea * inv; si[1] = eb * inv; si[2] = ec * inv;
    imp[0] = si[0]; imp[1] = si[1]; imp[2] = si[2];
  }
  __syncthreads();
  for (int idx = threadIdx.x; idx < 3072; idx += 256)
    rep[idx] = si[idx >> 10] * aob[idx & 1023];
}

// cb768 = gbih + [gbhh_r | gbhh_z | 0] ; cb2048 = [prb | 0]
__global__ __launch_bounds__(256) void bias_prep(
    const float* __restrict__ gbih, const float* __restrict__ gbhh,
    const float* __restrict__ prb, float* __restrict__ cb768,
    float* __restrict__ cb2048)
{
  int i = blockIdx.x * 256 + threadIdx.x;
  if (i < 768) cb768[i] = gbih[i] + (i < 512 ? gbhh[i] : 0.f);
  if (i < 2048) cb2048[i] = (i < 1024) ? prb[i] : 0.f;
}

// =====================================================================
// 3-token MHA, bf16 in -> bf16 out
// =====================================================================
__global__ __launch_bounds__(256) void attn3(
    const unsigned short* __restrict__ qkv, unsigned short* __restrict__ att)
{
  const int n = blockIdx.x;
  const unsigned short* row = qkv + (size_t)n * 9216;
  __shared__ float qk[6144];
  __shared__ float sc[72];
  __shared__ float pw[72];
  const int t = threadIdx.x;
  for (int idx = t; idx < 768; idx += 256) {
    int m = idx >> 7;                  // 0..5
    int off = (idx & 127) << 3;
    const unsigned short* srcp = (m < 3) ? (row + m * 3072 + off)
                                         : (row + (m - 3) * 3072 + 1024 + off);
    short8 v = *(const short8*)srcp;
    float* dst = &qk[m * 1024 + off];
    #pragma unroll
    for (int j = 0; j < 8; ++j) dst[j] = bf2f(((const unsigned short*)&v)[j]);
  }
  __syncthreads();
  if (t < 72) {
    int h = t / 9, i = (t % 9) / 3, j = t % 3;
    const float* qp = &qk[i * 1024 + h * 128];
    const float* kp = &qk[3072 + j * 1024 + h * 128];
    float s = 0.f;
    int rot = (t & 31) * 4;
    for (int d2 = 0; d2 < 128; ++d2) {
      int dx = (d2 + rot) & 127;
      s += qp[dx] * kp[dx];
    }
    sc[t] = s * 0.08838834764831845f;
  }
  __syncthreads();
  if (t < 24) {
    int base = t * 3;
    float a = sc[base], b = sc[base + 1], c = sc[base + 2];
    float mx = fmaxf(a, fmaxf(b, c));
    float ea = expf(a - mx), eb = expf(b - mx), ec = expf(c - mx);
    float inv = 1.f / (ea + eb + ec);
    pw[base] = ea * inv; pw[base + 1] = eb * inv; pw[base + 2] = ec * inv;
  }
  __syncthreads();
  unsigned short* outp = att + (size_t)n * 3072;
  #pragma unroll
  for (int rep = 0; rep < 3; ++rep) {
    int idx = (rep * 256 + t) << 2;
    int i = idx >> 10;
    int hd = idx & 1023;
    int h = hd >> 7;
    int pb = (h * 3 + i) * 3;
    float w0 = pw[pb], w1 = pw[pb + 1], w2 = pw[pb + 2];
    ushort4 v0 = *(const ushort4*)(row + 2048 + hd);
    ushort4 v1 = *(const ushort4*)(row + 3072 + 2048 + hd);
    ushort4 v2 = *(const ushort4*)(row + 6144 + 2048 + hd);
    ushort4 o;
    o.x = f2bf(w0 * bf2f(v0.x) + w1 * bf2f(v1.x) + w2 * bf2f(v2.x));
    o.y = f2bf(w0 * bf2f(v0.y) + w1 * bf2f(v1.y) + w2 * bf2f(v2.y));
    o.z = f2bf(w0 * bf2f(v0.z) + w1 * bf2f(v1.z) + w2 * bf2f(v2.z));
    o.w = f2bf(w0 * bf2f(v0.w) + w1 * bf2f(v1.w) + w2 * bf2f(v2.w));
    *(ushort4*)(outp + idx) = o;
  }
}

// =====================================================================
__global__ __launch_bounds__(256) void layernorm_bf(
    unsigned short* __restrict__ X, const float* __restrict__ g,
    const float* __restrict__ bta)
{
  int n = blockIdx.x, t = threadIdx.x;
  unsigned short* row = X + (size_t)n * 1024;
  ushort4 hv = *(ushort4*)(row + t * 4);
  float x0 = bf2f(hv.x), x1 = bf2f(hv.y), x2 = bf2f(hv.z), x3 = bf2f(hv.w);
  float s = x0 + x1 + x2 + x3;
  float ss = x0*x0 + x1*x1 + x2*x2 + x3*x3;
  #pragma unroll
  for (int m = 32; m > 0; m >>= 1) { s += __shfl_xor(s, m); ss += __shfl_xor(ss, m); }
  __shared__ float rs[4], rss[4];
  int w = t >> 6;
  if ((t & 63) == 0) { rs[w] = s; rss[w] = ss; }
  __syncthreads();
  s = rs[0] + rs[1] + rs[2] + rs[3];
  ss = rss[0] + rss[1] + rss[2] + rss[3];
  float mean = s * (1.0f / 1024.0f);
  float var = ss * (1.0f / 1024.0f) - mean * mean;
  float inv = 1.0f / sqrtf(var + 1e-5f);
  float4 gg = CF4(g + t * 4);
  float4 bb = CF4(bta + t * 4);
  ushort4 o;
  o.x = f2bf((x0 - mean) * inv * gg.x + bb.x);
  o.y = f2bf((x1 - mean) * inv * gg.y + bb.y);
  o.z = f2bf((x2 - mean) * inv * gg.z + bb.z);
  o.w = f2bf((x3 - mean) * inv * gg.w + bb.w);
  *(ushort4*)(row + t * 4) = o;
}

__global__ __launch_bounds__(256) void build_R_bf(
    const float* __restrict__ Fpb, const float* __restrict__ noise,
    const float* __restrict__ s0, unsigned short* __restrict__ R)
{
  size_t idx = (size_t)blockIdx.x * 256 + threadIdx.x;
  int n = (int)(idx >> 8);
  int k4 = (int)(idx & 255) << 2;
  float4 v;
  if ((n & 127) == 0) {
    v = CF4(s0 + (size_t)(n >> 7) * 1024 + k4);
  } else {
    float4 f = CF4(Fpb + (size_t)(n - 1) * 1024 + k4);
    float4 z = CF4(noise + (size_t)(n - 1) * 1024 + k4);
    v.x = f.x + z.x; v.y = f.y + z.y; v.z = f.z + z.z; v.w = f.w + z.w;
  }
  ushort4 o;
  o.x = f2bf(v.x); o.y = f2bf(v.y); o.z = f2bf(v.z); o.w = f2bf(v.w);
  *(ushort4*)(R + (size_t)n * 1024 + k4) = o;
}

__global__ __launch_bounds__(256) void s_out_k(
    float* __restrict__ outp, const float* __restrict__ noise)
{
  size_t idx = (size_t)blockIdx.x * 256 + threadIdx.x;
  int n = (int)(idx >> 8);
  int j4 = (int)(idx & 255) << 2;
  float4 p = CF4(outp + (size_t)n * 3328 + 2304 + j4);
  float4 z = CF4(noise + (size_t)n * 1024 + j4);
  float4 o; o.x = p.x + z.x; o.y = p.y + z.y; o.z = p.z + z.z; o.w = p.w + z.w;
  F4(outp + (size_t)n * 3328 + 256 + j4) = o;
}

// =====================================================================
// Recurrence weight prep: 8 d-slices x 12 row-tiles of 16 rows, B-frag order.
// =====================================================================
__global__ __launch_bounds__(256) void wr_prep(
    const unsigned short* __restrict__ M1bf, const unsigned short* __restrict__ Whhbf,
    unsigned short* __restrict__ Wr)
{
  int idx = blockIdx.x * 256 + threadIdx.x;   // < 393216
  int j = idx & 7, l = (idx >> 3) & 63, kt = (idx >> 9) & 7;
  int rest = idx >> 12;                        // dd*12 + r
  int r = rest % 12, dd = rest / 12;
  int g = r >> 1, dhalf = r & 1;
  int d = dd * 32 + dhalf * 16 + (l & 15);
  int srow = (g % 3) * 256 + d;
  int k = kt * 32 + ((l >> 4) << 3) + j;
  const unsigned short* srcp = (g < 3) ? M1bf : Whhbf;
  Wr[idx] = srcp[(size_t)srow * 256 + k];
}

// hist frag layout: [buf][w'][kt][l][j], b=16w'+(l&15), k=kt*32+(l>>4)*8+j
__global__ __launch_bounds__(256) void h0_prep(
    const float* __restrict__ h0, unsigned short* __restrict__ hist)
{
  int idx = blockIdx.x * 256 + threadIdx.x;   // < 16384
  int j = idx & 7, l = (idx >> 3) & 63, kt = (idx >> 9) & 7, w = idx >> 12;
  int b = 16 * w + (l & 15);
  int k = kt * 32 + ((l >> 4) << 3) + j;
  hist[idx] = f2bf(h0[(size_t)b * 256 + k]);
}

// =====================================================================
// Sequential RSSM v6. 256 blocks launched (1/CU); 8 workers ELECTED on
// XCD 0 via HW_REG_XCC_ID + per-XCD rank (others exit). All workers share
// one L2 -> h exchange is sc0-only (no MALL round-trip). Weights
// register-resident; barrier: vmcnt(0) -> sync -> relaxed atomic add ->
// background Hrow/out/Q-prefetch -> relaxed poll (tid0) -> sync.
// counters[0]=barrier, counters[8..15]=election ranks.
// =====================================================================
#define LOADQ(tt) do { \
  _Pragma("unroll") \
  for (int g = 0; g < 3; ++g) { \
    const float* qp = Qr + (((((size_t)(tt) * 8 + dd) * 3 + g) * 4 + w) * 64 + l) * 8; \
    float4 qa = CF4(qp); float4 qb = CF4(qp + 4); \
    qv[g][0] = qa.x; qv[g][1] = qa.y; qv[g][2] = qa.z; qv[g][3] = qa.w; \
    qv[g][4] = qb.x; qv[g][5] = qb.y; qv[g][6] = qb.z; qv[g][7] = qb.w; \
  } } while (0)

__global__ __launch_bounds__(256, 1) void rssm_recur6(
    const unsigned short* __restrict__ Wr, const float* __restrict__ Qr,
    const float* __restrict__ bhh_n, unsigned short* __restrict__ hist,
    unsigned short* __restrict__ Hrow, float* __restrict__ outp,
    unsigned int* __restrict__ counters)
{
  const int tid = threadIdx.x;
  __shared__ int s_role;
  if (tid == 0) {
    unsigned int xcc;
    asm volatile("s_getreg_b32 %0, hwreg(HW_REG_XCC_ID)" : "=s"(xcc));
    int role = -1;
    if ((xcc & 7u) == 0u) {
      unsigned int r = __hip_atomic_fetch_add(&counters[8], 1u, __ATOMIC_RELAXED,
                                              __HIP_MEMORY_SCOPE_AGENT);
      if (r < 8u) role = (int)r;
    }
    s_role = role;
  }
  __syncthreads();
  const int dd = s_role;                 // 0..7 for workers
  if (dd < 0) return;

  const int w = tid >> 6, l = tid & 63;
  __shared__ float G[12][16][68];            // 52KB gate exchange
  __shared__ unsigned short hL[16384];       // 32KB staged h frags

  // persistent B-frags: 3 row-tiles x 8 kt (96 VGPR)
  short8 Bf[3][8];
  {
    const unsigned short* wb = Wr + ((size_t)(dd * 12 + w * 3) * 8) * 512 + l * 8;
    #pragma unroll
    for (int ri = 0; ri < 3; ++ri)
      #pragma unroll
      for (int kt = 0; kt < 8; ++kt)
        Bf[ri][kt] = *(const short8*)(wb + (size_t)(ri * 8 + kt) * 512);
  }
  float bhn[8];
  #pragma unroll
  for (int j = 0; j < 8; ++j) bhn[j] = bhh_n[dd * 32 + ((l >> 4) << 3) + j];

  const int bg = w * 16 + (l & 15);       // GRU batch row
  const int dhalf = l >> 5;               // 0..1
  const int d16b = ((l >> 4) & 1) << 3;   // 0 or 8
  float qv[3][8];
  LOADQ(0);

  unsigned int target = 0;
  #pragma unroll 1
  for (int t = 0; t < 128; ++t) {
    // ---- stage hist[t&1] -> hL via L2-coherent loads ----
    const unsigned short* hsrc = hist + (size_t)(t & 1) * 16384;
    i32x4 sv[8];
    #pragma unroll
    for (int j = 0; j < 8; ++j)
      sv[j] = coh_load16(hsrc + (size_t)(j * 256 + tid) * 8);
    asm volatile("s_waitcnt vmcnt(0)" ::: "memory");
    SCHED_BARRIER();
    #pragma unroll
    for (int j = 0; j < 8; ++j)
      *(i32x4*)&hL[(size_t)(j * 256 + tid) * 8] = sv[j];
    __syncthreads();

    // ---- MFMA: 96 per wave ----
    f32x4 acc[4][3];
    #pragma unroll
    for (int bt = 0; bt < 4; ++bt)
      #pragma unroll
      for (int ri = 0; ri < 3; ++ri) acc[bt][ri] = (f32x4){0.f, 0.f, 0.f, 0.f};
    #pragma unroll
    for (int kt = 0; kt < 8; ++kt)
      #pragma unroll
      for (int bt = 0; bt < 4; ++bt) {
        short8 a = *(const short8*)&hL[((bt * 8 + kt) * 64 + l) * 8];
        acc[bt][0] = __builtin_amdgcn_mfma_f32_16x16x32_bf16(a, Bf[0][kt], acc[bt][0], 0, 0, 0);
        acc[bt][1] = __builtin_amdgcn_mfma_f32_16x16x32_bf16(a, Bf[1][kt], acc[bt][1], 0, 0, 0);
        acc[bt][2] = __builtin_amdgcn_mfma_f32_16x16x32_bf16(a, Bf[2][kt], acc[bt][2], 0, 0, 0);
      }
    short8 ha = *(const short8*)&hL[((w * 8 + dd) * 64 + l) * 8];

    // ---- gate exchange (vector ds_write_b128) ----
    #pragma unroll
    for (int bt = 0; bt < 4; ++bt)
      #pragma unroll
      for (int ri = 0; ri < 3; ++ri)
        *(f32x4*)&G[w * 3 + ri][l & 15][bt * 16 + ((l >> 4) << 2)] = acc[bt][ri];
    __syncthreads();

    // ---- GRU: 8 cells (b = bg, d = dd*32 + (l>>4)*8 + j) ----
    const float m1s = (t == 0) ? 0.f : 1.f;
    unsigned short hn8[8];
    float hf8[8];
    #pragma unroll
    for (int j = 0; j < 8; ++j) {
      int d16 = d16b + j;
      float m1r = G[0 + dhalf][d16][bg];
      float m1z = G[2 + dhalf][d16][bg];
      float m1n = G[4 + dhalf][d16][bg];
      float ghr = G[6 + dhalf][d16][bg];
      float ghz = G[8 + dhalf][d16][bg];
      float ghn = G[10 + dhalf][d16][bg] + bhn[j];
      float gir = fmaf(m1r, m1s, qv[0][j]);
      float giz = fmaf(m1z, m1s, qv[1][j]);
      float gin = fmaf(m1n, m1s, qv[2][j]);
      float r = fsigmoid(gir + ghr);
      float z = fsigmoid(giz + ghz);
      float nn = ftanh(gin + r * ghn);
      float hold = bf2f(((const unsigned short*)&ha)[j]);
      float hn = (1.f - z) * nn + z * hold;
      unsigned short hbv = f2bf(hn);
      hn8[j] = hbv;
      hf8[j] = bf2f(hbv);
    }

    // ---- L2-coherent h store (the only store on the critical path) ----
    union { short8 s; i32x4 i; } hu;
    hu.s = *(const short8*)hn8;
    coh_store16(hist + (size_t)((t + 1) & 1) * 16384
                + (size_t)((w * 8 + dd) * 64 + l) * 8, hu.i);

    if (t < 127) {
      asm volatile("s_waitcnt vmcnt(0)" ::: "memory");   // h store in L2
      __syncthreads();                                   // all 256 threads done
      target += 8;
      if (tid == 0)
        __hip_atomic_fetch_add(&counters[0], 1u, __ATOMIC_RELAXED,
                               __HIP_MEMORY_SCOPE_AGENT);
      // background work — drains during the poll
      LOADQ(t + 1);
      *(short8*)(Hrow + (size_t)(bg * 128 + t) * 256 + dd * 32 + ((l >> 4) << 3)) =
          *(const short8*)hn8;
      float* op = outp + (size_t)(bg * 128 + t) * 3328 + dd * 32 + ((l >> 4) << 3);
      float4 o0; o0.x = hf8[0]; o0.y = hf8[1]; o0.z = hf8[2]; o0.w = hf8[3];
      float4 o1; o1.x = hf8[4]; o1.y = hf8[5]; o1.z = hf8[6]; o1.w = hf8[7];
      F4(op) = o0; F4(op + 4) = o1;
      if (tid == 0) {
        while (__hip_atomic_load(&counters[0], __ATOMIC_RELAXED,
                                 __HIP_MEMORY_SCOPE_AGENT) < target) {}
      }
      __syncthreads();
    } else {
      *(short8*)(Hrow + (size_t)(bg * 128 + t) * 256 + dd * 32 + ((l >> 4) << 3)) =
          *(const short8*)hn8;
      float* op = outp + (size_t)(bg * 128 + t) * 3328 + dd * 32 + ((l >> 4) << 3);
      float4 o0; o0.x = hf8[0]; o0.y = hf8[1]; o0.z = hf8[2]; o0.w = hf8[3];
      float4 o1; o1.x = hf8[4]; o1.y = hf8[5]; o1.z = hf8[6]; o1.w = hf8[7];
      F4(op) = o0; F4(op + 4) = o1;
    }
  }
}

// =====================================================================
// Host side
// =====================================================================
static inline void g_bf(const unsigned short* A, int lda,
                        const unsigned short* B, int ldb,
                        void* C, int ldc, int M, int N, int K,
                        const float* bias, const float* src, int ldsrc,
                        const float* scale, int relu, int obf16, hipStream_t s,
                        const unsigned short* A2 = nullptr, int lda2 = 0,
                        int kSplit = 1 << 30,
                        const unsigned short* B2 = nullptr, int ldb2 = 0,
                        int nSplit = 1 << 30,
                        int src_c0 = 0, int qperm = 0)
{
  dim3 grid(N / 128, M / 128);
  gemm_bf<<<grid, 256, 0, s>>>(A, lda, A2, lda2, kSplit, B, ldb, B2, ldb2, nSplit,
                               C, ldc, K, bias, src, ldsrc, src_c0, scale, relu,
                               obf16, qperm);
}

extern "C" void kernel_launch(void* const* d_in, const int* in_sizes, int n_in,
                              void* d_out, int out_size, void* d_ws, size_t ws_size,
                              hipStream_t stream)
{
  (void)in_sizes; (void)n_in; (void)out_size;

  const float* emb_v = (const float*)d_in[0];
  const float* emb_t = (const float*)d_in[1];
  const float* emb_p = (const float*)d_in[2];
  const float* noise = (const float*)d_in[3];
  const float* h0    = (const float*)d_in[4];
  const float* s0    = (const float*)d_in[5];
  const float* pvw   = (const float*)d_in[6];
  const float* pvb   = (const float*)d_in[7];
  const float* ptw   = (const float*)d_in[8];
  const float* ptb   = (const float*)d_in[9];
  const float* ppw   = (const float*)d_in[10];
  const float* ppb   = (const float*)d_in[11];
  const float* aiw   = (const float*)d_in[12];
  const float* aib   = (const float*)d_in[13];
  const float* aow   = (const float*)d_in[14];
  const float* aob   = (const float*)d_in[15];
  const float* importance = (const float*)d_in[16];
  const float* fw1   = (const float*)d_in[17];
  const float* fb1   = (const float*)d_in[18];
  const float* fw2   = (const float*)d_in[19];
  const float* fb2   = (const float*)d_in[20];
  const float* ln_g  = (const float*)d_in[21];
  const float* ln_b  = (const float*)d_in[22];
  const float* gwih  = (const float*)d_in[23];
  const float* gwhh  = (const float*)d_in[24];
  const float* gbih  = (const float*)d_in[25];
  const float* gbhh  = (const float*)d_in[26];
  const float* prw   = (const float*)d_in[27];
  const float* prb   = (const float*)d_in[28];
  const float* pow_  = (const float*)d_in[29];
  const float* pob   = (const float*)d_in[30];

  float* out = (float*)d_out;
  char* W = (char*)d_ws;

  size_t off = 0;
  auto alloc = [&](size_t bytes) { off = (off + 63) & ~63ull; size_t o = off; off += bytes; return o; };
  const size_t o_cnt    = alloc(256);
  const size_t o_imp    = alloc(16);
  const size_t o_rep    = alloc(3072 * 4);
  const size_t o_bqkv   = alloc(9216 * 4);
  const size_t o_bf1    = alloc(1024 * 4);
  const size_t o_cb768  = alloc(768 * 4);
  const size_t o_cb2048 = alloc(2048 * 4);
  const size_t o_gwihb  = alloc(768ull * 2048 * 2);
  const size_t o_whhb   = alloc(768ull * 256 * 2);
  const size_t o_m1b    = alloc(768ull * 256 * 2);
  const size_t o_prwb   = alloc(1024ull * 256 * 2);
  const size_t o_powb   = alloc(1024ull * 1280 * 2);
  const size_t o_wr     = alloc(393216ull * 2);
  const size_t o_hist   = alloc(2ull * 16384 * 2);
  const size_t o_hrow   = alloc(8192ull * 256 * 2);
  const size_t o_fusedb = alloc(8192ull * 1024 * 2);
  const size_t o_fpb    = alloc(8192ull * 1024 * 4);
  const size_t o_rbf    = alloc(8192ull * 1024 * 2);
  const size_t o_embvb  = alloc(8192ull * 512 * 2);
  const size_t o_embtb  = alloc(8192ull * 512 * 2);
  const size_t o_embpb  = alloc(8192ull * 256 * 2);
  const size_t o_wqv    = alloc(3072ull * 512 * 2);
  const size_t o_wqt    = alloc(3072ull * 512 * 2);
  const size_t o_wqp    = alloc(3072ull * 256 * 2);
  const size_t o_wf1    = alloc(1024ull * 3072 * 2);
  const size_t o_fw2b   = alloc(1024ull * 1024 * 2);
  const size_t o_fused1 = alloc(8192ull * 1024 * 2);
  const size_t o_sub    = (off + 63) & ~63ull;

  // sub-pool (time-shared): prep temps -> per-chunk qkv/att -> Qr
  const size_t so_aiwb = 0;
  const size_t so_fw1b = so_aiwb + 3072ull * 1024 * 2;
  const size_t so_pTv  = so_fw1b + 1024ull * 3072 * 2;
  const size_t so_pTt  = so_pTv + 512ull * 1024 * 2;
  const size_t so_pTp  = so_pTt + 512ull * 1024 * 2;
  const size_t so_aoT  = so_pTp + 256ull * 1024 * 2;
  const size_t so_WphT = so_aoT + 1024ull * 1024 * 2;
  const size_t prep_bytes = so_WphT + 256ull * 1024 * 2;
  const size_t q_bytes = 8192ull * 768 * 4;

  int NC = 512;
  for (int cand : {8192, 4096, 2048, 1024}) {
    size_t sub = prep_bytes > q_bytes ? prep_bytes : q_bytes;
    size_t cb = (size_t)cand * 9216 * 2 + (size_t)cand * 3072 * 2;
    if (cb > sub) sub = cb;
    if (o_sub + sub <= ws_size) { NC = cand; break; }
  }
  const size_t o_qkvc = o_sub;
  const size_t o_attc = o_sub + (size_t)NC * 9216 * 2;
  const size_t o_qr   = o_sub;

  auto FP = [&](size_t o) { return (float*)(W + o); };
  auto UP = [&](size_t o) { return (unsigned short*)(W + o); };

  hipMemsetAsync(W + o_cnt, 0, 256, stream);
  imp_rep_k<<<1, 256, 0, stream>>>(importance, aob, FP(o_imp), FP(o_rep));
  bias_prep<<<8, 256, 0, stream>>>(gbih, gbhh, prb, FP(o_cb768), FP(o_cb2048));

  auto cvt = [&](const float* in, unsigned short* op, size_t n) {
    int n4 = (int)(n / 4);
    cvt_bf<<<(n4 + 255) / 256, 256, 0, stream>>>(in, op, n4);
  };
  cvt(aiw,  UP(o_sub + so_aiwb), 3072ull * 1024);
  cvt(fw1,  UP(o_sub + so_fw1b), 1024ull * 3072);
  cvt(fw2,  UP(o_fw2b), 1024ull * 1024);
  cvt(gwih, UP(o_gwihb), 768ull * 2048);
  cvt(gwhh, UP(o_whhb), 768ull * 256);
  cvt(prw,  UP(o_prwb), 1024ull * 256);
  cvt(pow_, UP(o_powb), 1024ull * 1280);
  cvt(emb_v, UP(o_embvb), 8192ull * 512);
  cvt(emb_t, UP(o_embtb), 8192ull * 512);
  cvt(emb_p, UP(o_embpb), 8192ull * 256);

  transpose_bf<<<dim3(16, 32), 256, 0, stream>>>(pvw, 512, UP(o_sub + so_pTv), 1024);
  transpose_bf<<<dim3(16, 32), 256, 0, stream>>>(ptw, 512, UP(o_sub + so_pTt), 1024);
  transpose_bf<<<dim3(8, 32), 256, 0, stream>>>(ppw, 256, UP(o_sub + so_pTp), 1024);
  transpose_bf<<<dim3(32, 32), 256, 0, stream>>>(aow, 1024, UP(o_sub + so_aoT), 1024);
  transpose_bf<<<dim3(8, 32), 256, 0, stream>>>(pow_, 1280, UP(o_sub + so_WphT), 1024);

  matvec3<<<3072, 64, 0, stream>>>(aiw, pvb, ptb, ppb, aib, FP(o_bqkv));
  matvec_nt<<<1024, 64, 0, stream>>>(fw1, 3072, FP(o_rep), fb1, FP(o_bf1), 3072);

  // folded weights
  g_bf(UP(o_sub + so_aiwb), 1024, UP(o_sub + so_pTv), 1024, UP(o_wqv), 512,
       3072, 512, 1024, nullptr, nullptr, 0, nullptr, 0, 1, stream);
  g_bf(UP(o_sub + so_aiwb), 1024, UP(o_sub + so_pTt), 1024, UP(o_wqt), 512,
       3072, 512, 1024, nullptr, nullptr, 0, nullptr, 0, 1, stream);
  g_bf(UP(o_sub + so_aiwb), 1024, UP(o_sub + so_pTp), 1024, UP(o_wqp), 256,
       3072, 256, 1024, nullptr, nullptr, 0, nullptr, 0, 1, stream);
  for (int m = 0; m < 3; ++m)
    g_bf(UP(o_sub + so_fw1b) + m * 1024, 3072, UP(o_sub + so_aoT), 1024,
         UP(o_wf1) + m * 1024, 3072, 1024, 1024, 1024,
         nullptr, nullptr, 0, FP(o_imp) + m, 0, 1, stream);
  g_bf(UP(o_gwihb), 2048, UP(o_sub + so_WphT), 1024, UP(o_m1b), 256,
       768, 256, 1024, nullptr, nullptr, 0, nullptr, 0, 1, stream);

  wr_prep<<<1536, 256, 0, stream>>>(UP(o_m1b), UP(o_whhb), UP(o_wr));
  h0_prep<<<64, 256, 0, stream>>>(h0, UP(o_hist));

  // phase A: qkv (bf16) -> attention -> fused1
  const int nchunk = 8192 / NC;
  for (int c = 0; c < nchunk; ++c) {
    g_bf(UP(o_embvb) + (size_t)c * NC * 512, 512, UP(o_wqv), 512,
         UP(o_qkvc) + 0, 9216, NC, 3072, 512, FP(o_bqkv) + 0,
         nullptr, 0, nullptr, 0, 1, stream);
    g_bf(UP(o_embtb) + (size_t)c * NC * 512, 512, UP(o_wqt), 512,
         UP(o_qkvc) + 3072, 9216, NC, 3072, 512, FP(o_bqkv) + 3072,
         nullptr, 0, nullptr, 0, 1, stream);
    g_bf(UP(o_embpb) + (size_t)c * NC * 256, 256, UP(o_wqp), 256,
         UP(o_qkvc) + 6144, 9216, NC, 3072, 256, FP(o_bqkv) + 6144,
         nullptr, 0, nullptr, 0, 1, stream);
    attn3<<<NC, 256, 0, stream>>>(UP(o_qkvc), UP(o_attc));
    g_bf(UP(o_attc), 3072, UP(o_wf1), 3072,
         UP(o_fused1) + (size_t)c * NC * 1024, 1024, NC, 1024, 3072,
         FP(o_bf1), nullptr, 0, nullptr, 1 /*relu*/, 1, stream);
  }

  g_bf(UP(o_fused1), 1024, UP(o_fw2b), 1024, UP(o_fusedb), 1024,
       8192, 1024, 1024, fb2, nullptr, 0, nullptr, 0, 1, stream);
  layernorm_bf<<<8192, 256, 0, stream>>>(UP(o_fusedb), ln_g, ln_b);

  g_bf(UP(o_fusedb), 1024, UP(o_powb) + 256, 1280, FP(o_fpb), 1024,
       8192, 1024, 1024, pob, nullptr, 0, nullptr, 0, 0, stream);
  build_R_bf<<<8192, 256, 0, stream>>>(FP(o_fpb), noise, s0, UP(o_rbf));
  // Qr = [R | fused] @ gwih^T + (gbih + bhh_rz), written in frag-perm order
  g_bf(UP(o_rbf), 1024, UP(o_gwihb), 2048, FP(o_qr), 768,
       8192, 768, 2048, FP(o_cb768), nullptr, 0, nullptr, 0, 0, stream,
       UP(o_fusedb), 1024, 1024, nullptr, 0, 1 << 30, 0, 1 /*qperm*/);

  rssm_recur6<<<256, 256, 0, stream>>>(UP(o_wr), FP(o_qr), gbhh + 512, UP(o_hist),
                                       UP(o_hrow), out, (unsigned int*)(W + o_cnt));

  // prior | post in one dual-B GEMM (out cols 1280..3327)
  g_bf(UP(o_hrow), 256, UP(o_prwb), 256, out + 1280, 3328,
       8192, 2048, 256, FP(o_cb2048), FP(o_fpb), 1024, nullptr, 0, 0, stream,
       nullptr, 0, 1 << 30, UP(o_powb), 1280, 1024, 1024 /*src_c0*/, 0);
  s_out_k<<<8192, 256, 0, stream>>>(out, noise);
}

// Round 7
// 1254.731 us; speedup vs baseline: 1.7312x; 1.0832x over previous
//
#include <hip/hip_runtime.h>
#include <cstdint>
#include <cstddef>

#define F4(p)  (*(reinterpret_cast<float4*>(p)))
#define CF4(p) (*(reinterpret_cast<const float4*>(p)))

typedef __attribute__((ext_vector_type(8))) short short8;
typedef __attribute__((ext_vector_type(4))) float f32x4;
typedef __attribute__((ext_vector_type(4))) int i32x4;

__device__ __forceinline__ float bf2f(unsigned short h) {
  return __uint_as_float(((unsigned int)h) << 16);
}
__device__ __forceinline__ unsigned short f2bf(float x) {
  unsigned int u = __float_as_uint(x);
  return (unsigned short)((u + 0x7FFFu + ((u >> 16) & 1u)) >> 16);
}

#if __has_builtin(__builtin_amdgcn_global_load_lds)
#define USE_GLL 1
#else
#define USE_GLL 0
#endif
#if __has_builtin(__builtin_amdgcn_sched_barrier)
#define SCHED_BARRIER() __builtin_amdgcn_sched_barrier(0)
#else
#define SCHED_BARRIER()
#endif

__device__ __forceinline__ void stage16(unsigned short* lds_lane,
                                        unsigned short* lds_wavebase,
                                        const unsigned short* g) {
#if USE_GLL
  __builtin_amdgcn_global_load_lds(
      (const __attribute__((address_space(1))) unsigned int*)g,
      (__attribute__((address_space(3))) unsigned int*)lds_wavebase, 16, 0, 0);
#else
  *(short8*)lds_lane = *(const short8*)g;
#endif
}

// L2-coherent (same-XCD) 16B load/store: sc0 bypasses L0/L1; all workers are
// pinned to one XCD, so the shared L2 is the coherence point (no MALL trip).
__device__ __forceinline__ i32x4 coh_load16(const void* p) {
  i32x4 r;
  asm volatile("global_load_dwordx4 %0, %1, off sc0"
               : "=v"(r) : "v"(p) : "memory");
  return r;
}
__device__ __forceinline__ void coh_store16(void* p, i32x4 v) {
  asm volatile("global_store_dwordx4 %0, %1, off sc0"
               :: "v"(p), "v"(v) : "memory");
}

__device__ __forceinline__ float frcp(float x) {
  float r;
  asm("v_rcp_f32 %0, %1" : "=v"(r) : "v"(x));
  return r;
}
__device__ __forceinline__ float fsigmoid(float x) {
  return frcp(1.0f + __expf(-x));
}
__device__ __forceinline__ float ftanh(float x) {
  float ax = fabsf(x);
  float e = __expf(2.0f * ax);
  float t = 1.0f - 2.0f * frcp(e + 1.0f);
  return copysignf(t, x);
}

// =====================================================================
// bf16 MFMA GEMM: C = post( scale*(A@B^T) + bias + src )
// dual-A (k-split) and dual-B (n-split) supported. 128x128 tile, BK=64,
// 4 waves 2x2, XOR-swizzled LDS via pre-swizzled global source.
// qperm: write f32 C in the recurrence's Qr fragment order.
// src_c0: src added only for gc>=src_c0, at column (gc-src_c0).
// XCD-aware bijective blockIdx swizzle (m204) for L2 locality.
// =====================================================================
__global__ __launch_bounds__(256) void gemm_bf(
    const unsigned short* __restrict__ A, int lda,
    const unsigned short* __restrict__ A2, int lda2, int kSplit,
    const unsigned short* __restrict__ B, int ldb,
    const unsigned short* __restrict__ B2, int ldb2, int nSplit,
    void* __restrict__ Cv, int ldc, int K,
    const float* __restrict__ bias,
    const float* __restrict__ src, int ldsrc, int src_c0,
    const float* __restrict__ scale_ptr, int relu, int obf16, int qperm)
{
  __shared__ unsigned short As[128 * 64];
  __shared__ unsigned short Bs[128 * 64];
  const int tid = threadIdx.x;
  const int wv = tid >> 6, ln = tid & 63;
  const int wm = wv >> 1, wn = wv & 1;

  // bijective XCD swizzle
  int nwg = (int)(gridDim.x * gridDim.y);
  int orig = (int)(blockIdx.y * gridDim.x + blockIdx.x);
  int q8 = nwg >> 3, r8 = nwg & 7;
  int xcd = orig & 7, ii = orig >> 3;
  int wg = (xcd < r8 ? xcd * (q8 + 1) : r8 * (q8 + 1) + (xcd - r8) * q8) + ii;
  const size_t gm0 = (size_t)(wg / (int)gridDim.x) * 128;
  const size_t gn0 = (size_t)(wg % (int)gridDim.x) * 128;

  f32x4 acc[4][4];
  #pragma unroll
  for (int i = 0; i < 4; ++i)
    #pragma unroll
    for (int j = 0; j < 4; ++j) acc[i][j] = (f32x4){0.f, 0.f, 0.f, 0.f};

  for (int kk = 0; kk < K; kk += 64) {
    const unsigned short* Ause = A; int lduse = lda; int kkA = kk;
    if (A2 != nullptr && kk >= kSplit) { Ause = A2; lduse = lda2; kkA = kk - kSplit; }
    #pragma unroll
    for (int j = 0; j < 4; ++j) {
      int idx = j * 256 + tid;
      int r = idx >> 3, u = idx & 7;
      int ksw = (u ^ (r & 7)) << 3;
      const unsigned short* ga = Ause + (gm0 + r) * lduse + kkA + ksw;
      stage16(&As[idx * 8], &As[(idx & ~63) * 8], ga);
      size_t nr = gn0 + r;
      const unsigned short* gb = (nr < (size_t)nSplit)
          ? B + nr * ldb + kk + ksw
          : B2 + (nr - nSplit) * ldb2 + kk + ksw;
      stage16(&Bs[idx * 8], &Bs[(idx & ~63) * 8], gb);
    }
    __syncthreads();
    #pragma unroll
    for (int ks = 0; ks < 2; ++ks) {
      short8 af[4], bfv[4];
      #pragma unroll
      for (int mi = 0; mi < 4; ++mi) {
        int r = wm * 64 + mi * 16 + (ln & 15);
        int u = (ks * 4 + (ln >> 4)) ^ (r & 7);
        af[mi] = *(const short8*)&As[(r * 8 + u) * 8];
      }
      #pragma unroll
      for (int nj = 0; nj < 4; ++nj) {
        int r = wn * 64 + nj * 16 + (ln & 15);
        int u = (ks * 4 + (ln >> 4)) ^ (r & 7);
        bfv[nj] = *(const short8*)&Bs[(r * 8 + u) * 8];
      }
      #pragma unroll
      for (int mi = 0; mi < 4; ++mi)
        #pragma unroll
        for (int nj = 0; nj < 4; ++nj)
          acc[mi][nj] = __builtin_amdgcn_mfma_f32_16x16x32_bf16(
              af[mi], bfv[nj], acc[mi][nj], 0, 0, 0);
    }
    __syncthreads();
  }

  float sc = scale_ptr ? *scale_ptr : 1.0f;
  #pragma unroll
  for (int nj = 0; nj < 4; ++nj) {
    int gc = (int)gn0 + wn * 64 + nj * 16 + (ln & 15);
    float bv = bias ? bias[gc] : 0.f;
    #pragma unroll
    for (int mi = 0; mi < 4; ++mi) {
      #pragma unroll
      for (int qq = 0; qq < 4; ++qq) {
        int gr = (int)gm0 + wm * 64 + mi * 16 + ((ln >> 4) << 2) + qq;
        float v = acc[mi][nj][qq] * sc + bv;
        if (src && gc >= src_c0) v += src[(size_t)gr * ldsrc + (gc - src_c0)];
        if (relu) v = fmaxf(v, 0.f);
        if (qperm) {
          int t = gr & 127, bq = gr >> 7;
          int g = gc >> 8, d = gc & 255;
          int ddq = d >> 5, doff = d & 31;
          int wq = bq >> 4;
          int lq = (bq & 15) + ((doff >> 3) << 4);
          size_t qi = (((((size_t)t * 8 + ddq) * 3 + g) * 4 + wq) * 64 + lq) * 8
                      + (doff & 7);
          ((float*)Cv)[qi] = v;
        } else if (obf16) {
          ((unsigned short*)Cv)[(size_t)gr * ldc + gc] = f2bf(v);
        } else {
          ((float*)Cv)[(size_t)gr * ldc + gc] = v;
        }
      }
    }
  }
}

// =====================================================================
// Batched fp32 -> bf16 conversion: 10 segments in one launch.
// Segment chosen by block range (uniform per block).
// =====================================================================
struct CvtArgs {
  const float* src[10];
  unsigned short* dst[10];
  int bend[10];   // cumulative block ends
  int n4[10];     // float4 count per segment
};

__global__ __launch_bounds__(256) void cvt_all(CvtArgs a)
{
  int b = blockIdx.x;
  int s = 0;
  #pragma unroll
  for (int k = 0; k < 10; ++k) s += (b >= a.bend[k]);
  int bstart = (s == 0) ? 0 : a.bend[s - 1];
  int i = (b - bstart) * 256 + threadIdx.x;
  if (i < a.n4[s]) {
    float4 v = CF4(a.src[s] + (size_t)i * 4);
    ushort4 o;
    o.x = f2bf(v.x); o.y = f2bf(v.y); o.z = f2bf(v.z); o.w = f2bf(v.w);
    *(ushort4*)(a.dst[s] + (size_t)i * 4) = o;
  }
}

__global__ __launch_bounds__(256) void transpose_bf(
    const float* __restrict__ in, int ldin, unsigned short* __restrict__ outp, int R)
{
  __shared__ float tile[32][33];
  int c0 = blockIdx.x * 32, r0 = blockIdx.y * 32;
  int tx = threadIdx.x & 31, ty = threadIdx.x >> 5;
  #pragma unroll
  for (int i = ty; i < 32; i += 8)
    tile[i][tx] = in[(size_t)(r0 + i) * ldin + c0 + tx];
  __syncthreads();
  #pragma unroll
  for (int i = ty; i < 32; i += 8)
    outp[(size_t)(c0 + i) * R + r0 + tx] = f2bf(tile[tx][i]);
}

// out3[m*3072+i] = dot(A[i], x_m) + aib[i],  m=0..2 (A row read once)
__global__ __launch_bounds__(64) void matvec3(
    const float* __restrict__ A,
    const float* __restrict__ x0, const float* __restrict__ x1,
    const float* __restrict__ x2, const float* __restrict__ aib,
    float* __restrict__ outp)
{
  int i = blockIdx.x, t = threadIdx.x;
  const float* Ar = A + (size_t)i * 1024;
  float s0 = 0.f, s1 = 0.f, s2 = 0.f;
  for (int k = t * 4; k < 1024; k += 256) {
    float4 a = CF4(Ar + k);
    float4 v0 = CF4(x0 + k), v1 = CF4(x1 + k), v2 = CF4(x2 + k);
    s0 += a.x*v0.x + a.y*v0.y + a.z*v0.z + a.w*v0.w;
    s1 += a.x*v1.x + a.y*v1.y + a.z*v1.z + a.w*v1.w;
    s2 += a.x*v2.x + a.y*v2.y + a.z*v2.z + a.w*v2.w;
  }
  #pragma unroll
  for (int m = 32; m > 0; m >>= 1) {
    s0 += __shfl_xor(s0, m); s1 += __shfl_xor(s1, m); s2 += __shfl_xor(s2, m);
  }
  if (t == 0) {
    float b = aib[i];
    outp[i] = s0 + b; outp[3072 + i] = s1 + b; outp[6144 + i] = s2 + b;
  }
}

__global__ __launch_bounds__(64) void matvec_nt(
    const float* __restrict__ A, int lda,
    const float* __restrict__ x, const float* __restrict__ badd,
    float* __restrict__ outp, int K)
{
  int i = blockIdx.x, t = threadIdx.x;
  const float* Ar = A + (size_t)i * lda;
  float s = 0.f;
  for (int k = t * 4; k < K; k += 256) {
    float4 a = CF4(Ar + k);
    float4 xx = CF4(x + k);
    s += a.x*xx.x + a.y*xx.y + a.z*xx.z + a.w*xx.w;
  }
  #pragma unroll
  for (int m = 32; m > 0; m >>= 1) s += __shfl_xor(s, m);
  if (t == 0) outp[i] = s + (badd ? badd[i] : 0.f);
}

__global__ __launch_bounds__(256) void imp_rep_k(
    const float* __restrict__ importance, const float* __restrict__ aob,
    float* __restrict__ imp, float* __restrict__ rep)
{
  __shared__ float si[3];
  if (threadIdx.x == 0) {
    float a = importance[0], b = importance[1], c = importance[2];
    float mx = fmaxf(a, fmaxf(b, c));
    float ea = expf(a - mx), eb = expf(b - mx), ec = expf(c - mx);
    float inv = 1.f / (ea + eb + ec);
    si[0] = ea * inv; si[1] = eb * inv; si[2] = ec * inv;
    imp[0] = si[0]; imp[1] = si[1]; imp[2] = si[2];
  }
  __syncthreads();
  for (int idx = threadIdx.x; idx < 3072; idx += 256)
    rep[idx] = si[idx >> 10] * aob[idx & 1023];
}

// cb768 = gbih + [gbhh_r | gbhh_z | 0] ; cb2048 = [prb | 0]
__global__ __launch_bounds__(256) void bias_prep(
    const float* __restrict__ gbih, const float* __restrict__ gbhh,
    const float* __restrict__ prb, float* __restrict__ cb768,
    float* __restrict__ cb2048)
{
  int i = blockIdx.x * 256 + threadIdx.x;
  if (i < 768) cb768[i] = gbih[i] + (i < 512 ? gbhh[i] : 0.f);
  if (i < 2048) cb2048[i] = (i < 1024) ? prb[i] : 0.f;
}

// =====================================================================
// 3-token MHA, bf16 in -> bf16 out
// =====================================================================
__global__ __launch_bounds__(256) void attn3(
    const unsigned short* __restrict__ qkv, unsigned short* __restrict__ att)
{
  const int n = blockIdx.x;
  const unsigned short* row = qkv + (size_t)n * 9216;
  __shared__ float qk[6144];
  __shared__ float sc[72];
  __shared__ float pw[72];
  const int t = threadIdx.x;
  for (int idx = t; idx < 768; idx += 256) {
    int m = idx >> 7;                  // 0..5
    int off = (idx & 127) << 3;
    const unsigned short* srcp = (m < 3) ? (row + m * 3072 + off)
                                         : (row + (m - 3) * 3072 + 1024 + off);
    short8 v = *(const short8*)srcp;
    float* dst = &qk[m * 1024 + off];
    #pragma unroll
    for (int j = 0; j < 8; ++j) dst[j] = bf2f(((const unsigned short*)&v)[j]);
  }
  __syncthreads();
  if (t < 72) {
    int h = t / 9, i = (t % 9) / 3, j = t % 3;
    const float* qp = &qk[i * 1024 + h * 128];
    const float* kp = &qk[3072 + j * 1024 + h * 128];
    float s = 0.f;
    int rot = (t & 31) * 4;
    for (int d2 = 0; d2 < 128; ++d2) {
      int dx = (d2 + rot) & 127;
      s += qp[dx] * kp[dx];
    }
    sc[t] = s * 0.08838834764831845f;
  }
  __syncthreads();
  if (t < 24) {
    int base = t * 3;
    float a = sc[base], b = sc[base + 1], c = sc[base + 2];
    float mx = fmaxf(a, fmaxf(b, c));
    float ea = expf(a - mx), eb = expf(b - mx), ec = expf(c - mx);
    float inv = 1.f / (ea + eb + ec);
    pw[base] = ea * inv; pw[base + 1] = eb * inv; pw[base + 2] = ec * inv;
  }
  __syncthreads();
  unsigned short* outp = att + (size_t)n * 3072;
  #pragma unroll
  for (int rep = 0; rep < 3; ++rep) {
    int idx = (rep * 256 + t) << 2;
    int i = idx >> 10;
    int hd = idx & 1023;
    int h = hd >> 7;
    int pb = (h * 3 + i) * 3;
    float w0 = pw[pb], w1 = pw[pb + 1], w2 = pw[pb + 2];
    ushort4 v0 = *(const ushort4*)(row + 2048 + hd);
    ushort4 v1 = *(const ushort4*)(row + 3072 + 2048 + hd);
    ushort4 v2 = *(const ushort4*)(row + 6144 + 2048 + hd);
    ushort4 o;
    o.x = f2bf(w0 * bf2f(v0.x) + w1 * bf2f(v1.x) + w2 * bf2f(v2.x));
    o.y = f2bf(w0 * bf2f(v0.y) + w1 * bf2f(v1.y) + w2 * bf2f(v2.y));
    o.z = f2bf(w0 * bf2f(v0.z) + w1 * bf2f(v1.z) + w2 * bf2f(v2.z));
    o.w = f2bf(w0 * bf2f(v0.w) + w1 * bf2f(v1.w) + w2 * bf2f(v2.w));
    *(ushort4*)(outp + idx) = o;
  }
}

// =====================================================================
__global__ __launch_bounds__(256) void layernorm_bf(
    unsigned short* __restrict__ X, const float* __restrict__ g,
    const float* __restrict__ bta)
{
  int n = blockIdx.x, t = threadIdx.x;
  unsigned short* row = X + (size_t)n * 1024;
  ushort4 hv = *(ushort4*)(row + t * 4);
  float x0 = bf2f(hv.x), x1 = bf2f(hv.y), x2 = bf2f(hv.z), x3 = bf2f(hv.w);
  float s = x0 + x1 + x2 + x3;
  float ss = x0*x0 + x1*x1 + x2*x2 + x3*x3;
  #pragma unroll
  for (int m = 32; m > 0; m >>= 1) { s += __shfl_xor(s, m); ss += __shfl_xor(ss, m); }
  __shared__ float rs[4], rss[4];
  int w = t >> 6;
  if ((t & 63) == 0) { rs[w] = s; rss[w] = ss; }
  __syncthreads();
  s = rs[0] + rs[1] + rs[2] + rs[3];
  ss = rss[0] + rss[1] + rss[2] + rss[3];
  float mean = s * (1.0f / 1024.0f);
  float var = ss * (1.0f / 1024.0f) - mean * mean;
  float inv = 1.0f / sqrtf(var + 1e-5f);
  float4 gg = CF4(g + t * 4);
  float4 bb = CF4(bta + t * 4);
  ushort4 o;
  o.x = f2bf((x0 - mean) * inv * gg.x + bb.x);
  o.y = f2bf((x1 - mean) * inv * gg.y + bb.y);
  o.z = f2bf((x2 - mean) * inv * gg.z + bb.z);
  o.w = f2bf((x3 - mean) * inv * gg.w + bb.w);
  *(ushort4*)(row + t * 4) = o;
}

__global__ __launch_bounds__(256) void build_R_bf(
    const float* __restrict__ Fpb, const float* __restrict__ noise,
    const float* __restrict__ s0, unsigned short* __restrict__ R)
{
  size_t idx = (size_t)blockIdx.x * 256 + threadIdx.x;
  int n = (int)(idx >> 8);
  int k4 = (int)(idx & 255) << 2;
  float4 v;
  if ((n & 127) == 0) {
    v = CF4(s0 + (size_t)(n >> 7) * 1024 + k4);
  } else {
    float4 f = CF4(Fpb + (size_t)(n - 1) * 1024 + k4);
    float4 z = CF4(noise + (size_t)(n - 1) * 1024 + k4);
    v.x = f.x + z.x; v.y = f.y + z.y; v.z = f.z + z.z; v.w = f.w + z.w;
  }
  ushort4 o;
  o.x = f2bf(v.x); o.y = f2bf(v.y); o.z = f2bf(v.z); o.w = f2bf(v.w);
  *(ushort4*)(R + (size_t)n * 1024 + k4) = o;
}

__global__ __launch_bounds__(256) void s_out_k(
    float* __restrict__ outp, const float* __restrict__ noise)
{
  size_t idx = (size_t)blockIdx.x * 256 + threadIdx.x;
  int n = (int)(idx >> 8);
  int j4 = (int)(idx & 255) << 2;
  float4 p = CF4(outp + (size_t)n * 3328 + 2304 + j4);
  float4 z = CF4(noise + (size_t)n * 1024 + j4);
  float4 o; o.x = p.x + z.x; o.y = p.y + z.y; o.z = p.z + z.z; o.w = p.w + z.w;
  F4(outp + (size_t)n * 3328 + 256 + j4) = o;
}

// =====================================================================
// Recurrence weight prep: 8 d-slices x 12 row-tiles of 16 rows, B-frag order.
// =====================================================================
__global__ __launch_bounds__(256) void wr_prep(
    const unsigned short* __restrict__ M1bf, const unsigned short* __restrict__ Whhbf,
    unsigned short* __restrict__ Wr)
{
  int idx = blockIdx.x * 256 + threadIdx.x;   // < 393216
  int j = idx & 7, l = (idx >> 3) & 63, kt = (idx >> 9) & 7;
  int rest = idx >> 12;                        // dd*12 + r
  int r = rest % 12, dd = rest / 12;
  int g = r >> 1, dhalf = r & 1;
  int d = dd * 32 + dhalf * 16 + (l & 15);
  int srow = (g % 3) * 256 + d;
  int k = kt * 32 + ((l >> 4) << 3) + j;
  const unsigned short* srcp = (g < 3) ? M1bf : Whhbf;
  Wr[idx] = srcp[(size_t)srow * 256 + k];
}

// hist frag layout: [buf][w'][kt][l][j], b=16w'+(l&15), k=kt*32+(l>>4)*8+j
__global__ __launch_bounds__(256) void h0_prep(
    const float* __restrict__ h0, unsigned short* __restrict__ hist)
{
  int idx = blockIdx.x * 256 + threadIdx.x;   // < 16384
  int j = idx & 7, l = (idx >> 3) & 63, kt = (idx >> 9) & 7, w = idx >> 12;
  int b = 16 * w + (l & 15);
  int k = kt * 32 + ((l >> 4) << 3) + j;
  hist[idx] = f2bf(h0[(size_t)b * 256 + k]);
}

// =====================================================================
// Sequential RSSM v7. 256 blocks launched (1/CU); 8 workers elected on
// XCD 0 (shared L2 -> sc0 coherence). Weights register-resident.
// Per-step sync: h-store(sc0) -> vmcnt(0) -> syncthreads -> flag[dd]=t+1
// (own cacheline, parallel stores, NO atomic RMW) -> background
// Hrow/out/Q-prefetch -> all-wave parallel poll of 8 flags (lane&7) ->
// stage next h -> syncthreads. counters: [8]=election, [16+16*dd]=flags.
// =====================================================================
#define LOADQ(tt) do { \
  _Pragma("unroll") \
  for (int g = 0; g < 3; ++g) { \
    const float* qp = Qr + (((((size_t)(tt) * 8 + dd) * 3 + g) * 4 + w) * 64 + l) * 8; \
    float4 qa = CF4(qp); float4 qb = CF4(qp + 4); \
    qv[g][0] = qa.x; qv[g][1] = qa.y; qv[g][2] = qa.z; qv[g][3] = qa.w; \
    qv[g][4] = qb.x; qv[g][5] = qb.y; qv[g][6] = qb.z; qv[g][7] = qb.w; \
  } } while (0)

#define STAGE_H(buf_idx) do { \
  const unsigned short* hsrc = hist + (size_t)(buf_idx) * 16384; \
  i32x4 sv[8]; \
  _Pragma("unroll") \
  for (int j = 0; j < 8; ++j) \
    sv[j] = coh_load16(hsrc + (size_t)(j * 256 + tid) * 8); \
  asm volatile("s_waitcnt vmcnt(0)" ::: "memory"); \
  SCHED_BARRIER(); \
  _Pragma("unroll") \
  for (int j = 0; j < 8; ++j) \
    *(i32x4*)&hL[(size_t)(j * 256 + tid) * 8] = sv[j]; \
  __syncthreads(); \
} while (0)

__global__ __launch_bounds__(256, 1) void rssm_recur7(
    const unsigned short* __restrict__ Wr, const float* __restrict__ Qr,
    const float* __restrict__ bhh_n, unsigned short* __restrict__ hist,
    unsigned short* __restrict__ Hrow, float* __restrict__ outp,
    unsigned int* __restrict__ counters)
{
  const int tid = threadIdx.x;
  __shared__ int s_role;
  if (tid == 0) {
    unsigned int xcc;
    asm volatile("s_getreg_b32 %0, hwreg(HW_REG_XCC_ID)" : "=s"(xcc));
    int role = -1;
    if ((xcc & 7u) == 0u) {
      unsigned int r = __hip_atomic_fetch_add(&counters[8], 1u, __ATOMIC_RELAXED,
                                              __HIP_MEMORY_SCOPE_AGENT);
      if (r < 8u) role = (int)r;
    }
    s_role = role;
  }
  __syncthreads();
  const int dd = s_role;                 // 0..7 for workers
  if (dd < 0) return;

  const int w = tid >> 6, l = tid & 63;
  __shared__ float G[12][16][68];            // 52KB gate exchange
  __shared__ unsigned short hL[16384];       // 32KB staged h frags

  // persistent B-frags: 3 row-tiles x 8 kt (96 VGPR)
  short8 Bf[3][8];
  {
    const unsigned short* wb = Wr + ((size_t)(dd * 12 + w * 3) * 8) * 512 + l * 8;
    #pragma unroll
    for (int ri = 0; ri < 3; ++ri)
      #pragma unroll
      for (int kt = 0; kt < 8; ++kt)
        Bf[ri][kt] = *(const short8*)(wb + (size_t)(ri * 8 + kt) * 512);
  }
  float bhn[8];
  #pragma unroll
  for (int j = 0; j < 8; ++j) bhn[j] = bhh_n[dd * 32 + ((l >> 4) << 3) + j];

  const int bg = w * 16 + (l & 15);       // GRU batch row
  const int dhalf = l >> 5;               // 0..1
  const int d16b = ((l >> 4) & 1) << 3;   // 0 or 8
  float qv[3][8];
  LOADQ(0);
  STAGE_H(0);   // prologue: h_0 from h0_prep

  #pragma unroll 1
  for (int t = 0; t < 128; ++t) {
    // ---- MFMA: 96 per wave (reads hL staged at end of prev iter) ----
    f32x4 acc[4][3];
    #pragma unroll
    for (int bt = 0; bt < 4; ++bt)
      #pragma unroll
      for (int ri = 0; ri < 3; ++ri) acc[bt][ri] = (f32x4){0.f, 0.f, 0.f, 0.f};
    #pragma unroll
    for (int kt = 0; kt < 8; ++kt)
      #pragma unroll
      for (int bt = 0; bt < 4; ++bt) {
        short8 a = *(const short8*)&hL[((bt * 8 + kt) * 64 + l) * 8];
        acc[bt][0] = __builtin_amdgcn_mfma_f32_16x16x32_bf16(a, Bf[0][kt], acc[bt][0], 0, 0, 0);
        acc[bt][1] = __builtin_amdgcn_mfma_f32_16x16x32_bf16(a, Bf[1][kt], acc[bt][1], 0, 0, 0);
        acc[bt][2] = __builtin_amdgcn_mfma_f32_16x16x32_bf16(a, Bf[2][kt], acc[bt][2], 0, 0, 0);
      }
    short8 ha = *(const short8*)&hL[((w * 8 + dd) * 64 + l) * 8];

    // ---- gate exchange (vector ds_write_b128) ----
    #pragma unroll
    for (int bt = 0; bt < 4; ++bt)
      #pragma unroll
      for (int ri = 0; ri < 3; ++ri)
        *(f32x4*)&G[w * 3 + ri][l & 15][bt * 16 + ((l >> 4) << 2)] = acc[bt][ri];
    __syncthreads();

    // ---- GRU: 8 cells (b = bg, d = dd*32 + (l>>4)*8 + j) ----
    const float m1s = (t == 0) ? 0.f : 1.f;
    unsigned short hn8[8];
    float hf8[8];
    #pragma unroll
    for (int j = 0; j < 8; ++j) {
      int d16 = d16b + j;
      float m1r = G[0 + dhalf][d16][bg];
      float m1z = G[2 + dhalf][d16][bg];
      float m1n = G[4 + dhalf][d16][bg];
      float ghr = G[6 + dhalf][d16][bg];
      float ghz = G[8 + dhalf][d16][bg];
      float ghn = G[10 + dhalf][d16][bg] + bhn[j];
      float gir = fmaf(m1r, m1s, qv[0][j]);
      float giz = fmaf(m1z, m1s, qv[1][j]);
      float gin = fmaf(m1n, m1s, qv[2][j]);
      float r = fsigmoid(gir + ghr);
      float z = fsigmoid(giz + ghz);
      float nn = ftanh(gin + r * ghn);
      float hold = bf2f(((const unsigned short*)&ha)[j]);
      float hn = (1.f - z) * nn + z * hold;
      unsigned short hbv = f2bf(hn);
      hn8[j] = hbv;
      hf8[j] = bf2f(hbv);
    }

    // ---- L2-coherent h store (the only store gating the flag) ----
    union { short8 s; i32x4 i; } hu;
    hu.s = *(const short8*)hn8;
    coh_store16(hist + (size_t)((t + 1) & 1) * 16384
                + (size_t)((w * 8 + dd) * 64 + l) * 8, hu.i);

    if (t < 127) {
      asm volatile("s_waitcnt vmcnt(0)" ::: "memory");   // h store in L2
      __syncthreads();                                   // all threads stored
      if (tid == 0)
        __hip_atomic_store(&counters[16 + dd * 16], (unsigned int)(t + 1),
                           __ATOMIC_RELAXED, __HIP_MEMORY_SCOPE_AGENT);
      // background work — drains during the poll
      *(short8*)(Hrow + (size_t)(bg * 128 + t) * 256 + dd * 32 + ((l >> 4) << 3)) =
          *(const short8*)hn8;
      float* op = outp + (size_t)(bg * 128 + t) * 3328 + dd * 32 + ((l >> 4) << 3);
      float4 o0; o0.x = hf8[0]; o0.y = hf8[1]; o0.z = hf8[2]; o0.w = hf8[3];
      float4 o1; o1.x = hf8[4]; o1.y = hf8[5]; o1.z = hf8[6]; o1.w = hf8[7];
      F4(op) = o0; F4(op + 4) = o1;
      LOADQ(t + 1);
      // ---- all-wave parallel flag poll (lane l&7 watches flag l&7) ----
      const unsigned int tgt = (unsigned int)(t + 1);
      while (true) {
        unsigned int v = __hip_atomic_load(&counters[16 + (l & 7) * 16],
                                           __ATOMIC_RELAXED,
                                           __HIP_MEMORY_SCOPE_AGENT);
        if (__all((int)(v >= tgt))) break;
      }
      // ---- stage h_{t+1} ----
      STAGE_H((t + 1) & 1);
    } else {
      *(short8*)(Hrow + (size_t)(bg * 128 + t) * 256 + dd * 32 + ((l >> 4) << 3)) =
          *(const short8*)hn8;
      float* op = outp + (size_t)(bg * 128 + t) * 3328 + dd * 32 + ((l >> 4) << 3);
      float4 o0; o0.x = hf8[0]; o0.y = hf8[1]; o0.z = hf8[2]; o0.w = hf8[3];
      float4 o1; o1.x = hf8[4]; o1.y = hf8[5]; o1.z = hf8[6]; o1.w = hf8[7];
      F4(op) = o0; F4(op + 4) = o1;
    }
  }
}

// =====================================================================
// Host side
// =====================================================================
static inline void g_bf(const unsigned short* A, int lda,
                        const unsigned short* B, int ldb,
                        void* C, int ldc, int M, int N, int K,
                        const float* bias, const float* src, int ldsrc,
                        const float* scale, int relu, int obf16, hipStream_t s,
                        const unsigned short* A2 = nullptr, int lda2 = 0,
                        int kSplit = 1 << 30,
                        const unsigned short* B2 = nullptr, int ldb2 = 0,
                        int nSplit = 1 << 30,
                        int src_c0 = 0, int qperm = 0)
{
  dim3 grid(N / 128, M / 128);
  gemm_bf<<<grid, 256, 0, s>>>(A, lda, A2, lda2, kSplit, B, ldb, B2, ldb2, nSplit,
                               C, ldc, K, bias, src, ldsrc, src_c0, scale, relu,
                               obf16, qperm);
}

extern "C" void kernel_launch(void* const* d_in, const int* in_sizes, int n_in,
                              void* d_out, int out_size, void* d_ws, size_t ws_size,
                              hipStream_t stream)
{
  (void)in_sizes; (void)n_in; (void)out_size;

  const float* emb_v = (const float*)d_in[0];
  const float* emb_t = (const float*)d_in[1];
  const float* emb_p = (const float*)d_in[2];
  const float* noise = (const float*)d_in[3];
  const float* h0    = (const float*)d_in[4];
  const float* s0    = (const float*)d_in[5];
  const float* pvw   = (const float*)d_in[6];
  const float* pvb   = (const float*)d_in[7];
  const float* ptw   = (const float*)d_in[8];
  const float* ptb   = (const float*)d_in[9];
  const float* ppw   = (const float*)d_in[10];
  const float* ppb   = (const float*)d_in[11];
  const float* aiw   = (const float*)d_in[12];
  const float* aib   = (const float*)d_in[13];
  const float* aow   = (const float*)d_in[14];
  const float* aob   = (const float*)d_in[15];
  const float* importance = (const float*)d_in[16];
  const float* fw1   = (const float*)d_in[17];
  const float* fb1   = (const float*)d_in[18];
  const float* fw2   = (const float*)d_in[19];
  const float* fb2   = (const float*)d_in[20];
  const float* ln_g  = (const float*)d_in[21];
  const float* ln_b  = (const float*)d_in[22];
  const float* gwih  = (const float*)d_in[23];
  const float* gwhh  = (const float*)d_in[24];
  const float* gbih  = (const float*)d_in[25];
  const float* gbhh  = (const float*)d_in[26];
  const float* prw   = (const float*)d_in[27];
  const float* prb   = (const float*)d_in[28];
  const float* pow_  = (const float*)d_in[29];
  const float* pob   = (const float*)d_in[30];

  float* out = (float*)d_out;
  char* W = (char*)d_ws;

  size_t off = 0;
  auto alloc = [&](size_t bytes) { off = (off + 63) & ~63ull; size_t o = off; off += bytes; return o; };
  const size_t o_cnt    = alloc(2048);
  const size_t o_imp    = alloc(16);
  const size_t o_rep    = alloc(3072 * 4);
  const size_t o_bqkv   = alloc(9216 * 4);
  const size_t o_bf1    = alloc(1024 * 4);
  const size_t o_cb768  = alloc(768 * 4);
  const size_t o_cb2048 = alloc(2048 * 4);
  const size_t o_gwihb  = alloc(768ull * 2048 * 2);
  const size_t o_whhb   = alloc(768ull * 256 * 2);
  const size_t o_m1b    = alloc(768ull * 256 * 2);
  const size_t o_prwb   = alloc(1024ull * 256 * 2);
  const size_t o_powb   = alloc(1024ull * 1280 * 2);
  const size_t o_wr     = alloc(393216ull * 2);
  const size_t o_hist   = alloc(2ull * 16384 * 2);
  const size_t o_hrow   = alloc(8192ull * 256 * 2);
  const size_t o_fusedb = alloc(8192ull * 1024 * 2);
  const size_t o_fpb    = alloc(8192ull * 1024 * 4);
  const size_t o_rbf    = alloc(8192ull * 1024 * 2);
  const size_t o_embvb  = alloc(8192ull * 512 * 2);
  const size_t o_embtb  = alloc(8192ull * 512 * 2);
  const size_t o_embpb  = alloc(8192ull * 256 * 2);
  const size_t o_wqv    = alloc(3072ull * 512 * 2);
  const size_t o_wqt    = alloc(3072ull * 512 * 2);
  const size_t o_wqp    = alloc(3072ull * 256 * 2);
  const size_t o_wf1    = alloc(1024ull * 3072 * 2);
  const size_t o_fw2b   = alloc(1024ull * 1024 * 2);
  const size_t o_fused1 = alloc(8192ull * 1024 * 2);
  const size_t o_sub    = (off + 63) & ~63ull;

  // sub-pool (time-shared): prep temps -> per-chunk qkv/att -> Qr
  const size_t so_aiwb = 0;
  const size_t so_fw1b = so_aiwb + 3072ull * 1024 * 2;
  const size_t so_pTv  = so_fw1b + 1024ull * 3072 * 2;
  const size_t so_pTt  = so_pTv + 512ull * 1024 * 2;
  const size_t so_pTp  = so_pTt + 512ull * 1024 * 2;
  const size_t so_aoT  = so_pTp + 256ull * 1024 * 2;
  const size_t so_WphT = so_aoT + 1024ull * 1024 * 2;
  const size_t prep_bytes = so_WphT + 256ull * 1024 * 2;
  const size_t q_bytes = 8192ull * 768 * 4;

  int NC = 512;
  for (int cand : {8192, 4096, 2048, 1024}) {
    size_t sub = prep_bytes > q_bytes ? prep_bytes : q_bytes;
    size_t cb = (size_t)cand * 9216 * 2 + (size_t)cand * 3072 * 2;
    if (cb > sub) sub = cb;
    if (o_sub + sub <= ws_size) { NC = cand; break; }
  }
  const size_t o_qkvc = o_sub;
  const size_t o_attc = o_sub + (size_t)NC * 9216 * 2;
  const size_t o_qr   = o_sub;

  auto FP = [&](size_t o) { return (float*)(W + o); };
  auto UP = [&](size_t o) { return (unsigned short*)(W + o); };

  hipMemsetAsync(W + o_cnt, 0, 2048, stream);
  imp_rep_k<<<1, 256, 0, stream>>>(importance, aob, FP(o_imp), FP(o_rep));
  bias_prep<<<8, 256, 0, stream>>>(gbih, gbhh, prb, FP(o_cb768), FP(o_cb2048));

  // batched bf16 conversions (one launch)
  {
    CvtArgs a;
    const float* srcs[10] = {aiw, fw1, fw2, gwih, gwhh, prw, pow_,
                             emb_v, emb_t, emb_p};
    unsigned short* dsts[10] = {
        UP(o_sub + so_aiwb), UP(o_sub + so_fw1b), UP(o_fw2b), UP(o_gwihb),
        UP(o_whhb), UP(o_prwb), UP(o_powb),
        UP(o_embvb), UP(o_embtb), UP(o_embpb)};
    const size_t n4s[10] = {3072ull*1024/4, 1024ull*3072/4, 1024ull*1024/4,
                            768ull*2048/4, 768ull*256/4, 1024ull*256/4,
                            1024ull*1280/4,
                            8192ull*512/4, 8192ull*512/4, 8192ull*256/4};
    int cum = 0;
    for (int k = 0; k < 10; ++k) {
      a.src[k] = srcs[k]; a.dst[k] = dsts[k];
      a.n4[k] = (int)n4s[k];
      cum += (int)((n4s[k] + 255) / 256);
      a.bend[k] = cum;
    }
    cvt_all<<<cum, 256, 0, stream>>>(a);
  }

  transpose_bf<<<dim3(16, 32), 256, 0, stream>>>(pvw, 512, UP(o_sub + so_pTv), 1024);
  transpose_bf<<<dim3(16, 32), 256, 0, stream>>>(ptw, 512, UP(o_sub + so_pTt), 1024);
  transpose_bf<<<dim3(8, 32), 256, 0, stream>>>(ppw, 256, UP(o_sub + so_pTp), 1024);
  transpose_bf<<<dim3(32, 32), 256, 0, stream>>>(aow, 1024, UP(o_sub + so_aoT), 1024);
  transpose_bf<<<dim3(8, 32), 256, 0, stream>>>(pow_, 1280, UP(o_sub + so_WphT), 1024);

  matvec3<<<3072, 64, 0, stream>>>(aiw, pvb, ptb, ppb, aib, FP(o_bqkv));
  matvec_nt<<<1024, 64, 0, stream>>>(fw1, 3072, FP(o_rep), fb1, FP(o_bf1), 3072);

  // folded weights
  g_bf(UP(o_sub + so_aiwb), 1024, UP(o_sub + so_pTv), 1024, UP(o_wqv), 512,
       3072, 512, 1024, nullptr, nullptr, 0, nullptr, 0, 1, stream);
  g_bf(UP(o_sub + so_aiwb), 1024, UP(o_sub + so_pTt), 1024, UP(o_wqt), 512,
       3072, 512, 1024, nullptr, nullptr, 0, nullptr, 0, 1, stream);
  g_bf(UP(o_sub + so_aiwb), 1024, UP(o_sub + so_pTp), 1024, UP(o_wqp), 256,
       3072, 256, 1024, nullptr, nullptr, 0, nullptr, 0, 1, stream);
  for (int m = 0; m < 3; ++m)
    g_bf(UP(o_sub + so_fw1b) + m * 1024, 3072, UP(o_sub + so_aoT), 1024,
         UP(o_wf1) + m * 1024, 3072, 1024, 1024, 1024,
         nullptr, nullptr, 0, FP(o_imp) + m, 0, 1, stream);
  g_bf(UP(o_gwihb), 2048, UP(o_sub + so_WphT), 1024, UP(o_m1b), 256,
       768, 256, 1024, nullptr, nullptr, 0, nullptr, 0, 1, stream);

  wr_prep<<<1536, 256, 0, stream>>>(UP(o_m1b), UP(o_whhb), UP(o_wr));
  h0_prep<<<64, 256, 0, stream>>>(h0, UP(o_hist));

  // phase A: qkv (bf16) -> attention -> fused1
  const int nchunk = 8192 / NC;
  for (int c = 0; c < nchunk; ++c) {
    g_bf(UP(o_embvb) + (size_t)c * NC * 512, 512, UP(o_wqv), 512,
         UP(o_qkvc) + 0, 9216, NC, 3072, 512, FP(o_bqkv) + 0,
         nullptr, 0, nullptr, 0, 1, stream);
    g_bf(UP(o_embtb) + (size_t)c * NC * 512, 512, UP(o_wqt), 512,
         UP(o_qkvc) + 3072, 9216, NC, 3072, 512, FP(o_bqkv) + 3072,
         nullptr, 0, nullptr, 0, 1, stream);
    g_bf(UP(o_embpb) + (size_t)c * NC * 256, 256, UP(o_wqp), 256,
         UP(o_qkvc) + 6144, 9216, NC, 3072, 256, FP(o_bqkv) + 6144,
         nullptr, 0, nullptr, 0, 1, stream);
    attn3<<<NC, 256, 0, stream>>>(UP(o_qkvc), UP(o_attc));
    g_bf(UP(o_attc), 3072, UP(o_wf1), 3072,
         UP(o_fused1) + (size_t)c * NC * 1024, 1024, NC, 1024, 3072,
         FP(o_bf1), nullptr, 0, nullptr, 1 /*relu*/, 1, stream);
  }

  g_bf(UP(o_fused1), 1024, UP(o_fw2b), 1024, UP(o_fusedb), 1024,
       8192, 1024, 1024, fb2, nullptr, 0, nullptr, 0, 1, stream);
  layernorm_bf<<<8192, 256, 0, stream>>>(UP(o_fusedb), ln_g, ln_b);

  g_bf(UP(o_fusedb), 1024, UP(o_powb) + 256, 1280, FP(o_fpb), 1024,
       8192, 1024, 1024, pob, nullptr, 0, nullptr, 0, 0, stream);
  build_R_bf<<<8192, 256, 0, stream>>>(FP(o_fpb), noise, s0, UP(o_rbf));
  // Qr = [R | fused] @ gwih^T + (gbih + bhh_rz), written in frag-perm order
  g_bf(UP(o_rbf), 1024, UP(o_gwihb), 2048, FP(o_qr), 768,
       8192, 768, 2048, FP(o_cb768), nullptr, 0, nullptr, 0, 0, stream,
       UP(o_fusedb), 1024, 1024, nullptr, 0, 1 << 30, 0, 1 /*qperm*/);

  rssm_recur7<<<256, 256, 0, stream>>>(UP(o_wr), FP(o_qr), gbhh + 512, UP(o_hist),
                                       UP(o_hrow), out, (unsigned int*)(W + o_cnt));

  // prior | post in one dual-B GEMM (out cols 1280..3327)
  g_bf(UP(o_hrow), 256, UP(o_prwb), 256, out + 1280, 3328,
       8192, 2048, 256, FP(o_cb2048), FP(o_fpb), 1024, nullptr, 0, 0, stream,
       nullptr, 0, 1 << 30, UP(o_powb), 1280, 1024, 1024 /*src_c0*/, 0);
  s_out_k<<<8192, 256, 0, stream>>>(out, noise);
}